// Round 1
// baseline (3840.371 us; speedup 1.0000x reference)
//
#include <hip/hip_runtime.h>
#include <hip/hip_bf16.h>

#define NEG_SLOPE 0.2f

static __device__ __forceinline__ unsigned fkey(float f) {
    unsigned b = __float_as_uint(f);
    return (b & 0x80000000u) ? ~b : (b | 0x80000000u);
}
static __device__ __forceinline__ float funkey(unsigned k) {
    return __uint_as_float((k & 0x80000000u) ? (k & 0x7FFFFFFFu) : ~k);
}

// combW[o][i] = sum_k out_w[o][k]*in_w[256+k][i] ; combb[o] = out_b[o] + sum_k out_w[o][k]*in_b[256+k]
__global__ __launch_bounds__(256) void mha_combine(
    const float* __restrict__ in_w, const float* __restrict__ in_b,
    const float* __restrict__ out_w, const float* __restrict__ out_b,
    float* __restrict__ combW, float* __restrict__ combb)
{
    int idx = blockIdx.x * blockDim.x + threadIdx.x;
    if (idx >= 128 * 128) return;
    int o = idx >> 7, i = idx & 127;
    float a = 0.f;
    for (int k = 0; k < 128; ++k)
        a = fmaf(out_w[o * 128 + k], in_w[(256 + k) * 128 + i], a);
    combW[idx] = a;
    if (i == 0) {
        float b = out_b[o];
        for (int k = 0; k < 128; ++k)
            b = fmaf(out_w[o * 128 + k], in_b[256 + k], b);
        combb[o] = b;
    }
}

// out[n][o] = sum_k A[n][k] * W[o][k]  (+bias[o]); optional epilogue:
// ssrc[n] = sum_o out[n][o]*asrc[o], sdst likewise.
// Tile: 32 rows x 128 cols per block (256 thr), W staged in LDS in two k-halves.
__global__ __launch_bounds__(256) void gemm_nt(
    const float* __restrict__ A, const float* __restrict__ W,
    const float* __restrict__ bias,
    const float* __restrict__ asrc, const float* __restrict__ adst,
    float* __restrict__ out, float* __restrict__ ssrc, float* __restrict__ sdst,
    int n)
{
    __shared__ float Wt[64 * 132];   // Wt[kk][o], padded stride 132
    __shared__ float xs[32 * 128];
    const int t = threadIdx.x;
    const int row0 = blockIdx.x * 32;

    for (int i = t; i < 32 * 32; i += 256) {          // 1024 float4
        int r = i >> 5, c4 = i & 31;
        int gr = row0 + r;
        float4 v = (gr < n) ? ((const float4*)A)[(size_t)gr * 32 + c4]
                            : make_float4(0.f, 0.f, 0.f, 0.f);
        ((float4*)xs)[i] = v;
    }

    const int co = (t & 31) * 4;        // col base (0..124)
    const int rbase = (t >> 5) * 4;     // row base within tile (0..28)
    float4 acc[4];
#pragma unroll
    for (int j = 0; j < 4; ++j) acc[j] = make_float4(0.f, 0.f, 0.f, 0.f);

    for (int half = 0; half < 2; ++half) {
        const int kbase = half * 64;
        __syncthreads();
        for (int i = t; i < 64 * 128; i += 256) {     // load W^T slice
            int o = i >> 6, kk = i & 63;
            Wt[kk * 132 + o] = W[o * 128 + kbase + kk];
        }
        __syncthreads();
#pragma unroll 4
        for (int k4 = 0; k4 < 16; ++k4) {
            float4 xv[4];
#pragma unroll
            for (int j = 0; j < 4; ++j)
                xv[j] = ((const float4*)xs)[(rbase + j) * 32 + (kbase >> 2) + k4];
#pragma unroll
            for (int kk = 0; kk < 4; ++kk) {
                float4 w = *(const float4*)&Wt[(k4 * 4 + kk) * 132 + co];
#pragma unroll
                for (int j = 0; j < 4; ++j) {
                    float xb = (&xv[j].x)[kk];
                    acc[j].x = fmaf(xb, w.x, acc[j].x);
                    acc[j].y = fmaf(xb, w.y, acc[j].y);
                    acc[j].z = fmaf(xb, w.z, acc[j].z);
                    acc[j].w = fmaf(xb, w.w, acc[j].w);
                }
            }
        }
    }

    float4 bv = make_float4(0.f, 0.f, 0.f, 0.f);
    if (bias) bv = *(const float4*)&bias[co];
#pragma unroll
    for (int j = 0; j < 4; ++j) {
        int r = row0 + rbase + j;
        if (r < n) {
            float4 v = acc[j];
            v.x += bv.x; v.y += bv.y; v.z += bv.z; v.w += bv.w;
            ((float4*)out)[(size_t)r * 32 + (t & 31)] = v;
        }
    }

    if (asrc != nullptr) {
        float4 as = *(const float4*)&asrc[co];
        float4 ad = *(const float4*)&adst[co];
#pragma unroll
        for (int j = 0; j < 4; ++j) {
            float ps = acc[j].x * as.x + acc[j].y * as.y + acc[j].z * as.z + acc[j].w * as.w;
            float pd = acc[j].x * ad.x + acc[j].y * ad.y + acc[j].z * ad.z + acc[j].w * ad.w;
#pragma unroll
            for (int off = 16; off; off >>= 1) {
                ps += __shfl_xor(ps, off);
                pd += __shfl_xor(pd, off);
            }
            if ((t & 31) == 0) {
                int r = row0 + rbase + j;
                if (r < n) { ssrc[r] = ps; sdst[r] = pd; }
            }
        }
    }
}

__global__ __launch_bounds__(256) void edge_logits(
    const int* __restrict__ ei, int E, int n,
    const float* __restrict__ ssrc, const float* __restrict__ sdst,
    float* __restrict__ elog, unsigned* __restrict__ mkey)
{
    int e = blockIdx.x * blockDim.x + threadIdx.x;
    int ET = E + n;
    if (e >= ET) return;
    int src = (e < E) ? ei[e] : (e - E);
    int dst = (e < E) ? ei[E + e] : (e - E);
    float v = ssrc[src] + sdst[dst];
    v = (v > 0.f) ? v : NEG_SLOPE * v;
    elog[e] = v;
    atomicMax(&mkey[dst], fkey(v));
}

__global__ __launch_bounds__(256) void unmap_max(unsigned* __restrict__ m, int n)
{
    int i = blockIdx.x * blockDim.x + threadIdx.x;
    if (i < n) ((float*)m)[i] = funkey(m[i]);
}

// one 64-lane wave per edge: broadcast weight, gather h[src] (float2/lane), scatter-add to num[dst]
__global__ __launch_bounds__(256) void edge_aggregate(
    const int* __restrict__ ei, int E, int n,
    const float* __restrict__ elog, const float* __restrict__ mf,
    float* __restrict__ s,
    const float* __restrict__ h, float* __restrict__ num)
{
    int wid = (int)((blockIdx.x * (size_t)blockDim.x + threadIdx.x) >> 6);
    int lane = threadIdx.x & 63;
    int ET = E + n;
    if (wid >= ET) return;
    int src = (wid < E) ? ei[wid] : (wid - E);
    int dst = (wid < E) ? ei[E + wid] : (wid - E);
    float ex = __expf(elog[wid] - mf[dst]);
    if (lane == 0) unsafeAtomicAdd(&s[dst], ex);
    float2 hv = ((const float2*)(h + (size_t)src * 128))[lane];
    float* np = num + (size_t)dst * 128 + lane * 2;
    unsafeAtomicAdd(np, ex * hv.x);
    unsafeAtomicAdd(np + 1, ex * hv.y);
}

__global__ __launch_bounds__(256) void finalize_k(
    const float* __restrict__ num, const float* __restrict__ s,
    const float* __restrict__ bias, float* __restrict__ out, int n, int relu)
{
    size_t i = blockIdx.x * (size_t)blockDim.x + threadIdx.x;
    if (i >= (size_t)n * 128) return;
    int node = (int)(i >> 7), c = (int)(i & 127);
    float v = num[i] / (s[node] + 1e-16f) + bias[c];
    if (relu) v = fmaxf(v, 0.f);
    out[i] = v;
}

// one wave per node: 40-class fc over [ox|oy|x] + log_softmax
__global__ __launch_bounds__(256) void fc_logsoftmax(
    const float* __restrict__ ox, const float* __restrict__ oy,
    const float* __restrict__ xres,
    const float* __restrict__ fcw, const float* __restrict__ fcb,
    float* __restrict__ out, int n)
{
    __shared__ float rows[4][384];
    int w = threadIdx.x >> 6;
    int lane = threadIdx.x & 63;
    int node = blockIdx.x * 4 + w;
    if (node >= n) node = n - 1;   // duplicate work, identical values
    for (int i = lane; i < 128; i += 64) {
        rows[w][i]       = ox[(size_t)node * 128 + i];
        rows[w][128 + i] = oy[(size_t)node * 128 + i];
        rows[w][256 + i] = xres[(size_t)node * 128 + i];
    }
    __syncthreads();
    float acc;
    if (lane < 40) {
        const float4* wr = (const float4*)(fcw + (size_t)lane * 384);
        const float4* rr = (const float4*)&rows[w][0];
        float a = 0.f;
#pragma unroll 4
        for (int k = 0; k < 96; ++k) {
            float4 rv = rr[k], wv = wr[k];
            a = fmaf(rv.x, wv.x, a); a = fmaf(rv.y, wv.y, a);
            a = fmaf(rv.z, wv.z, a); a = fmaf(rv.w, wv.w, a);
        }
        acc = a + fcb[lane];
    } else {
        acc = -INFINITY;
    }
    float mx = acc;
#pragma unroll
    for (int off = 32; off; off >>= 1) mx = fmaxf(mx, __shfl_xor(mx, off));
    float ex = (lane < 40) ? __expf(acc - mx) : 0.f;
    float sm = ex;
#pragma unroll
    for (int off = 32; off; off >>= 1) sm += __shfl_xor(sm, off);
    if (lane < 40) out[(size_t)node * 40 + lane] = acc - mx - logf(sm);
}

static void gat_layer(const float* f, const float* Wg,
                      const float* asrc_w, const float* adst_w, const float* bias,
                      const int* ei, int E, int N, int relu,
                      float* hbuf, float* numbuf, float* outbuf,
                      float* mbuf, float* sbuf, float* ssrc, float* sdst, float* elog,
                      hipStream_t stream)
{
    int gblocks = (N + 31) / 32;
    gemm_nt<<<gblocks, 256, 0, stream>>>(f, Wg, nullptr, asrc_w, adst_w, hbuf, ssrc, sdst, N);
    hipMemsetAsync(numbuf, 0, (size_t)N * 128 * sizeof(float), stream);
    hipMemsetAsync(mbuf, 0, (size_t)N * sizeof(float), stream);
    hipMemsetAsync(sbuf, 0, (size_t)N * sizeof(float), stream);
    int ET = E + N;
    edge_logits<<<(ET + 255) / 256, 256, 0, stream>>>(ei, E, N, ssrc, sdst, elog, (unsigned*)mbuf);
    unmap_max<<<(N + 255) / 256, 256, 0, stream>>>((unsigned*)mbuf, N);
    edge_aggregate<<<(ET + 3) / 4, 256, 0, stream>>>(ei, E, N, elog, mbuf, sbuf, hbuf, numbuf);
    finalize_k<<<(int)(((size_t)N * 128 + 255) / 256), 256, 0, stream>>>(numbuf, sbuf, bias, outbuf, N, relu);
}

extern "C" void kernel_launch(void* const* d_in, const int* in_sizes, int n_in,
                              void* d_out, int out_size, void* d_ws, size_t ws_size,
                              hipStream_t stream)
{
    const float* x    = (const float*)d_in[0];
    const float* y    = (const float*)d_in[1];
    const int*   eix  = (const int*)d_in[2];
    const int*   eiy  = (const int*)d_in[3];
    const float* a1iw = (const float*)d_in[4];
    const float* a1ib = (const float*)d_in[5];
    const float* a1ow = (const float*)d_in[6];
    const float* a1ob = (const float*)d_in[7];
    const float* a2iw = (const float*)d_in[8];
    const float* a2ib = (const float*)d_in[9];
    const float* a2ow = (const float*)d_in[10];
    const float* a2ob = (const float*)d_in[11];
    const float* g1w  = (const float*)d_in[12];
    const float* g1as = (const float*)d_in[13];
    const float* g1ad = (const float*)d_in[14];
    const float* g1b  = (const float*)d_in[15];
    const float* g2xw = (const float*)d_in[16];
    const float* g2xas= (const float*)d_in[17];
    const float* g2xad= (const float*)d_in[18];
    const float* g2xb = (const float*)d_in[19];
    const float* g2yw = (const float*)d_in[20];
    const float* g2yas= (const float*)d_in[21];
    const float* g2yad= (const float*)d_in[22];
    const float* g2yb = (const float*)d_in[23];
    const float* fcw  = (const float*)d_in[24];
    const float* fcb  = (const float*)d_in[25];
    float* outp = (float*)d_out;

    const int N = in_sizes[0] / 128;
    const int E = in_sizes[2] / 2;
    (void)n_in; (void)out_size; (void)ws_size;

    float* ws = (float*)d_ws;
    size_t NF = (size_t)N * 128;
    float* A    = ws;
    float* B    = A + NF;
    float* C    = B + NF;
    float* D    = C + NF;
    float* mbuf = D + NF;
    float* sbuf = mbuf + N;
    float* ssrc = sbuf + N;
    float* sdst = ssrc + N;
    float* elog = sdst + N;
    float* cw1  = elog + (size_t)(E + N);
    float* cb1  = cw1 + 128 * 128;
    float* cw2  = cb1 + 128;
    float* cb2  = cw2 + 128 * 128;

    mha_combine<<<64, 256, 0, stream>>>(a1iw, a1ib, a1ow, a1ob, cw1, cb1);
    mha_combine<<<64, 256, 0, stream>>>(a2iw, a2ib, a2ow, a2ob, cw2, cb2);

    int gblocks = (N + 31) / 32;

    // ---- x path ----
    gemm_nt<<<gblocks, 256, 0, stream>>>(x, cw1, cb1, nullptr, nullptr, A, nullptr, nullptr, N);
    gat_layer(A, g1w,  g1as,  g1ad,  g1b,  eix, E, N, 1, B, C, C, mbuf, sbuf, ssrc, sdst, elog, stream);
    gat_layer(C, g2xw, g2xas, g2xad, g2xb, eix, E, N, 0, B, D, D, mbuf, sbuf, ssrc, sdst, elog, stream);

    // ---- y path ----
    gemm_nt<<<gblocks, 256, 0, stream>>>(y, cw2, cb2, nullptr, nullptr, A, nullptr, nullptr, N);
    gat_layer(A, g1w,  g1as,  g1ad,  g1b,  eiy, E, N, 1, B, C, C, mbuf, sbuf, ssrc, sdst, elog, stream);
    gat_layer(C, g2yw, g2yas, g2yad, g2yb, eiy, E, N, 0, B, A, A, mbuf, sbuf, ssrc, sdst, elog, stream);

    // ---- fusion fc + log_softmax ----
    fc_logsoftmax<<<(N + 3) / 4, 256, 0, stream>>>(D, A, x, fcw, fcb, outp, N);
}

// Round 2
// 1367.388 us; speedup vs baseline: 2.8085x; 2.8085x over previous
//
#include <hip/hip_runtime.h>
#include <hip/hip_bf16.h>

#define NEG_SLOPE 0.2f

// combW[o][i] = sum_k out_w[o][k]*in_w[256+k][i] ; combb[o] = out_b[o] + sum_k out_w[o][k]*in_b[256+k]
__global__ __launch_bounds__(256) void mha_combine(
    const float* __restrict__ in_w, const float* __restrict__ in_b,
    const float* __restrict__ out_w, const float* __restrict__ out_b,
    float* __restrict__ combW, float* __restrict__ combb)
{
    int idx = blockIdx.x * blockDim.x + threadIdx.x;
    if (idx >= 128 * 128) return;
    int o = idx >> 7, i = idx & 127;
    float a = 0.f;
    for (int k = 0; k < 128; ++k)
        a = fmaf(out_w[o * 128 + k], in_w[(256 + k) * 128 + i], a);
    combW[idx] = a;
    if (i == 0) {
        float b = out_b[o];
        for (int k = 0; k < 128; ++k)
            b = fmaf(out_w[o * 128 + k], in_b[256 + k], b);
        combb[o] = b;
    }
}

// out[n][o] = sum_k A[n][k] * W[o][k]  (+bias[o]); optional epilogue:
// ssrc[n] = sum_o out[n][o]*asrc[o], sdst likewise.
__global__ __launch_bounds__(256) void gemm_nt(
    const float* __restrict__ A, const float* __restrict__ W,
    const float* __restrict__ bias,
    const float* __restrict__ asrc, const float* __restrict__ adst,
    float* __restrict__ out, float* __restrict__ ssrc, float* __restrict__ sdst,
    int n)
{
    __shared__ float Wt[64 * 132];   // Wt[kk][o], padded stride 132
    __shared__ float xs[32 * 128];
    const int t = threadIdx.x;
    const int row0 = blockIdx.x * 32;

    for (int i = t; i < 32 * 32; i += 256) {          // 1024 float4
        int r = i >> 5, c4 = i & 31;
        int gr = row0 + r;
        float4 v = (gr < n) ? ((const float4*)A)[(size_t)gr * 32 + c4]
                            : make_float4(0.f, 0.f, 0.f, 0.f);
        ((float4*)xs)[i] = v;
    }

    const int co = (t & 31) * 4;        // col base (0..124)
    const int rbase = (t >> 5) * 4;     // row base within tile (0..28)
    float4 acc[4];
#pragma unroll
    for (int j = 0; j < 4; ++j) acc[j] = make_float4(0.f, 0.f, 0.f, 0.f);

    for (int half = 0; half < 2; ++half) {
        const int kbase = half * 64;
        __syncthreads();
        for (int i = t; i < 64 * 128; i += 256) {     // load W^T slice
            int o = i >> 6, kk = i & 63;
            Wt[kk * 132 + o] = W[o * 128 + kbase + kk];
        }
        __syncthreads();
#pragma unroll 4
        for (int k4 = 0; k4 < 16; ++k4) {
            float4 xv[4];
#pragma unroll
            for (int j = 0; j < 4; ++j)
                xv[j] = ((const float4*)xs)[(rbase + j) * 32 + (kbase >> 2) + k4];
#pragma unroll
            for (int kk = 0; kk < 4; ++kk) {
                float4 w = *(const float4*)&Wt[(k4 * 4 + kk) * 132 + co];
#pragma unroll
                for (int j = 0; j < 4; ++j) {
                    float xb = (&xv[j].x)[kk];
                    acc[j].x = fmaf(xb, w.x, acc[j].x);
                    acc[j].y = fmaf(xb, w.y, acc[j].y);
                    acc[j].z = fmaf(xb, w.z, acc[j].z);
                    acc[j].w = fmaf(xb, w.w, acc[j].w);
                }
            }
        }
    }

    float4 bv = make_float4(0.f, 0.f, 0.f, 0.f);
    if (bias) bv = *(const float4*)&bias[co];
#pragma unroll
    for (int j = 0; j < 4; ++j) {
        int r = row0 + rbase + j;
        if (r < n) {
            float4 v = acc[j];
            v.x += bv.x; v.y += bv.y; v.z += bv.z; v.w += bv.w;
            ((float4*)out)[(size_t)r * 32 + (t & 31)] = v;
        }
    }

    if (asrc != nullptr) {
        float4 as = *(const float4*)&asrc[co];
        float4 ad = *(const float4*)&adst[co];
#pragma unroll
        for (int j = 0; j < 4; ++j) {
            float ps = acc[j].x * as.x + acc[j].y * as.y + acc[j].z * as.z + acc[j].w * as.w;
            float pd = acc[j].x * ad.x + acc[j].y * ad.y + acc[j].z * ad.z + acc[j].w * ad.w;
#pragma unroll
            for (int off = 16; off; off >>= 1) {
                ps += __shfl_xor(ps, off);
                pd += __shfl_xor(pd, off);
            }
            if ((t & 31) == 0) {
                int r = row0 + rbase + j;
                if (r < n) { ssrc[r] = ps; sdst[r] = pd; }
            }
        }
    }
}

// ---------------- CSR build (counting sort by dst, incl. self loops) ----------------

__global__ __launch_bounds__(256) void hist_k(
    const int* __restrict__ ei, int E, int n, int* __restrict__ cnt)
{
    int e = blockIdx.x * blockDim.x + threadIdx.x;
    if (e >= E + n) return;
    int d = (e < E) ? ei[E + e] : (e - E);
    atomicAdd(&cnt[d], 1);
}

// single-block exclusive scan, 1024 threads, chunked
__global__ __launch_bounds__(1024) void exscan_k(
    const int* __restrict__ cnt, int* __restrict__ off, int n)
{
    __shared__ int tmp[1024];
    __shared__ int carry_s;
    int t = threadIdx.x;
    if (t == 0) carry_s = 0;
    __syncthreads();
    for (int base = 0; base < n; base += 1024) {
        int i = base + t;
        int v = (i < n) ? cnt[i] : 0;
        tmp[t] = v;
        __syncthreads();
        for (int d = 1; d < 1024; d <<= 1) {
            int add = (t >= d) ? tmp[t - d] : 0;
            __syncthreads();
            tmp[t] += add;
            __syncthreads();
        }
        int carry = carry_s;
        if (i < n) off[i] = carry + tmp[t] - v;   // exclusive
        __syncthreads();
        if (t == 1023) carry_s = carry + tmp[1023];
        __syncthreads();
    }
    if (t == 0) off[n] = carry_s;
}

__global__ __launch_bounds__(256) void csr_scatter(
    const int* __restrict__ ei, int E, int n,
    const int* __restrict__ off, int* __restrict__ cursor, int* __restrict__ csrc)
{
    int e = blockIdx.x * blockDim.x + threadIdx.x;
    if (e >= E + n) return;
    int s, d;
    if (e < E) { s = ei[e]; d = ei[E + e]; }
    else       { s = e - E; d = e - E; }
    int pos = off[d] + atomicAdd(&cursor[d], 1);
    csrc[pos] = s;
}

// ---------------- fused GAT aggregation: one 64-lane wave per destination node ----------------
// pass A: segment max of leaky(ssrc[src]+sdst[node]); pass B: exp-sum + weighted gather
// of h rows (float2/lane), then normalize + bias (+relu) and write out once.
__global__ __launch_bounds__(256) void gat_aggregate(
    const int* __restrict__ off, const int* __restrict__ csrc,
    const float* __restrict__ ssrc, const float* __restrict__ sdst,
    const float* __restrict__ h, const float* __restrict__ bias,
    float* __restrict__ out, int n, int relu)
{
    int node = blockIdx.x * 4 + (threadIdx.x >> 6);
    int lane = threadIdx.x & 63;
    if (node >= n) return;
    int p0 = off[node], p1 = off[node + 1];
    float sd = sdst[node];

    // pass A: max over segment (lanes stride the neighbor list)
    float m = -INFINITY;
    for (int p = p0 + lane; p < p1; p += 64) {
        int s = csrc[p];
        float v = ssrc[s] + sd;
        v = (v > 0.f) ? v : NEG_SLOPE * v;
        m = fmaxf(m, v);
    }
#pragma unroll
    for (int o = 32; o; o >>= 1) m = fmaxf(m, __shfl_xor(m, o));

    // pass B: whole wave processes one neighbor at a time
    float2 acc = make_float2(0.f, 0.f);
    float ssum = 0.f;
    for (int p = p0; p < p1; ++p) {
        int s = csrc[p];                       // same addr all lanes -> broadcast
        float v = ssrc[s] + sd;
        v = (v > 0.f) ? v : NEG_SLOPE * v;
        float ex = __expf(v - m);
        ssum += ex;
        float2 hv = ((const float2*)(h + (size_t)s * 128))[lane];
        acc.x = fmaf(ex, hv.x, acc.x);
        acc.y = fmaf(ex, hv.y, acc.y);
    }
    float inv = 1.f / (ssum + 1e-16f);
    float2 bv = ((const float2*)bias)[lane];
    float ox = fmaf(acc.x, inv, bv.x);
    float oy = fmaf(acc.y, inv, bv.y);
    if (relu) { ox = fmaxf(ox, 0.f); oy = fmaxf(oy, 0.f); }
    ((float2*)(out + (size_t)node * 128))[lane] = make_float2(ox, oy);
}

// one wave per node: 40-class fc over [ox|oy|x] + log_softmax
__global__ __launch_bounds__(256) void fc_logsoftmax(
    const float* __restrict__ ox, const float* __restrict__ oy,
    const float* __restrict__ xres,
    const float* __restrict__ fcw, const float* __restrict__ fcb,
    float* __restrict__ out, int n)
{
    __shared__ float rows[4][384];
    int w = threadIdx.x >> 6;
    int lane = threadIdx.x & 63;
    int node = blockIdx.x * 4 + w;
    if (node >= n) node = n - 1;   // duplicate work, identical values
    for (int i = lane; i < 128; i += 64) {
        rows[w][i]       = ox[(size_t)node * 128 + i];
        rows[w][128 + i] = oy[(size_t)node * 128 + i];
        rows[w][256 + i] = xres[(size_t)node * 128 + i];
    }
    __syncthreads();
    float acc;
    if (lane < 40) {
        const float4* wr = (const float4*)(fcw + (size_t)lane * 384);
        const float4* rr = (const float4*)&rows[w][0];
        float a = 0.f;
#pragma unroll 4
        for (int k = 0; k < 96; ++k) {
            float4 rv = rr[k], wv = wr[k];
            a = fmaf(rv.x, wv.x, a); a = fmaf(rv.y, wv.y, a);
            a = fmaf(rv.z, wv.z, a); a = fmaf(rv.w, wv.w, a);
        }
        acc = a + fcb[lane];
    } else {
        acc = -INFINITY;
    }
    float mx = acc;
#pragma unroll
    for (int off = 32; off; off >>= 1) mx = fmaxf(mx, __shfl_xor(mx, off));
    float ex = (lane < 40) ? __expf(acc - mx) : 0.f;
    float sm = ex;
#pragma unroll
    for (int off = 32; off; off >>= 1) sm += __shfl_xor(sm, off);
    if (lane < 40) out[(size_t)node * 40 + lane] = acc - mx - logf(sm);
}

// ---------------- host-side helpers ----------------

static void build_csr(const int* ei, int E, int N,
                      int* cnt, int* off, int* csrc, hipStream_t stream)
{
    int ET = E + N;
    hipMemsetAsync(cnt, 0, (size_t)N * sizeof(int), stream);
    hist_k<<<(ET + 255) / 256, 256, 0, stream>>>(ei, E, N, cnt);
    exscan_k<<<1, 1024, 0, stream>>>(cnt, off, N);
    hipMemsetAsync(cnt, 0, (size_t)N * sizeof(int), stream);  // reuse as cursor
    csr_scatter<<<(ET + 255) / 256, 256, 0, stream>>>(ei, E, N, off, cnt, csrc);
}

static void gat_layer(const float* f, const float* Wg,
                      const float* asrc_w, const float* adst_w, const float* bias,
                      const int* off, const int* csrc, int N, int relu,
                      float* hbuf, float* outbuf, float* ssrc, float* sdst,
                      hipStream_t stream)
{
    gemm_nt<<<(N + 31) / 32, 256, 0, stream>>>(f, Wg, nullptr, asrc_w, adst_w, hbuf, ssrc, sdst, N);
    gat_aggregate<<<(N + 3) / 4, 256, 0, stream>>>(off, csrc, ssrc, sdst, hbuf, bias, outbuf, N, relu);
}

extern "C" void kernel_launch(void* const* d_in, const int* in_sizes, int n_in,
                              void* d_out, int out_size, void* d_ws, size_t ws_size,
                              hipStream_t stream)
{
    const float* x    = (const float*)d_in[0];
    const float* y    = (const float*)d_in[1];
    const int*   eix  = (const int*)d_in[2];
    const int*   eiy  = (const int*)d_in[3];
    const float* a1iw = (const float*)d_in[4];
    const float* a1ib = (const float*)d_in[5];
    const float* a1ow = (const float*)d_in[6];
    const float* a1ob = (const float*)d_in[7];
    const float* a2iw = (const float*)d_in[8];
    const float* a2ib = (const float*)d_in[9];
    const float* a2ow = (const float*)d_in[10];
    const float* a2ob = (const float*)d_in[11];
    const float* g1w  = (const float*)d_in[12];
    const float* g1as = (const float*)d_in[13];
    const float* g1ad = (const float*)d_in[14];
    const float* g1b  = (const float*)d_in[15];
    const float* g2xw = (const float*)d_in[16];
    const float* g2xas= (const float*)d_in[17];
    const float* g2xad= (const float*)d_in[18];
    const float* g2xb = (const float*)d_in[19];
    const float* g2yw = (const float*)d_in[20];
    const float* g2yas= (const float*)d_in[21];
    const float* g2yad= (const float*)d_in[22];
    const float* g2yb = (const float*)d_in[23];
    const float* fcw  = (const float*)d_in[24];
    const float* fcb  = (const float*)d_in[25];
    float* outp = (float*)d_out;

    const int N = in_sizes[0] / 128;
    const int E = in_sizes[2] / 2;
    (void)n_in; (void)out_size; (void)ws_size;

    float* ws = (float*)d_ws;
    size_t NF = (size_t)N * 128;
    float* A    = ws;            // xa / oy
    float* B    = A + NF;        // h scratch
    float* C    = B + NF;        // hx / hy
    float* D    = C + NF;        // ox
    float* ssrc = D + NF;
    float* sdst = ssrc + N;
    float* cw1  = sdst + N;
    float* cb1  = cw1 + 128 * 128;
    float* cw2  = cb1 + 128;
    float* cb2  = cw2 + 128 * 128;
    int*   off  = (int*)(cb2 + 128);      // N+1
    int*   cnt  = off + (N + 1);          // N (histogram, then cursor)
    int*   csrc = cnt + N;                // E+N

    mha_combine<<<64, 256, 0, stream>>>(a1iw, a1ib, a1ow, a1ob, cw1, cb1);
    mha_combine<<<64, 256, 0, stream>>>(a2iw, a2ib, a2ow, a2ob, cw2, cb2);

    int gblocks = (N + 31) / 32;

    // ---- x path ----
    build_csr(eix, E, N, cnt, off, csrc, stream);
    gemm_nt<<<gblocks, 256, 0, stream>>>(x, cw1, cb1, nullptr, nullptr, A, nullptr, nullptr, N);
    gat_layer(A, g1w,  g1as,  g1ad,  g1b,  off, csrc, N, 1, B, C, ssrc, sdst, stream);
    gat_layer(C, g2xw, g2xas, g2xad, g2xb, off, csrc, N, 0, B, D, ssrc, sdst, stream);

    // ---- y path (reuse CSR buffers) ----
    build_csr(eiy, E, N, cnt, off, csrc, stream);
    gemm_nt<<<gblocks, 256, 0, stream>>>(y, cw2, cb2, nullptr, nullptr, A, nullptr, nullptr, N);
    gat_layer(A, g1w,  g1as,  g1ad,  g1b,  off, csrc, N, 1, B, C, ssrc, sdst, stream);
    gat_layer(C, g2yw, g2yas, g2yad, g2yb, off, csrc, N, 0, B, A, ssrc, sdst, stream);

    // ---- fusion fc + log_softmax ----
    fc_logsoftmax<<<(N + 3) / 4, 256, 0, stream>>>(D, A, x, fcw, fcb, outp, N);
}

// Round 3
// 896.811 us; speedup vs baseline: 4.2823x; 1.5247x over previous
//
#include <hip/hip_runtime.h>
#include <hip/hip_bf16.h>

#define NEG_SLOPE 0.2f

// combW[o][i] = sum_k out_w[o][k]*in_w[256+k][i] ; combb[o] = out_b[o] + sum_k out_w[o][k]*in_b[256+k]
__global__ __launch_bounds__(256) void mha_combine(
    const float* __restrict__ in_w, const float* __restrict__ in_b,
    const float* __restrict__ out_w, const float* __restrict__ out_b,
    float* __restrict__ combW, float* __restrict__ combb)
{
    int idx = blockIdx.x * blockDim.x + threadIdx.x;
    if (idx >= 128 * 128) return;
    int o = idx >> 7, i = idx & 127;
    float a = 0.f;
    for (int k = 0; k < 128; ++k)
        a = fmaf(out_w[o * 128 + k], in_w[(256 + k) * 128 + i], a);
    combW[idx] = a;
    if (i == 0) {
        float b = out_b[o];
        for (int k = 0; k < 128; ++k)
            b = fmaf(out_w[o * 128 + k], in_b[256 + k], b);
        combb[o] = b;
    }
}

// out[n][o] = sum_k A[n][k] * W[o][k]  (+bias[o]); optional epilogue:
// ssrc[n] = sum_o out[n][o]*asrc[o], sdst likewise.
__global__ __launch_bounds__(256) void gemm_nt(
    const float* __restrict__ A, const float* __restrict__ W,
    const float* __restrict__ bias,
    const float* __restrict__ asrc, const float* __restrict__ adst,
    float* __restrict__ out, float* __restrict__ ssrc, float* __restrict__ sdst,
    int n)
{
    __shared__ float Wt[64 * 132];   // Wt[kk][o], padded stride 132
    __shared__ float xs[32 * 128];
    const int t = threadIdx.x;
    const int row0 = blockIdx.x * 32;

    for (int i = t; i < 32 * 32; i += 256) {          // 1024 float4
        int r = i >> 5, c4 = i & 31;
        int gr = row0 + r;
        float4 v = (gr < n) ? ((const float4*)A)[(size_t)gr * 32 + c4]
                            : make_float4(0.f, 0.f, 0.f, 0.f);
        ((float4*)xs)[i] = v;
    }

    const int co = (t & 31) * 4;        // col base (0..124)
    const int rbase = (t >> 5) * 4;     // row base within tile (0..28)
    float4 acc[4];
#pragma unroll
    for (int j = 0; j < 4; ++j) acc[j] = make_float4(0.f, 0.f, 0.f, 0.f);

    for (int half = 0; half < 2; ++half) {
        const int kbase = half * 64;
        __syncthreads();
        for (int i = t; i < 64 * 128; i += 256) {     // load W^T slice
            int o = i >> 6, kk = i & 63;
            Wt[kk * 132 + o] = W[o * 128 + kbase + kk];
        }
        __syncthreads();
#pragma unroll 4
        for (int k4 = 0; k4 < 16; ++k4) {
            float4 xv[4];
#pragma unroll
            for (int j = 0; j < 4; ++j)
                xv[j] = ((const float4*)xs)[(rbase + j) * 32 + (kbase >> 2) + k4];
#pragma unroll
            for (int kk = 0; kk < 4; ++kk) {
                float4 w = *(const float4*)&Wt[(k4 * 4 + kk) * 132 + co];
#pragma unroll
                for (int j = 0; j < 4; ++j) {
                    float xb = (&xv[j].x)[kk];
                    acc[j].x = fmaf(xb, w.x, acc[j].x);
                    acc[j].y = fmaf(xb, w.y, acc[j].y);
                    acc[j].z = fmaf(xb, w.z, acc[j].z);
                    acc[j].w = fmaf(xb, w.w, acc[j].w);
                }
            }
        }
    }

    float4 bv = make_float4(0.f, 0.f, 0.f, 0.f);
    if (bias) bv = *(const float4*)&bias[co];
#pragma unroll
    for (int j = 0; j < 4; ++j) {
        int r = row0 + rbase + j;
        if (r < n) {
            float4 v = acc[j];
            v.x += bv.x; v.y += bv.y; v.z += bv.z; v.w += bv.w;
            ((float4*)out)[(size_t)r * 32 + (t & 31)] = v;
        }
    }

    if (asrc != nullptr) {
        float4 as = *(const float4*)&asrc[co];
        float4 ad = *(const float4*)&adst[co];
#pragma unroll
        for (int j = 0; j < 4; ++j) {
            float ps = acc[j].x * as.x + acc[j].y * as.y + acc[j].z * as.z + acc[j].w * as.w;
            float pd = acc[j].x * ad.x + acc[j].y * ad.y + acc[j].z * ad.z + acc[j].w * ad.w;
#pragma unroll
            for (int off = 16; off; off >>= 1) {
                ps += __shfl_xor(ps, off);
                pd += __shfl_xor(pd, off);
            }
            if ((t & 31) == 0) {
                int r = row0 + rbase + j;
                if (r < n) { ssrc[r] = ps; sdst[r] = pd; }
            }
        }
    }
}

// ---------------- CSR build (counting sort by dst, incl. self loops) ----------------

__global__ __launch_bounds__(256) void hist_k(
    const int* __restrict__ ei, int E, int n, int* __restrict__ cnt)
{
    int e = blockIdx.x * blockDim.x + threadIdx.x;
    if (e >= E + n) return;
    int d = (e < E) ? ei[E + e] : (e - E);
    atomicAdd(&cnt[d], 1);
}

// 3-kernel exclusive scan over n ints (1024 elems per block)
__global__ __launch_bounds__(256) void scan1(
    const int* __restrict__ cnt, int n, int* __restrict__ bsum)
{
    __shared__ int ws[256];
    int t = threadIdx.x;
    int i = blockIdx.x * 1024 + t * 4;
    int s = 0;
    if (i + 3 < n) { int4 v = *(const int4*)&cnt[i]; s = v.x + v.y + v.z + v.w; }
    else {
        for (int j = 0; j < 4; ++j) if (i + j < n) s += cnt[i + j];
    }
    ws[t] = s; __syncthreads();
    for (int o = 128; o; o >>= 1) { if (t < o) ws[t] += ws[t + o]; __syncthreads(); }
    if (t == 0) bsum[blockIdx.x] = ws[0];
}

__global__ void scan2(int* __restrict__ bsum, int nb, int* __restrict__ total_out)
{
    if (threadIdx.x == 0 && blockIdx.x == 0) {
        int run = 0;
        for (int i = 0; i < nb; ++i) { int v = bsum[i]; bsum[i] = run; run += v; }
        *total_out = run;
    }
}

__global__ __launch_bounds__(256) void scan3(
    const int* __restrict__ cnt, int n,
    const int* __restrict__ bsum, int* __restrict__ off)
{
    __shared__ int ws[256];
    int t = threadIdx.x;
    int i = blockIdx.x * 1024 + t * 4;
    int4 v = make_int4(0, 0, 0, 0);
    if (i + 3 < n) v = *(const int4*)&cnt[i];
    else {
        if (i     < n) v.x = cnt[i];
        if (i + 1 < n) v.y = cnt[i + 1];
        if (i + 2 < n) v.z = cnt[i + 2];
        if (i + 3 < n) v.w = cnt[i + 3];
    }
    int s = v.x + v.y + v.z + v.w;
    ws[t] = s; __syncthreads();
    for (int o = 1; o < 256; o <<= 1) {
        int a = (t >= o) ? ws[t - o] : 0;
        __syncthreads();
        ws[t] += a;
        __syncthreads();
    }
    int excl = ws[t] - s + bsum[blockIdx.x];
    if (i     < n) off[i]     = excl;
    if (i + 1 < n) off[i + 1] = excl + v.x;
    if (i + 2 < n) off[i + 2] = excl + v.x + v.y;
    if (i + 3 < n) off[i + 3] = excl + v.x + v.y + v.z;
}

__global__ __launch_bounds__(256) void csr_scatter(
    const int* __restrict__ ei, int E, int n,
    const int* __restrict__ off, int* __restrict__ cursor, int* __restrict__ csrc)
{
    int e = blockIdx.x * blockDim.x + threadIdx.x;
    if (e >= E + n) return;
    int s, d;
    if (e < E) { s = ei[e]; d = ei[E + e]; }
    else       { s = e - E; d = e - E; }
    int pos = off[d] + atomicAdd(&cursor[d], 1);
    csrc[pos] = s;
}

// ---------------- fused GAT aggregation: one 64-lane wave per destination node ----------------
__global__ __launch_bounds__(256) void gat_aggregate(
    const int* __restrict__ off, const int* __restrict__ csrc,
    const float* __restrict__ ssrc, const float* __restrict__ sdst,
    const float* __restrict__ h, const float* __restrict__ bias,
    float* __restrict__ out, int n, int relu)
{
    int node = blockIdx.x * 4 + (threadIdx.x >> 6);
    int lane = threadIdx.x & 63;
    if (node >= n) return;
    int p0 = off[node], p1 = off[node + 1];
    float sd = sdst[node];

    // pass A: max over segment (lanes stride the neighbor list)
    float m = -INFINITY;
    for (int p = p0 + lane; p < p1; p += 64) {
        int s = csrc[p];
        float v = ssrc[s] + sd;
        v = (v > 0.f) ? v : NEG_SLOPE * v;
        m = fmaxf(m, v);
    }
#pragma unroll
    for (int o = 32; o; o >>= 1) m = fmaxf(m, __shfl_xor(m, o));

    // pass B: whole wave processes one neighbor at a time
    float2 acc = make_float2(0.f, 0.f);
    float ssum = 0.f;
    for (int p = p0; p < p1; ++p) {
        int s = csrc[p];                       // same addr all lanes -> broadcast
        float v = ssrc[s] + sd;
        v = (v > 0.f) ? v : NEG_SLOPE * v;
        float ex = __expf(v - m);
        ssum += ex;
        float2 hv = ((const float2*)(h + (size_t)s * 128))[lane];
        acc.x = fmaf(ex, hv.x, acc.x);
        acc.y = fmaf(ex, hv.y, acc.y);
    }
    float inv = 1.f / (ssum + 1e-16f);
    float2 bv = ((const float2*)bias)[lane];
    float ox = fmaf(acc.x, inv, bv.x);
    float oy = fmaf(acc.y, inv, bv.y);
    if (relu) { ox = fmaxf(ox, 0.f); oy = fmaxf(oy, 0.f); }
    ((float2*)(out + (size_t)node * 128))[lane] = make_float2(ox, oy);
}

// ---------------- fused fc + log_softmax: 64 nodes/block, LDS-staged GEMM ----------------
// thread t: rows (t>>3)*2, (t>>3)*2+1 ; classes (t&7)*5 .. +4
__global__ __launch_bounds__(256) void fc_logsoftmax(
    const float* __restrict__ ox, const float* __restrict__ oy,
    const float* __restrict__ xres,
    const float* __restrict__ fcw, const float* __restrict__ fcb,
    float* __restrict__ out, int n)
{
    __shared__ float xs[64 * 132];   // [row][k] padded
    __shared__ float wt[40 * 132];   // [class][k] padded
    const int t = threadIdx.x;
    const int node0 = blockIdx.x * 64;
    const int r0 = (t >> 3) * 2;
    const int c0 = (t & 7) * 5;

    float acc0[5] = {0.f, 0.f, 0.f, 0.f, 0.f};
    float acc1[5] = {0.f, 0.f, 0.f, 0.f, 0.f};

    const float* srcs[3] = {ox, oy, xres};
    for (int kc = 0; kc < 3; ++kc) {
        const float* S = srcs[kc];
        __syncthreads();
        for (int i = t; i < 64 * 32; i += 256) {      // x tile: 2048 float4
            int rr = i >> 5, c4 = i & 31;
            int gr = node0 + rr; if (gr >= n) gr = n - 1;
            float4 v = ((const float4*)S)[(size_t)gr * 32 + c4];
            *(float4*)&xs[rr * 132 + c4 * 4] = v;
        }
        for (int i = t; i < 40 * 32; i += 256) {      // w tile: 1280 float4
            int cc = i >> 5, c4 = i & 31;
            float4 v = ((const float4*)fcw)[(size_t)cc * 96 + kc * 32 + c4];
            *(float4*)&wt[cc * 132 + c4 * 4] = v;
        }
        __syncthreads();
#pragma unroll 8
        for (int k4 = 0; k4 < 32; ++k4) {
            float4 x0 = *(const float4*)&xs[r0 * 132 + k4 * 4];
            float4 x1 = *(const float4*)&xs[(r0 + 1) * 132 + k4 * 4];
#pragma unroll
            for (int j = 0; j < 5; ++j) {
                float4 wv = *(const float4*)&wt[(c0 + j) * 132 + k4 * 4];
                acc0[j] = fmaf(x0.x, wv.x, acc0[j]);
                acc0[j] = fmaf(x0.y, wv.y, acc0[j]);
                acc0[j] = fmaf(x0.z, wv.z, acc0[j]);
                acc0[j] = fmaf(x0.w, wv.w, acc0[j]);
                acc1[j] = fmaf(x1.x, wv.x, acc1[j]);
                acc1[j] = fmaf(x1.y, wv.y, acc1[j]);
                acc1[j] = fmaf(x1.z, wv.z, acc1[j]);
                acc1[j] = fmaf(x1.w, wv.w, acc1[j]);
            }
        }
    }

#pragma unroll
    for (int j = 0; j < 5; ++j) {
        float b = fcb[c0 + j];
        acc0[j] += b; acc1[j] += b;
    }

    // per-row log-softmax: reduce over the 8 class-group lanes (xor 1,2,4)
    float m0 = acc0[0], m1 = acc1[0];
#pragma unroll
    for (int j = 1; j < 5; ++j) { m0 = fmaxf(m0, acc0[j]); m1 = fmaxf(m1, acc1[j]); }
#pragma unroll
    for (int o = 1; o < 8; o <<= 1) {
        m0 = fmaxf(m0, __shfl_xor(m0, o));
        m1 = fmaxf(m1, __shfl_xor(m1, o));
    }
    float s0 = 0.f, s1 = 0.f;
#pragma unroll
    for (int j = 0; j < 5; ++j) { s0 += __expf(acc0[j] - m0); s1 += __expf(acc1[j] - m1); }
#pragma unroll
    for (int o = 1; o < 8; o <<= 1) {
        s0 += __shfl_xor(s0, o);
        s1 += __shfl_xor(s1, o);
    }
    float lse0 = m0 + logf(s0), lse1 = m1 + logf(s1);

    int g0 = node0 + r0, g1 = node0 + r0 + 1;
    if (g0 >= n) g0 = n - 1;
    if (g1 >= n) g1 = n - 1;
#pragma unroll
    for (int j = 0; j < 5; ++j) {
        out[(size_t)g0 * 40 + c0 + j] = acc0[j] - lse0;
        out[(size_t)g1 * 40 + c0 + j] = acc1[j] - lse1;
    }
}

// ---------------- host-side helpers ----------------

static void build_csr(const int* ei, int E, int N,
                      int* cnt, int* off, int* csrc, int* bsum, hipStream_t stream)
{
    int ET = E + N;
    int nb = (N + 1023) / 1024;
    hipMemsetAsync(cnt, 0, (size_t)N * sizeof(int), stream);
    hist_k<<<(ET + 255) / 256, 256, 0, stream>>>(ei, E, N, cnt);
    scan1<<<nb, 256, 0, stream>>>(cnt, N, bsum);
    scan2<<<1, 64, 0, stream>>>(bsum, nb, off + N);
    scan3<<<nb, 256, 0, stream>>>(cnt, N, bsum, off);
    hipMemsetAsync(cnt, 0, (size_t)N * sizeof(int), stream);  // reuse as cursor
    csr_scatter<<<(ET + 255) / 256, 256, 0, stream>>>(ei, E, N, off, cnt, csrc);
}

static void gat_layer(const float* f, const float* Wg,
                      const float* asrc_w, const float* adst_w, const float* bias,
                      const int* off, const int* csrc, int N, int relu,
                      float* hbuf, float* outbuf, float* ssrc, float* sdst,
                      hipStream_t stream)
{
    gemm_nt<<<(N + 31) / 32, 256, 0, stream>>>(f, Wg, nullptr, asrc_w, adst_w, hbuf, ssrc, sdst, N);
    gat_aggregate<<<(N + 3) / 4, 256, 0, stream>>>(off, csrc, ssrc, sdst, hbuf, bias, outbuf, N, relu);
}

extern "C" void kernel_launch(void* const* d_in, const int* in_sizes, int n_in,
                              void* d_out, int out_size, void* d_ws, size_t ws_size,
                              hipStream_t stream)
{
    const float* x    = (const float*)d_in[0];
    const float* y    = (const float*)d_in[1];
    const int*   eix  = (const int*)d_in[2];
    const int*   eiy  = (const int*)d_in[3];
    const float* a1iw = (const float*)d_in[4];
    const float* a1ib = (const float*)d_in[5];
    const float* a1ow = (const float*)d_in[6];
    const float* a1ob = (const float*)d_in[7];
    const float* a2iw = (const float*)d_in[8];
    const float* a2ib = (const float*)d_in[9];
    const float* a2ow = (const float*)d_in[10];
    const float* a2ob = (const float*)d_in[11];
    const float* g1w  = (const float*)d_in[12];
    const float* g1as = (const float*)d_in[13];
    const float* g1ad = (const float*)d_in[14];
    const float* g1b  = (const float*)d_in[15];
    const float* g2xw = (const float*)d_in[16];
    const float* g2xas= (const float*)d_in[17];
    const float* g2xad= (const float*)d_in[18];
    const float* g2xb = (const float*)d_in[19];
    const float* g2yw = (const float*)d_in[20];
    const float* g2yas= (const float*)d_in[21];
    const float* g2yad= (const float*)d_in[22];
    const float* g2yb = (const float*)d_in[23];
    const float* fcw  = (const float*)d_in[24];
    const float* fcb  = (const float*)d_in[25];
    float* outp = (float*)d_out;

    const int N = in_sizes[0] / 128;
    const int E = in_sizes[2] / 2;
    (void)n_in; (void)out_size; (void)ws_size;

    float* ws = (float*)d_ws;
    size_t NF = (size_t)N * 128;
    float* A    = ws;            // xa / oy
    float* B    = A + NF;        // h scratch
    float* C    = B + NF;        // hx / hy
    float* D    = C + NF;        // ox
    float* ssrc = D + NF;
    float* sdst = ssrc + N;
    float* cw1  = sdst + N;
    float* cb1  = cw1 + 128 * 128;
    float* cw2  = cb1 + 128;
    float* cb2  = cw2 + 128 * 128;
    int*   off  = (int*)(cb2 + 128);          // N+1
    int*   cnt  = off + ((N + 4) & ~3);       // N  (16B-aligned for int4)
    int*   bsum = cnt + ((N + 4) & ~3);       // ceil(N/1024)
    int*   csrc = bsum + 1024;                // E+N

    mha_combine<<<64, 256, 0, stream>>>(a1iw, a1ib, a1ow, a1ob, cw1, cb1);
    mha_combine<<<64, 256, 0, stream>>>(a2iw, a2ib, a2ow, a2ob, cw2, cb2);

    int gblocks = (N + 31) / 32;

    // ---- x path ----
    build_csr(eix, E, N, cnt, off, csrc, bsum, stream);
    gemm_nt<<<gblocks, 256, 0, stream>>>(x, cw1, cb1, nullptr, nullptr, A, nullptr, nullptr, N);
    gat_layer(A, g1w,  g1as,  g1ad,  g1b,  off, csrc, N, 1, B, C, ssrc, sdst, stream);
    gat_layer(C, g2xw, g2xas, g2xad, g2xb, off, csrc, N, 0, B, D, ssrc, sdst, stream);

    // ---- y path (reuse CSR buffers) ----
    build_csr(eiy, E, N, cnt, off, csrc, bsum, stream);
    gemm_nt<<<gblocks, 256, 0, stream>>>(y, cw2, cb2, nullptr, nullptr, A, nullptr, nullptr, N);
    gat_layer(A, g1w,  g1as,  g1ad,  g1b,  off, csrc, N, 1, B, C, ssrc, sdst, stream);
    gat_layer(C, g2yw, g2yas, g2yad, g2yb, off, csrc, N, 0, B, A, ssrc, sdst, stream);

    // ---- fusion fc + log_softmax ----
    fc_logsoftmax<<<(N + 63) / 64, 256, 0, stream>>>(D, A, x, fcw, fcb, outp, N);
}

// Round 4
// 675.160 us; speedup vs baseline: 5.6881x; 1.3283x over previous
//
#include <hip/hip_runtime.h>
#include <hip/hip_bf16.h>

#define NEG_SLOPE 0.2f

static __device__ __forceinline__ unsigned pkbf(float a, float b) {
    unsigned ua = __float_as_uint(a);
    ua = (ua + 0x7FFFu + ((ua >> 16) & 1u)) >> 16;
    unsigned ub = __float_as_uint(b);
    ub = (ub + 0x7FFFu + ((ub >> 16) & 1u)) & 0xFFFF0000u;
    return (ua & 0xFFFFu) | ub;
}
static __device__ __forceinline__ float bflo(unsigned u) { return __uint_as_float(u << 16); }
static __device__ __forceinline__ float bfhi(unsigned u) { return __uint_as_float(u & 0xFFFF0000u); }

// combW[o][i] = sum_k out_w[o][k]*in_w[256+k][i] ; combb[o] = out_b[o] + sum_k out_w[o][k]*in_b[256+k]
__global__ __launch_bounds__(256) void mha_combine(
    const float* __restrict__ in_w, const float* __restrict__ in_b,
    const float* __restrict__ out_w, const float* __restrict__ out_b,
    float* __restrict__ combW, float* __restrict__ combb)
{
    int idx = blockIdx.x * blockDim.x + threadIdx.x;
    if (idx >= 128 * 128) return;
    int o = idx >> 7, i = idx & 127;
    float a = 0.f;
    for (int k = 0; k < 128; ++k)
        a = fmaf(out_w[o * 128 + k], in_w[(256 + k) * 128 + i], a);
    combW[idx] = a;
    if (i == 0) {
        float b = out_b[o];
        for (int k = 0; k < 128; ++k)
            b = fmaf(out_w[o * 128 + k], in_b[256 + k], b);
        combb[o] = b;
    }
}

// out[n][o] = sum_k A[n][k] * W[o][k]  (+bias[o]).
// Optional: f32 store to `out`, packed-bf16 store to `hb`, and
// ssrc[n]=sum_o out[n][o]*asrc[o] / sdst likewise.
__global__ __launch_bounds__(256) void gemm_nt(
    const float* __restrict__ A, const float* __restrict__ W,
    const float* __restrict__ bias,
    const float* __restrict__ asrc, const float* __restrict__ adst,
    float* __restrict__ out, unsigned* __restrict__ hb,
    float* __restrict__ ssrc, float* __restrict__ sdst,
    int n)
{
    __shared__ float Wt[64 * 132];   // Wt[kk][o], padded stride 132
    __shared__ float xs[32 * 128];
    const int t = threadIdx.x;
    const int row0 = blockIdx.x * 32;

    for (int i = t; i < 32 * 32; i += 256) {          // 1024 float4
        int r = i >> 5, c4 = i & 31;
        int gr = row0 + r;
        float4 v = (gr < n) ? ((const float4*)A)[(size_t)gr * 32 + c4]
                            : make_float4(0.f, 0.f, 0.f, 0.f);
        ((float4*)xs)[i] = v;
    }

    const int co = (t & 31) * 4;        // col base (0..124)
    const int rbase = (t >> 5) * 4;     // row base within tile (0..28)
    float4 acc[4];
#pragma unroll
    for (int j = 0; j < 4; ++j) acc[j] = make_float4(0.f, 0.f, 0.f, 0.f);

    for (int half = 0; half < 2; ++half) {
        const int kbase = half * 64;
        __syncthreads();
        for (int i = t; i < 64 * 128; i += 256) {     // load W^T slice
            int o = i >> 6, kk = i & 63;
            Wt[kk * 132 + o] = W[o * 128 + kbase + kk];
        }
        __syncthreads();
#pragma unroll 4
        for (int k4 = 0; k4 < 16; ++k4) {
            float4 xv[4];
#pragma unroll
            for (int j = 0; j < 4; ++j)
                xv[j] = ((const float4*)xs)[(rbase + j) * 32 + (kbase >> 2) + k4];
#pragma unroll
            for (int kk = 0; kk < 4; ++kk) {
                float4 w = *(const float4*)&Wt[(k4 * 4 + kk) * 132 + co];
#pragma unroll
                for (int j = 0; j < 4; ++j) {
                    float xb = (&xv[j].x)[kk];
                    acc[j].x = fmaf(xb, w.x, acc[j].x);
                    acc[j].y = fmaf(xb, w.y, acc[j].y);
                    acc[j].z = fmaf(xb, w.z, acc[j].z);
                    acc[j].w = fmaf(xb, w.w, acc[j].w);
                }
            }
        }
    }

    float4 bv = make_float4(0.f, 0.f, 0.f, 0.f);
    if (bias) bv = *(const float4*)&bias[co];
#pragma unroll
    for (int j = 0; j < 4; ++j) {
        acc[j].x += bv.x; acc[j].y += bv.y; acc[j].z += bv.z; acc[j].w += bv.w;
    }

    if (out) {
#pragma unroll
        for (int j = 0; j < 4; ++j) {
            int r = row0 + rbase + j;
            if (r < n) ((float4*)out)[(size_t)r * 32 + (t & 31)] = acc[j];
        }
    }
    if (hb) {
#pragma unroll
        for (int j = 0; j < 4; ++j) {
            int r = row0 + rbase + j;
            if (r < n) {
                uint2 p = make_uint2(pkbf(acc[j].x, acc[j].y), pkbf(acc[j].z, acc[j].w));
                *(uint2*)&hb[(size_t)r * 64 + (t & 31) * 2] = p;
            }
        }
    }

    if (asrc != nullptr) {
        float4 as = *(const float4*)&asrc[co];
        float4 ad = *(const float4*)&adst[co];
#pragma unroll
        for (int j = 0; j < 4; ++j) {
            float ps = acc[j].x * as.x + acc[j].y * as.y + acc[j].z * as.z + acc[j].w * as.w;
            float pd = acc[j].x * ad.x + acc[j].y * ad.y + acc[j].z * ad.z + acc[j].w * ad.w;
#pragma unroll
            for (int off = 16; off; off >>= 1) {
                ps += __shfl_xor(ps, off);
                pd += __shfl_xor(pd, off);
            }
            if ((t & 31) == 0) {
                int r = row0 + rbase + j;
                if (r < n) { ssrc[r] = ps; sdst[r] = pd; }
            }
        }
    }
}

// ---------------- CSR build (counting sort by dst, incl. self loops) ----------------

__global__ __launch_bounds__(256) void hist_k(
    const int* __restrict__ ei, int E, int n, int* __restrict__ cnt)
{
    int e = blockIdx.x * blockDim.x + threadIdx.x;
    if (e >= E + n) return;
    int d = (e < E) ? ei[E + e] : (e - E);
    atomicAdd(&cnt[d], 1);
}

// 3-kernel exclusive scan over n ints (1024 elems per block)
__global__ __launch_bounds__(256) void scan1(
    const int* __restrict__ cnt, int n, int* __restrict__ bsum)
{
    __shared__ int ws[256];
    int t = threadIdx.x;
    int i = blockIdx.x * 1024 + t * 4;
    int s = 0;
    if (i + 3 < n) { int4 v = *(const int4*)&cnt[i]; s = v.x + v.y + v.z + v.w; }
    else {
        for (int j = 0; j < 4; ++j) if (i + j < n) s += cnt[i + j];
    }
    ws[t] = s; __syncthreads();
    for (int o = 128; o; o >>= 1) { if (t < o) ws[t] += ws[t + o]; __syncthreads(); }
    if (t == 0) bsum[blockIdx.x] = ws[0];
}

__global__ void scan2(int* __restrict__ bsum, int nb, int* __restrict__ total_out)
{
    if (threadIdx.x == 0 && blockIdx.x == 0) {
        int run = 0;
        for (int i = 0; i < nb; ++i) { int v = bsum[i]; bsum[i] = run; run += v; }
        *total_out = run;
    }
}

__global__ __launch_bounds__(256) void scan3(
    const int* __restrict__ cnt, int n,
    const int* __restrict__ bsum, int* __restrict__ off)
{
    __shared__ int ws[256];
    int t = threadIdx.x;
    int i = blockIdx.x * 1024 + t * 4;
    int4 v = make_int4(0, 0, 0, 0);
    if (i + 3 < n) v = *(const int4*)&cnt[i];
    else {
        if (i     < n) v.x = cnt[i];
        if (i + 1 < n) v.y = cnt[i + 1];
        if (i + 2 < n) v.z = cnt[i + 2];
        if (i + 3 < n) v.w = cnt[i + 3];
    }
    int s = v.x + v.y + v.z + v.w;
    ws[t] = s; __syncthreads();
    for (int o = 1; o < 256; o <<= 1) {
        int a = (t >= o) ? ws[t - o] : 0;
        __syncthreads();
        ws[t] += a;
        __syncthreads();
    }
    int excl = ws[t] - s + bsum[blockIdx.x];
    if (i     < n) off[i]     = excl;
    if (i + 1 < n) off[i + 1] = excl + v.x;
    if (i + 2 < n) off[i + 2] = excl + v.x + v.y;
    if (i + 3 < n) off[i + 3] = excl + v.x + v.y + v.z;
}

__global__ __launch_bounds__(256) void csr_scatter(
    const int* __restrict__ ei, int E, int n,
    const int* __restrict__ off, int* __restrict__ cursor, int* __restrict__ csrc)
{
    int e = blockIdx.x * blockDim.x + threadIdx.x;
    if (e >= E + n) return;
    int s, d;
    if (e < E) { s = ei[e]; d = ei[E + e]; }
    else       { s = e - E; d = e - E; }
    int pos = off[d] + atomicAdd(&cursor[d], 1);
    csrc[pos] = s;
}

// ---------------- fused GAT aggregation: one 64-lane wave per destination node ----------------
// pass A: each lane owns one neighbor (deg<=64 fast path): load src+logit+exp once into regs.
// pass B: shfl-broadcast (src, ex) from lane j; gather bf16 h row (4 B/lane), unroll x4.
__global__ __launch_bounds__(256) void gat_aggregate(
    const int* __restrict__ off, const int* __restrict__ csrc,
    const float* __restrict__ ssrc, const float* __restrict__ sdst,
    const unsigned* __restrict__ hb, const float* __restrict__ bias,
    float* __restrict__ out, int n, int relu)
{
    int node = blockIdx.x * 4 + (threadIdx.x >> 6);
    int lane = threadIdx.x & 63;
    if (node >= n) return;
    int p0 = off[node], p1 = off[node + 1];
    int deg = p1 - p0;
    float sd = sdst[node];

    int mysrc = 0; float myv = -INFINITY;
    if (lane < deg) {
        mysrc = csrc[p0 + lane];
        float v = ssrc[mysrc] + sd;
        myv = (v > 0.f) ? v : NEG_SLOPE * v;
    }
    float m = myv;
    for (int p = p0 + 64 + lane; p < p1; p += 64) {   // rare deg>64 overflow
        int s = csrc[p];
        float v = ssrc[s] + sd;
        v = (v > 0.f) ? v : NEG_SLOPE * v;
        m = fmaxf(m, v);
    }
#pragma unroll
    for (int o = 32; o; o >>= 1) m = fmaxf(m, __shfl_xor(m, o));

    float myex = (lane < deg) ? __expf(myv - m) : 0.f;
    float part = myex;
    for (int p = p0 + 64 + lane; p < p1; p += 64) {
        int s = csrc[p];
        float v = ssrc[s] + sd;
        v = (v > 0.f) ? v : NEG_SLOPE * v;
        part += __expf(v - m);
    }
    float ssum = part;
#pragma unroll
    for (int o = 32; o; o >>= 1) ssum += __shfl_xor(ssum, o);

    float ax = 0.f, ay = 0.f;
    int jcap = deg < 64 ? deg : 64;
    int j = 0;
    for (; j + 4 <= jcap; j += 4) {
        int s0 = __shfl(mysrc, j),     s1 = __shfl(mysrc, j + 1);
        int s2 = __shfl(mysrc, j + 2), s3 = __shfl(mysrc, j + 3);
        float e0 = __shfl(myex, j),     e1 = __shfl(myex, j + 1);
        float e2 = __shfl(myex, j + 2), e3 = __shfl(myex, j + 3);
        unsigned u0 = hb[(size_t)s0 * 64 + lane];
        unsigned u1 = hb[(size_t)s1 * 64 + lane];
        unsigned u2 = hb[(size_t)s2 * 64 + lane];
        unsigned u3 = hb[(size_t)s3 * 64 + lane];
        ax = fmaf(e0, bflo(u0), ax); ay = fmaf(e0, bfhi(u0), ay);
        ax = fmaf(e1, bflo(u1), ax); ay = fmaf(e1, bfhi(u1), ay);
        ax = fmaf(e2, bflo(u2), ax); ay = fmaf(e2, bfhi(u2), ay);
        ax = fmaf(e3, bflo(u3), ax); ay = fmaf(e3, bfhi(u3), ay);
    }
    for (; j < jcap; ++j) {
        int s = __shfl(mysrc, j);
        float e = __shfl(myex, j);
        unsigned u = hb[(size_t)s * 64 + lane];
        ax = fmaf(e, bflo(u), ax); ay = fmaf(e, bfhi(u), ay);
    }
    for (int p = p0 + 64; p < p1; ++p) {              // rare deg>64 overflow
        int s = csrc[p];
        float v = ssrc[s] + sd;
        v = (v > 0.f) ? v : NEG_SLOPE * v;
        float e = __expf(v - m);
        unsigned u = hb[(size_t)s * 64 + lane];
        ax = fmaf(e, bflo(u), ax); ay = fmaf(e, bfhi(u), ay);
    }

    float inv = 1.f / (ssum + 1e-16f);
    float2 bv = ((const float2*)bias)[lane];
    float ox = fmaf(ax, inv, bv.x);
    float oy = fmaf(ay, inv, bv.y);
    if (relu) { ox = fmaxf(ox, 0.f); oy = fmaxf(oy, 0.f); }
    ((float2*)(out + (size_t)node * 128))[lane] = make_float2(ox, oy);
}

// ---------------- fused fc + log_softmax: 64 nodes/block, LDS-staged GEMM ----------------
__global__ __launch_bounds__(256) void fc_logsoftmax(
    const float* __restrict__ ox, const float* __restrict__ oy,
    const float* __restrict__ xres,
    const float* __restrict__ fcw, const float* __restrict__ fcb,
    float* __restrict__ out, int n)
{
    __shared__ float xs[64 * 132];   // [row][k] padded
    __shared__ float wt[40 * 132];   // [class][k] padded
    const int t = threadIdx.x;
    const int node0 = blockIdx.x * 64;
    const int r0 = (t >> 3) * 2;
    const int c0 = (t & 7) * 5;

    float acc0[5] = {0.f, 0.f, 0.f, 0.f, 0.f};
    float acc1[5] = {0.f, 0.f, 0.f, 0.f, 0.f};

    const float* srcs[3] = {ox, oy, xres};
    for (int kc = 0; kc < 3; ++kc) {
        const float* S = srcs[kc];
        __syncthreads();
        for (int i = t; i < 64 * 32; i += 256) {      // x tile: 2048 float4
            int rr = i >> 5, c4 = i & 31;
            int gr = node0 + rr; if (gr >= n) gr = n - 1;
            float4 v = ((const float4*)S)[(size_t)gr * 32 + c4];
            *(float4*)&xs[rr * 132 + c4 * 4] = v;
        }
        for (int i = t; i < 40 * 32; i += 256) {      // w tile: 1280 float4
            int cc = i >> 5, c4 = i & 31;
            float4 v = ((const float4*)fcw)[(size_t)cc * 96 + kc * 32 + c4];
            *(float4*)&wt[cc * 132 + c4 * 4] = v;
        }
        __syncthreads();
#pragma unroll 8
        for (int k4 = 0; k4 < 32; ++k4) {
            float4 x0 = *(const float4*)&xs[r0 * 132 + k4 * 4];
            float4 x1 = *(const float4*)&xs[(r0 + 1) * 132 + k4 * 4];
#pragma unroll
            for (int j = 0; j < 5; ++j) {
                float4 wv = *(const float4*)&wt[(c0 + j) * 132 + k4 * 4];
                acc0[j] = fmaf(x0.x, wv.x, acc0[j]);
                acc0[j] = fmaf(x0.y, wv.y, acc0[j]);
                acc0[j] = fmaf(x0.z, wv.z, acc0[j]);
                acc0[j] = fmaf(x0.w, wv.w, acc0[j]);
                acc1[j] = fmaf(x1.x, wv.x, acc1[j]);
                acc1[j] = fmaf(x1.y, wv.y, acc1[j]);
                acc1[j] = fmaf(x1.z, wv.z, acc1[j]);
                acc1[j] = fmaf(x1.w, wv.w, acc1[j]);
            }
        }
    }

#pragma unroll
    for (int j = 0; j < 5; ++j) {
        float b = fcb[c0 + j];
        acc0[j] += b; acc1[j] += b;
    }

    float m0 = acc0[0], m1 = acc1[0];
#pragma unroll
    for (int j = 1; j < 5; ++j) { m0 = fmaxf(m0, acc0[j]); m1 = fmaxf(m1, acc1[j]); }
#pragma unroll
    for (int o = 1; o < 8; o <<= 1) {
        m0 = fmaxf(m0, __shfl_xor(m0, o));
        m1 = fmaxf(m1, __shfl_xor(m1, o));
    }
    float s0 = 0.f, s1 = 0.f;
#pragma unroll
    for (int j = 0; j < 5; ++j) { s0 += __expf(acc0[j] - m0); s1 += __expf(acc1[j] - m1); }
#pragma unroll
    for (int o = 1; o < 8; o <<= 1) {
        s0 += __shfl_xor(s0, o);
        s1 += __shfl_xor(s1, o);
    }
    float lse0 = m0 + logf(s0), lse1 = m1 + logf(s1);

    int g0 = node0 + r0, g1 = node0 + r0 + 1;
    if (g0 >= n) g0 = n - 1;
    if (g1 >= n) g1 = n - 1;
#pragma unroll
    for (int j = 0; j < 5; ++j) {
        out[(size_t)g0 * 40 + c0 + j] = acc0[j] - lse0;
        out[(size_t)g1 * 40 + c0 + j] = acc1[j] - lse1;
    }
}

// ---------------- host-side helpers ----------------

static void build_csr(const int* ei, int E, int N,
                      int* cnt, int* off, int* csrc, int* bsum, hipStream_t stream)
{
    int ET = E + N;
    int nb = (N + 1023) / 1024;
    hipMemsetAsync(cnt, 0, (size_t)N * sizeof(int), stream);
    hist_k<<<(ET + 255) / 256, 256, 0, stream>>>(ei, E, N, cnt);
    scan1<<<nb, 256, 0, stream>>>(cnt, N, bsum);
    scan2<<<1, 64, 0, stream>>>(bsum, nb, off + N);
    scan3<<<nb, 256, 0, stream>>>(cnt, N, bsum, off);
    hipMemsetAsync(cnt, 0, (size_t)N * sizeof(int), stream);  // reuse as cursor
    csr_scatter<<<(ET + 255) / 256, 256, 0, stream>>>(ei, E, N, off, cnt, csrc);
}

static void gat_layer(const float* f, const float* Wg,
                      const float* asrc_w, const float* adst_w, const float* bias,
                      const int* off, const int* csrc, int N, int relu,
                      unsigned* hb, float* outbuf, float* ssrc, float* sdst,
                      hipStream_t stream)
{
    gemm_nt<<<(N + 31) / 32, 256, 0, stream>>>(f, Wg, nullptr, asrc_w, adst_w,
                                               nullptr, hb, ssrc, sdst, N);
    gat_aggregate<<<(N + 3) / 4, 256, 0, stream>>>(off, csrc, ssrc, sdst, hb, bias, outbuf, N, relu);
}

extern "C" void kernel_launch(void* const* d_in, const int* in_sizes, int n_in,
                              void* d_out, int out_size, void* d_ws, size_t ws_size,
                              hipStream_t stream)
{
    const float* x    = (const float*)d_in[0];
    const float* y    = (const float*)d_in[1];
    const int*   eix  = (const int*)d_in[2];
    const int*   eiy  = (const int*)d_in[3];
    const float* a1iw = (const float*)d_in[4];
    const float* a1ib = (const float*)d_in[5];
    const float* a1ow = (const float*)d_in[6];
    const float* a1ob = (const float*)d_in[7];
    const float* a2iw = (const float*)d_in[8];
    const float* a2ib = (const float*)d_in[9];
    const float* a2ow = (const float*)d_in[10];
    const float* a2ob = (const float*)d_in[11];
    const float* g1w  = (const float*)d_in[12];
    const float* g1as = (const float*)d_in[13];
    const float* g1ad = (const float*)d_in[14];
    const float* g1b  = (const float*)d_in[15];
    const float* g2xw = (const float*)d_in[16];
    const float* g2xas= (const float*)d_in[17];
    const float* g2xad= (const float*)d_in[18];
    const float* g2xb = (const float*)d_in[19];
    const float* g2yw = (const float*)d_in[20];
    const float* g2yas= (const float*)d_in[21];
    const float* g2yad= (const float*)d_in[22];
    const float* g2yb = (const float*)d_in[23];
    const float* fcw  = (const float*)d_in[24];
    const float* fcb  = (const float*)d_in[25];
    float* outp = (float*)d_out;

    const int N = in_sizes[0] / 128;
    const int E = in_sizes[2] / 2;
    (void)n_in; (void)out_size; (void)ws_size;

    float* ws = (float*)d_ws;
    size_t NF = (size_t)N * 128;
    float*    A    = ws;                       // xa / ya / oy
    float*    C    = A + NF;                   // hx / hy
    float*    D    = C + NF;                   // ox
    unsigned* hb   = (unsigned*)(D + NF);      // packed bf16 h, N*64 uints
    float*    ssrc = (float*)(hb + (size_t)N * 64);
    float*    sdst = ssrc + N;
    float*    cw1  = sdst + N;
    float*    cb1  = cw1 + 128 * 128;
    float*    cw2  = cb1 + 128;
    float*    cb2  = cw2 + 128 * 128;
    int*      off  = (int*)(cb2 + 128);        // N+1
    int*      cnt  = off + ((N + 4) & ~3);     // N  (16B-aligned for int4)
    int*      bsum = cnt + ((N + 4) & ~3);     // ceil(N/1024)
    int*      csrc = bsum + 1024;              // E+N

    mha_combine<<<64, 256, 0, stream>>>(a1iw, a1ib, a1ow, a1ob, cw1, cb1);
    mha_combine<<<64, 256, 0, stream>>>(a2iw, a2ib, a2ow, a2ob, cw2, cb2);

    int gblocks = (N + 31) / 32;

    // ---- x path ----
    build_csr(eix, E, N, cnt, off, csrc, bsum, stream);
    gemm_nt<<<gblocks, 256, 0, stream>>>(x, cw1, cb1, nullptr, nullptr, A, nullptr, nullptr, nullptr, N);
    gat_layer(A, g1w,  g1as,  g1ad,  g1b,  off, csrc, N, 1, hb, C, ssrc, sdst, stream);
    gat_layer(C, g2xw, g2xas, g2xad, g2xb, off, csrc, N, 0, hb, D, ssrc, sdst, stream);

    // ---- y path (reuse CSR buffers) ----
    build_csr(eiy, E, N, cnt, off, csrc, bsum, stream);
    gemm_nt<<<gblocks, 256, 0, stream>>>(y, cw2, cb2, nullptr, nullptr, A, nullptr, nullptr, nullptr, N);
    gat_layer(A, g1w,  g1as,  g1ad,  g1b,  off, csrc, N, 1, hb, C, ssrc, sdst, stream);
    gat_layer(C, g2yw, g2yas, g2yad, g2yb, off, csrc, N, 0, hb, A, ssrc, sdst, stream);

    // ---- fusion fc + log_softmax ----
    fc_logsoftmax<<<(N + 63) / 64, 256, 0, stream>>>(D, A, x, fcw, fcb, outp, N);
}

// Round 5
// 664.795 us; speedup vs baseline: 5.7768x; 1.0156x over previous
//
#include <hip/hip_runtime.h>
#include <hip/hip_bf16.h>

#define NEG_SLOPE 0.2f

static __device__ __forceinline__ unsigned pkbf(float a, float b) {
    unsigned ua = __float_as_uint(a);
    ua = (ua + 0x7FFFu + ((ua >> 16) & 1u)) >> 16;
    unsigned ub = __float_as_uint(b);
    ub = (ub + 0x7FFFu + ((ub >> 16) & 1u)) & 0xFFFF0000u;
    return (ua & 0xFFFFu) | ub;
}
static __device__ __forceinline__ float bflo(unsigned u) { return __uint_as_float(u << 16); }
static __device__ __forceinline__ float bfhi(unsigned u) { return __uint_as_float(u & 0xFFFF0000u); }

// combW[o][i] = sum_k out_w[o][k]*in_w[256+k][i] ; combb[o] = out_b[o] + sum_k out_w[o][k]*in_b[256+k]
__global__ __launch_bounds__(256) void mha_combine(
    const float* __restrict__ in_w, const float* __restrict__ in_b,
    const float* __restrict__ out_w, const float* __restrict__ out_b,
    float* __restrict__ combW, float* __restrict__ combb)
{
    int idx = blockIdx.x * blockDim.x + threadIdx.x;
    if (idx >= 128 * 128) return;
    int o = idx >> 7, i = idx & 127;
    float a = 0.f;
    for (int k = 0; k < 128; ++k)
        a = fmaf(out_w[o * 128 + k], in_w[(256 + k) * 128 + i], a);
    combW[idx] = a;
    if (i == 0) {
        float b = out_b[o];
        for (int k = 0; k < 128; ++k)
            b = fmaf(out_w[o * 128 + k], in_b[256 + k], b);
        combb[o] = b;
    }
}

// out[n][o] = sum_k A[n][k] * W[o][k]  (+bias[o]).
// Optional: f32 store to `out`, packed-bf16 store to `hb`, and
// ssrc[n]=sum_o out[n][o]*asrc[o] / sdst likewise.
__global__ __launch_bounds__(256) void gemm_nt(
    const float* __restrict__ A, const float* __restrict__ W,
    const float* __restrict__ bias,
    const float* __restrict__ asrc, const float* __restrict__ adst,
    float* __restrict__ out, unsigned* __restrict__ hb,
    float* __restrict__ ssrc, float* __restrict__ sdst,
    int n)
{
    __shared__ float Wt[64 * 132];   // Wt[kk][o], padded stride 132
    __shared__ float xs[32 * 128];
    const int t = threadIdx.x;
    const int row0 = blockIdx.x * 32;

    for (int i = t; i < 32 * 32; i += 256) {          // 1024 float4
        int r = i >> 5, c4 = i & 31;
        int gr = row0 + r;
        float4 v = (gr < n) ? ((const float4*)A)[(size_t)gr * 32 + c4]
                            : make_float4(0.f, 0.f, 0.f, 0.f);
        ((float4*)xs)[i] = v;
    }

    const int co = (t & 31) * 4;        // col base (0..124)
    const int rbase = (t >> 5) * 4;     // row base within tile (0..28)
    float4 acc[4];
#pragma unroll
    for (int j = 0; j < 4; ++j) acc[j] = make_float4(0.f, 0.f, 0.f, 0.f);

    for (int half = 0; half < 2; ++half) {
        const int kbase = half * 64;
        __syncthreads();
        for (int i = t; i < 64 * 128; i += 256) {     // load W^T slice
            int o = i >> 6, kk = i & 63;
            Wt[kk * 132 + o] = W[o * 128 + kbase + kk];
        }
        __syncthreads();
#pragma unroll 4
        for (int k4 = 0; k4 < 16; ++k4) {
            float4 xv[4];
#pragma unroll
            for (int j = 0; j < 4; ++j)
                xv[j] = ((const float4*)xs)[(rbase + j) * 32 + (kbase >> 2) + k4];
#pragma unroll
            for (int kk = 0; kk < 4; ++kk) {
                float4 w = *(const float4*)&Wt[(k4 * 4 + kk) * 132 + co];
#pragma unroll
                for (int j = 0; j < 4; ++j) {
                    float xb = (&xv[j].x)[kk];
                    acc[j].x = fmaf(xb, w.x, acc[j].x);
                    acc[j].y = fmaf(xb, w.y, acc[j].y);
                    acc[j].z = fmaf(xb, w.z, acc[j].z);
                    acc[j].w = fmaf(xb, w.w, acc[j].w);
                }
            }
        }
    }

    float4 bv = make_float4(0.f, 0.f, 0.f, 0.f);
    if (bias) bv = *(const float4*)&bias[co];
#pragma unroll
    for (int j = 0; j < 4; ++j) {
        acc[j].x += bv.x; acc[j].y += bv.y; acc[j].z += bv.z; acc[j].w += bv.w;
    }

    if (out) {
#pragma unroll
        for (int j = 0; j < 4; ++j) {
            int r = row0 + rbase + j;
            if (r < n) ((float4*)out)[(size_t)r * 32 + (t & 31)] = acc[j];
        }
    }
    if (hb) {
#pragma unroll
        for (int j = 0; j < 4; ++j) {
            int r = row0 + rbase + j;
            if (r < n) {
                uint2 p = make_uint2(pkbf(acc[j].x, acc[j].y), pkbf(acc[j].z, acc[j].w));
                *(uint2*)&hb[(size_t)r * 64 + (t & 31) * 2] = p;
            }
        }
    }

    if (asrc != nullptr) {
        float4 as = *(const float4*)&asrc[co];
        float4 ad = *(const float4*)&adst[co];
#pragma unroll
        for (int j = 0; j < 4; ++j) {
            float ps = acc[j].x * as.x + acc[j].y * as.y + acc[j].z * as.z + acc[j].w * as.w;
            float pd = acc[j].x * ad.x + acc[j].y * ad.y + acc[j].z * ad.z + acc[j].w * ad.w;
#pragma unroll
            for (int off = 16; off; off >>= 1) {
                ps += __shfl_xor(ps, off);
                pd += __shfl_xor(pd, off);
            }
            if ((t & 31) == 0) {
                int r = row0 + rbase + j;
                if (r < n) { ssrc[r] = ps; sdst[r] = pd; }
            }
        }
    }
}

// ---------------- CSR build (counting sort by dst, incl. self loops) ----------------

__global__ __launch_bounds__(256) void hist_k(
    const int* __restrict__ ei, int E, int n, int* __restrict__ cnt)
{
    int e = blockIdx.x * blockDim.x + threadIdx.x;
    if (e >= E + n) return;
    int d = (e < E) ? ei[E + e] : (e - E);
    atomicAdd(&cnt[d], 1);
}

// 3-kernel exclusive scan over n ints (1024 elems per block)
__global__ __launch_bounds__(256) void scan1(
    const int* __restrict__ cnt, int n, int* __restrict__ bsum)
{
    __shared__ int ws[256];
    int t = threadIdx.x;
    int i = blockIdx.x * 1024 + t * 4;
    int s = 0;
    if (i + 3 < n) { int4 v = *(const int4*)&cnt[i]; s = v.x + v.y + v.z + v.w; }
    else {
        for (int j = 0; j < 4; ++j) if (i + j < n) s += cnt[i + j];
    }
    ws[t] = s; __syncthreads();
    for (int o = 128; o; o >>= 1) { if (t < o) ws[t] += ws[t + o]; __syncthreads(); }
    if (t == 0) bsum[blockIdx.x] = ws[0];
}

// single-wave shfl scan (nb <= 64 fast path)
__global__ void scan2(int* __restrict__ bsum, int nb, int* __restrict__ total_out)
{
    if (nb <= 64) {
        int lane = threadIdx.x & 63;
        int orig = (lane < nb) ? bsum[lane] : 0;
        int v = orig;
#pragma unroll
        for (int o = 1; o < 64; o <<= 1) {
            int u = __shfl_up(v, o);
            if (lane >= o) v += u;
        }
        if (lane < nb) bsum[lane] = v - orig;   // exclusive
        if (lane == 63) *total_out = v;
    } else if (threadIdx.x == 0) {
        int run = 0;
        for (int i = 0; i < nb; ++i) { int v = bsum[i]; bsum[i] = run; run += v; }
        *total_out = run;
    }
}

__global__ __launch_bounds__(256) void scan3(
    const int* __restrict__ cnt, int n,
    const int* __restrict__ bsum, int* __restrict__ off)
{
    __shared__ int ws[256];
    int t = threadIdx.x;
    int i = blockIdx.x * 1024 + t * 4;
    int4 v = make_int4(0, 0, 0, 0);
    if (i + 3 < n) v = *(const int4*)&cnt[i];
    else {
        if (i     < n) v.x = cnt[i];
        if (i + 1 < n) v.y = cnt[i + 1];
        if (i + 2 < n) v.z = cnt[i + 2];
        if (i + 3 < n) v.w = cnt[i + 3];
    }
    int s = v.x + v.y + v.z + v.w;
    ws[t] = s; __syncthreads();
    for (int o = 1; o < 256; o <<= 1) {
        int a = (t >= o) ? ws[t - o] : 0;
        __syncthreads();
        ws[t] += a;
        __syncthreads();
    }
    int excl = ws[t] - s + bsum[blockIdx.x];
    if (i     < n) off[i]     = excl;
    if (i + 1 < n) off[i + 1] = excl + v.x;
    if (i + 2 < n) off[i + 2] = excl + v.x + v.y;
    if (i + 3 < n) off[i + 3] = excl + v.x + v.y + v.z;
}

__global__ __launch_bounds__(256) void csr_scatter(
    const int* __restrict__ ei, int E, int n,
    const int* __restrict__ off, int* __restrict__ cursor, int* __restrict__ csrc)
{
    int e = blockIdx.x * blockDim.x + threadIdx.x;
    if (e >= E + n) return;
    int s, d;
    if (e < E) { s = ei[e]; d = ei[E + e]; }
    else       { s = e - E; d = e - E; }
    int pos = off[d] + atomicAdd(&cursor[d], 1);
    csrc[pos] = s;
}

// ---------------- fused GAT aggregation: one 64-lane wave per destination node ----------------
// pass A: each lane owns one neighbor (deg<=64 fast path): load src+logit+exp once into regs.
// pass B: shfl-broadcast (src, ex) from lane j; gather bf16 h row (4 B/lane), unroll x4.
__global__ __launch_bounds__(256) void gat_aggregate(
    const int* __restrict__ off, const int* __restrict__ csrc,
    const float* __restrict__ ssrc, const float* __restrict__ sdst,
    const unsigned* __restrict__ hb, const float* __restrict__ bias,
    float* __restrict__ out, int n, int relu)
{
    int node = blockIdx.x * 4 + (threadIdx.x >> 6);
    int lane = threadIdx.x & 63;
    if (node >= n) return;
    int p0 = off[node], p1 = off[node + 1];
    int deg = p1 - p0;
    float sd = sdst[node];

    int mysrc = 0; float myv = -INFINITY;
    if (lane < deg) {
        mysrc = csrc[p0 + lane];
        float v = ssrc[mysrc] + sd;
        myv = (v > 0.f) ? v : NEG_SLOPE * v;
    }
    float m = myv;
    for (int p = p0 + 64 + lane; p < p1; p += 64) {   // rare deg>64 overflow
        int s = csrc[p];
        float v = ssrc[s] + sd;
        v = (v > 0.f) ? v : NEG_SLOPE * v;
        m = fmaxf(m, v);
    }
#pragma unroll
    for (int o = 32; o; o >>= 1) m = fmaxf(m, __shfl_xor(m, o));

    float myex = (lane < deg) ? __expf(myv - m) : 0.f;
    float part = myex;
    for (int p = p0 + 64 + lane; p < p1; p += 64) {
        int s = csrc[p];
        float v = ssrc[s] + sd;
        v = (v > 0.f) ? v : NEG_SLOPE * v;
        part += __expf(v - m);
    }
    float ssum = part;
#pragma unroll
    for (int o = 32; o; o >>= 1) ssum += __shfl_xor(ssum, o);

    float ax = 0.f, ay = 0.f;
    int jcap = deg < 64 ? deg : 64;
    int j = 0;
    for (; j + 4 <= jcap; j += 4) {
        int s0 = __shfl(mysrc, j),     s1 = __shfl(mysrc, j + 1);
        int s2 = __shfl(mysrc, j + 2), s3 = __shfl(mysrc, j + 3);
        float e0 = __shfl(myex, j),     e1 = __shfl(myex, j + 1);
        float e2 = __shfl(myex, j + 2), e3 = __shfl(myex, j + 3);
        unsigned u0 = hb[(size_t)s0 * 64 + lane];
        unsigned u1 = hb[(size_t)s1 * 64 + lane];
        unsigned u2 = hb[(size_t)s2 * 64 + lane];
        unsigned u3 = hb[(size_t)s3 * 64 + lane];
        ax = fmaf(e0, bflo(u0), ax); ay = fmaf(e0, bfhi(u0), ay);
        ax = fmaf(e1, bflo(u1), ax); ay = fmaf(e1, bfhi(u1), ay);
        ax = fmaf(e2, bflo(u2), ax); ay = fmaf(e2, bfhi(u2), ay);
        ax = fmaf(e3, bflo(u3), ax); ay = fmaf(e3, bfhi(u3), ay);
    }
    for (; j < jcap; ++j) {
        int s = __shfl(mysrc, j);
        float e = __shfl(myex, j);
        unsigned u = hb[(size_t)s * 64 + lane];
        ax = fmaf(e, bflo(u), ax); ay = fmaf(e, bfhi(u), ay);
    }
    for (int p = p0 + 64; p < p1; ++p) {              // rare deg>64 overflow
        int s = csrc[p];
        float v = ssrc[s] + sd;
        v = (v > 0.f) ? v : NEG_SLOPE * v;
        float e = __expf(v - m);
        unsigned u = hb[(size_t)s * 64 + lane];
        ax = fmaf(e, bflo(u), ax); ay = fmaf(e, bfhi(u), ay);
    }

    float inv = 1.f / (ssum + 1e-16f);
    float2 bv = ((const float2*)bias)[lane];
    float ox = fmaf(ax, inv, bv.x);
    float oy = fmaf(ay, inv, bv.y);
    if (relu) { ox = fmaxf(ox, 0.f); oy = fmaxf(oy, 0.f); }
    ((float2*)(out + (size_t)node * 128))[lane] = make_float2(ox, oy);
}

// ---------------- fused fc + log_softmax: 32 nodes/block, LDS-staged GEMM ----------------
// thread t: row t>>3 ; classes (t&7)*5 .. +4  (38 KB LDS -> 4 blocks/CU)
__global__ __launch_bounds__(256) void fc_logsoftmax(
    const float* __restrict__ ox, const float* __restrict__ oy,
    const float* __restrict__ xres,
    const float* __restrict__ fcw, const float* __restrict__ fcb,
    float* __restrict__ out, int n)
{
    __shared__ float xs[32 * 132];   // [row][k] padded
    __shared__ float wt[40 * 132];   // [class][k] padded
    const int t = threadIdx.x;
    const int node0 = blockIdx.x * 32;
    const int r0 = t >> 3;
    const int c0 = (t & 7) * 5;

    float acc[5] = {0.f, 0.f, 0.f, 0.f, 0.f};

    const float* srcs[3] = {ox, oy, xres};
    for (int kc = 0; kc < 3; ++kc) {
        const float* S = srcs[kc];
        __syncthreads();
        for (int i = t; i < 32 * 32; i += 256) {      // x tile: 1024 float4
            int rr = i >> 5, c4 = i & 31;
            int gr = node0 + rr; if (gr >= n) gr = n - 1;
            *(float4*)&xs[rr * 132 + c4 * 4] = ((const float4*)S)[(size_t)gr * 32 + c4];
        }
        for (int i = t; i < 40 * 32; i += 256) {      // w tile: 1280 float4
            int cc = i >> 5, c4 = i & 31;
            *(float4*)&wt[cc * 132 + c4 * 4] = ((const float4*)fcw)[(size_t)cc * 96 + kc * 32 + c4];
        }
        __syncthreads();
#pragma unroll 8
        for (int k4 = 0; k4 < 32; ++k4) {
            float4 xv = *(const float4*)&xs[r0 * 132 + k4 * 4];
#pragma unroll
            for (int j = 0; j < 5; ++j) {
                float4 wv = *(const float4*)&wt[(c0 + j) * 132 + k4 * 4];
                acc[j] = fmaf(xv.x, wv.x, acc[j]);
                acc[j] = fmaf(xv.y, wv.y, acc[j]);
                acc[j] = fmaf(xv.z, wv.z, acc[j]);
                acc[j] = fmaf(xv.w, wv.w, acc[j]);
            }
        }
    }

#pragma unroll
    for (int j = 0; j < 5; ++j) acc[j] += fcb[c0 + j];

    // per-row log-softmax: reduce over the 8 class-group lanes (xor 1,2,4)
    float m0 = acc[0];
#pragma unroll
    for (int j = 1; j < 5; ++j) m0 = fmaxf(m0, acc[j]);
#pragma unroll
    for (int o = 1; o < 8; o <<= 1) m0 = fmaxf(m0, __shfl_xor(m0, o));
    float s0 = 0.f;
#pragma unroll
    for (int j = 0; j < 5; ++j) s0 += __expf(acc[j] - m0);
#pragma unroll
    for (int o = 1; o < 8; o <<= 1) s0 += __shfl_xor(s0, o);
    float lse = m0 + logf(s0);

    int g0 = node0 + r0;
    if (g0 >= n) g0 = n - 1;
#pragma unroll
    for (int j = 0; j < 5; ++j)
        out[(size_t)g0 * 40 + c0 + j] = acc[j] - lse;
}

// ---------------- host-side helpers ----------------

static void build_csr(const int* ei, int E, int N,
                      int* cnt, int* off, int* csrc, int* bsum, hipStream_t stream)
{
    int ET = E + N;
    int nb = (N + 1023) / 1024;
    hipMemsetAsync(cnt, 0, (size_t)N * sizeof(int), stream);
    hist_k<<<(ET + 255) / 256, 256, 0, stream>>>(ei, E, N, cnt);
    scan1<<<nb, 256, 0, stream>>>(cnt, N, bsum);
    scan2<<<1, 64, 0, stream>>>(bsum, nb, off + N);
    scan3<<<nb, 256, 0, stream>>>(cnt, N, bsum, off);
    hipMemsetAsync(cnt, 0, (size_t)N * sizeof(int), stream);  // reuse as cursor
    csr_scatter<<<(ET + 255) / 256, 256, 0, stream>>>(ei, E, N, off, cnt, csrc);
}

static void gat_layer(const float* f, const float* Wg,
                      const float* asrc_w, const float* adst_w, const float* bias,
                      const int* off, const int* csrc, int N, int relu,
                      unsigned* hb, float* outbuf, float* ssrc, float* sdst,
                      hipStream_t stream)
{
    gemm_nt<<<(N + 31) / 32, 256, 0, stream>>>(f, Wg, nullptr, asrc_w, adst_w,
                                               nullptr, hb, ssrc, sdst, N);
    gat_aggregate<<<(N + 3) / 4, 256, 0, stream>>>(off, csrc, ssrc, sdst, hb, bias, outbuf, N, relu);
}

extern "C" void kernel_launch(void* const* d_in, const int* in_sizes, int n_in,
                              void* d_out, int out_size, void* d_ws, size_t ws_size,
                              hipStream_t stream)
{
    const float* x    = (const float*)d_in[0];
    const float* y    = (const float*)d_in[1];
    const int*   eix  = (const int*)d_in[2];
    const int*   eiy  = (const int*)d_in[3];
    const float* a1iw = (const float*)d_in[4];
    const float* a1ib = (const float*)d_in[5];
    const float* a1ow = (const float*)d_in[6];
    const float* a1ob = (const float*)d_in[7];
    const float* a2iw = (const float*)d_in[8];
    const float* a2ib = (const float*)d_in[9];
    const float* a2ow = (const float*)d_in[10];
    const float* a2ob = (const float*)d_in[11];
    const float* g1w  = (const float*)d_in[12];
    const float* g1as = (const float*)d_in[13];
    const float* g1ad = (const float*)d_in[14];
    const float* g1b  = (const float*)d_in[15];
    const float* g2xw = (const float*)d_in[16];
    const float* g2xas= (const float*)d_in[17];
    const float* g2xad= (const float*)d_in[18];
    const float* g2xb = (const float*)d_in[19];
    const float* g2yw = (const float*)d_in[20];
    const float* g2yas= (const float*)d_in[21];
    const float* g2yad= (const float*)d_in[22];
    const float* g2yb = (const float*)d_in[23];
    const float* fcw  = (const float*)d_in[24];
    const float* fcb  = (const float*)d_in[25];
    float* outp = (float*)d_out;

    const int N = in_sizes[0] / 128;
    const int E = in_sizes[2] / 2;
    (void)n_in; (void)out_size; (void)ws_size;

    float* ws = (float*)d_ws;
    size_t NF = (size_t)N * 128;
    float*    A    = ws;                       // xa / ya / oy
    float*    C    = A + NF;                   // hx / hy
    float*    D    = C + NF;                   // ox
    unsigned* hb   = (unsigned*)(D + NF);      // packed bf16 h, N*64 uints
    float*    ssrc = (float*)(hb + (size_t)N * 64);
    float*    sdst = ssrc + N;
    float*    cw1  = sdst + N;
    float*    cb1  = cw1 + 128 * 128;
    float*    cw2  = cb1 + 128;
    float*    cb2  = cw2 + 128 * 128;
    int*      off  = (int*)(cb2 + 128);        // N+1
    int*      cnt  = off + ((N + 4) & ~3);     // N  (16B-aligned for int4)
    int*      bsum = cnt + ((N + 4) & ~3);     // ceil(N/1024)
    int*      csrc = bsum + 1024;              // E+N

    mha_combine<<<64, 256, 0, stream>>>(a1iw, a1ib, a1ow, a1ob, cw1, cb1);
    mha_combine<<<64, 256, 0, stream>>>(a2iw, a2ib, a2ow, a2ob, cw2, cb2);

    int gblocks = (N + 31) / 32;

    // ---- x path ----
    build_csr(eix, E, N, cnt, off, csrc, bsum, stream);
    gemm_nt<<<gblocks, 256, 0, stream>>>(x, cw1, cb1, nullptr, nullptr, A, nullptr, nullptr, nullptr, N);
    gat_layer(A, g1w,  g1as,  g1ad,  g1b,  off, csrc, N, 1, hb, C, ssrc, sdst, stream);
    gat_layer(C, g2xw, g2xas, g2xad, g2xb, off, csrc, N, 0, hb, D, ssrc, sdst, stream);

    // ---- y path (reuse CSR buffers) ----
    build_csr(eiy, E, N, cnt, off, csrc, bsum, stream);
    gemm_nt<<<gblocks, 256, 0, stream>>>(y, cw2, cb2, nullptr, nullptr, A, nullptr, nullptr, nullptr, N);
    gat_layer(A, g1w,  g1as,  g1ad,  g1b,  off, csrc, N, 1, hb, C, ssrc, sdst, stream);
    gat_layer(C, g2yw, g2yas, g2yad, g2yb, off, csrc, N, 0, hb, A, ssrc, sdst, stream);

    // ---- fusion fc + log_softmax ----
    fc_logsoftmax<<<(N + 31) / 32, 256, 0, stream>>>(D, A, x, fcw, fcb, outp, N);
}

// Round 6
// 486.259 us; speedup vs baseline: 7.8978x; 1.3672x over previous
//
#include <hip/hip_runtime.h>
#include <hip/hip_bf16.h>

#define NEG_SLOPE 0.2f

typedef __attribute__((ext_vector_type(4))) float f32x4;
typedef __attribute__((ext_vector_type(8))) short s16x8;

static __device__ __forceinline__ unsigned pkbf(float a, float b) {
    unsigned ua = __float_as_uint(a);
    ua = (ua + 0x7FFFu + ((ua >> 16) & 1u)) >> 16;
    unsigned ub = __float_as_uint(b);
    ub = (ub + 0x7FFFu + ((ub >> 16) & 1u)) & 0xFFFF0000u;
    return (ua & 0xFFFFu) | ub;
}
static __device__ __forceinline__ unsigned short bf1(float a) {
    unsigned ua = __float_as_uint(a);
    return (unsigned short)((ua + 0x7FFFu + ((ua >> 16) & 1u)) >> 16);
}
static __device__ __forceinline__ float bflo(unsigned u) { return __uint_as_float(u << 16); }
static __device__ __forceinline__ float bfhi(unsigned u) { return __uint_as_float(u & 0xFFFF0000u); }

// both MHA weight-combines in one kernel
__global__ __launch_bounds__(256) void mha_combine2(
    const float* __restrict__ iw1, const float* __restrict__ ib1,
    const float* __restrict__ ow1, const float* __restrict__ ob1,
    const float* __restrict__ iw2, const float* __restrict__ ib2,
    const float* __restrict__ ow2, const float* __restrict__ ob2,
    float* __restrict__ cw1, float* __restrict__ cb1,
    float* __restrict__ cw2, float* __restrict__ cb2)
{
    int idx = blockIdx.x * blockDim.x + threadIdx.x;
    int set = idx >> 14;
    int local = idx & 16383;
    int o = local >> 7, i = local & 127;
    const float* in_w  = set ? iw2 : iw1;
    const float* in_b  = set ? ib2 : ib1;
    const float* out_w = set ? ow2 : ow1;
    const float* out_b = set ? ob2 : ob1;
    float* combW = set ? cw2 : cw1;
    float* combb = set ? cb2 : cb1;
    float a = 0.f;
    for (int k = 0; k < 128; ++k)
        a = fmaf(out_w[o * 128 + k], in_w[(256 + k) * 128 + i], a);
    combW[local] = a;
    if (i == 0) {
        float b = out_b[o];
        for (int k = 0; k < 128; ++k)
            b = fmaf(out_w[o * 128 + k], in_b[256 + k], b);
        combb[o] = b;
    }
}

// MFMA GEMM: out[r][o] = sum_k A[r][k]*W[o][k] (+bias[o]); A f32 or packed-bf16.
// Writes bf16 h (ushort [r][128]) and optional ssrc/sdst epilogue reductions.
// Block: 64 rows, 4 waves; full K=128 staged in LDS (bf16, XOR slot swizzle).
template<bool ABF>
__global__ __launch_bounds__(256) void gemm_mfma(
    const void* __restrict__ Ain, const float* __restrict__ W,
    const float* __restrict__ bias,
    const float* __restrict__ asrc, const float* __restrict__ adst,
    unsigned short* __restrict__ hbs, float* __restrict__ ssrc, float* __restrict__ sdst,
    int n)
{
    __shared__ unsigned xl[64 * 64];    // A tile bf16 pairs, 16 KB
    __shared__ unsigned wl[128 * 64];   // W bf16 pairs, 32 KB
    const int t = threadIdx.x;
    const int row0 = blockIdx.x * 64;

    // stage A: 1024 16B-slots, 4 per thread
#pragma unroll
    for (int i = 0; i < 4; ++i) {
        int q = t + i * 256;
        int r = q >> 4, sl = q & 15;
        int gr = row0 + r; if (gr >= n) gr = n - 1;
        unsigned p0, p1, p2, p3;
        if (ABF) {
            uint4 v = ((const uint4*)Ain)[(size_t)gr * 16 + sl];
            p0 = v.x; p1 = v.y; p2 = v.z; p3 = v.w;
        } else {
            float4 a = ((const float4*)Ain)[(size_t)gr * 32 + sl * 2];
            float4 b = ((const float4*)Ain)[(size_t)gr * 32 + sl * 2 + 1];
            p0 = pkbf(a.x, a.y); p1 = pkbf(a.z, a.w);
            p2 = pkbf(b.x, b.y); p3 = pkbf(b.z, b.w);
        }
        int dsl = sl ^ (r & 7);
        *(uint4*)&xl[r * 64 + dsl * 4] = make_uint4(p0, p1, p2, p3);
    }
    // stage W: 2048 slots, 8 per thread (f32 -> bf16)
#pragma unroll
    for (int i = 0; i < 8; ++i) {
        int q = t + i * 256;
        int r = q >> 4, sl = q & 15;
        float4 a = ((const float4*)W)[(size_t)r * 32 + sl * 2];
        float4 b = ((const float4*)W)[(size_t)r * 32 + sl * 2 + 1];
        int dsl = sl ^ (r & 7);
        *(uint4*)&wl[r * 64 + dsl * 4] = make_uint4(
            pkbf(a.x, a.y), pkbf(a.z, a.w), pkbf(b.x, b.y), pkbf(b.z, b.w));
    }
    __syncthreads();

    const int l = t & 63, w = t >> 6;
    const int c = l & 15, q4 = l >> 4;
    const int rloc = w * 16 + c;            // A-frag row (local)
    f32x4 acc[8];
#pragma unroll
    for (int nt = 0; nt < 8; ++nt) acc[nt] = (f32x4){0.f, 0.f, 0.f, 0.f};

#pragma unroll
    for (int s = 0; s < 4; ++s) {
        int slot = (s * 4 + q4) ^ (c & 7);  // rloc&7 == c&7, wr&7 == c&7
        s16x8 af = *(const s16x8*)&xl[rloc * 64 + slot * 4];
#pragma unroll
        for (int nt = 0; nt < 8; ++nt) {
            int wr = nt * 16 + c;
            s16x8 bfr = *(const s16x8*)&wl[wr * 64 + slot * 4];
            acc[nt] = __builtin_amdgcn_mfma_f32_16x16x32_bf16(af, bfr, acc[nt], 0, 0, 0);
        }
    }

    // epilogue: D[row][col]: col = nt*16 + c, row = row0 + w*16 + q4*4 + j
    float bv[8], as8[8], ad8[8];
#pragma unroll
    for (int nt = 0; nt < 8; ++nt) {
        bv[nt]  = bias ? bias[nt * 16 + c] : 0.f;
        as8[nt] = asrc ? asrc[nt * 16 + c] : 0.f;
        ad8[nt] = asrc ? adst[nt * 16 + c] : 0.f;
    }
    float ps[4] = {0.f, 0.f, 0.f, 0.f}, pd[4] = {0.f, 0.f, 0.f, 0.f};
    const int grow0 = row0 + w * 16 + q4 * 4;
#pragma unroll
    for (int nt = 0; nt < 8; ++nt) {
#pragma unroll
        for (int j = 0; j < 4; ++j) {
            float val = acc[nt][j] + bv[nt];
            if (grow0 + j < n) hbs[(size_t)(grow0 + j) * 128 + nt * 16 + c] = bf1(val);
            ps[j] = fmaf(val, as8[nt], ps[j]);
            pd[j] = fmaf(val, ad8[nt], pd[j]);
        }
    }
    if (asrc) {
#pragma unroll
        for (int j = 0; j < 4; ++j) {
            float a = ps[j], b = pd[j];
#pragma unroll
            for (int o = 1; o < 16; o <<= 1) {
                a += __shfl_xor(a, o);
                b += __shfl_xor(b, o);
            }
            if (c == 0 && grow0 + j < n) { ssrc[grow0 + j] = a; sdst[grow0 + j] = b; }
        }
    }
}

// ---------------- CSR build (counting sort by dst, incl. self loops) ----------------

__global__ __launch_bounds__(256) void hist_k(
    const int* __restrict__ ei, int E, int n, int* __restrict__ cnt)
{
    int e = blockIdx.x * blockDim.x + threadIdx.x;
    if (e >= E + n) return;
    int d = (e < E) ? ei[E + e] : (e - E);
    atomicAdd(&cnt[d], 1);
}

__global__ __launch_bounds__(256) void scan1(
    const int* __restrict__ cnt, int n, int* __restrict__ bsum)
{
    __shared__ int ws[256];
    int t = threadIdx.x;
    int i = blockIdx.x * 1024 + t * 4;
    int s = 0;
    if (i + 3 < n) { int4 v = *(const int4*)&cnt[i]; s = v.x + v.y + v.z + v.w; }
    else {
        for (int j = 0; j < 4; ++j) if (i + j < n) s += cnt[i + j];
    }
    ws[t] = s; __syncthreads();
    for (int o = 128; o; o >>= 1) { if (t < o) ws[t] += ws[t + o]; __syncthreads(); }
    if (t == 0) bsum[blockIdx.x] = ws[0];
}

__global__ void scan2(int* __restrict__ bsum, int nb, int* __restrict__ total_out)
{
    if (nb <= 64) {
        int lane = threadIdx.x & 63;
        int orig = (lane < nb) ? bsum[lane] : 0;
        int v = orig;
#pragma unroll
        for (int o = 1; o < 64; o <<= 1) {
            int u = __shfl_up(v, o);
            if (lane >= o) v += u;
        }
        if (lane < nb) bsum[lane] = v - orig;
        if (lane == 63) *total_out = v;
    } else if (threadIdx.x == 0) {
        int run = 0;
        for (int i = 0; i < nb; ++i) { int v = bsum[i]; bsum[i] = run; run += v; }
        *total_out = run;
    }
}

// writes exclusive scan to off AND initializes cursor with the same values
__global__ __launch_bounds__(256) void scan3(
    const int* __restrict__ cnt, int n,
    const int* __restrict__ bsum, int* __restrict__ off, int* __restrict__ cursor)
{
    __shared__ int ws[256];
    int t = threadIdx.x;
    int i = blockIdx.x * 1024 + t * 4;
    int4 v = make_int4(0, 0, 0, 0);
    if (i + 3 < n) v = *(const int4*)&cnt[i];
    else {
        if (i     < n) v.x = cnt[i];
        if (i + 1 < n) v.y = cnt[i + 1];
        if (i + 2 < n) v.z = cnt[i + 2];
        if (i + 3 < n) v.w = cnt[i + 3];
    }
    int s = v.x + v.y + v.z + v.w;
    ws[t] = s; __syncthreads();
    for (int o = 1; o < 256; o <<= 1) {
        int a = (t >= o) ? ws[t - o] : 0;
        __syncthreads();
        ws[t] += a;
        __syncthreads();
    }
    int excl = ws[t] - s + bsum[blockIdx.x];
    int e0 = excl, e1 = excl + v.x, e2 = e1 + v.y, e3 = e2 + v.z;
    if (i     < n) { off[i]     = e0; cursor[i]     = e0; }
    if (i + 1 < n) { off[i + 1] = e1; cursor[i + 1] = e1; }
    if (i + 2 < n) { off[i + 2] = e2; cursor[i + 2] = e2; }
    if (i + 3 < n) { off[i + 3] = e3; cursor[i + 3] = e3; }
}

__global__ __launch_bounds__(256) void csr_scatter(
    const int* __restrict__ ei, int E, int n,
    int* __restrict__ cursor, int* __restrict__ csrc)
{
    int e = blockIdx.x * blockDim.x + threadIdx.x;
    if (e >= E + n) return;
    int s, d;
    if (e < E) { s = ei[e]; d = ei[E + e]; }
    else       { s = e - E; d = e - E; }
    int pos = atomicAdd(&cursor[d], 1);
    csrc[pos] = s;
}

// ---------------- fused GAT aggregation: one 64-lane wave per destination node ----------------
// outputs packed bf16 (uint per lane = cols 2l, 2l+1)
__global__ __launch_bounds__(256) void gat_aggregate(
    const int* __restrict__ off, const int* __restrict__ csrc,
    const float* __restrict__ ssrc, const float* __restrict__ sdst,
    const unsigned* __restrict__ hb, const float* __restrict__ bias,
    unsigned* __restrict__ outu, int n, int relu)
{
    int node = blockIdx.x * 4 + (threadIdx.x >> 6);
    int lane = threadIdx.x & 63;
    if (node >= n) return;
    int p0 = off[node], p1 = off[node + 1];
    int deg = p1 - p0;
    float sd = sdst[node];

    int mysrc = 0; float myv = -INFINITY;
    if (lane < deg) {
        mysrc = csrc[p0 + lane];
        float v = ssrc[mysrc] + sd;
        myv = (v > 0.f) ? v : NEG_SLOPE * v;
    }
    float m = myv;
    for (int p = p0 + 64 + lane; p < p1; p += 64) {
        int s = csrc[p];
        float v = ssrc[s] + sd;
        v = (v > 0.f) ? v : NEG_SLOPE * v;
        m = fmaxf(m, v);
    }
#pragma unroll
    for (int o = 32; o; o >>= 1) m = fmaxf(m, __shfl_xor(m, o));

    float myex = (lane < deg) ? __expf(myv - m) : 0.f;
    float part = myex;
    for (int p = p0 + 64 + lane; p < p1; p += 64) {
        int s = csrc[p];
        float v = ssrc[s] + sd;
        v = (v > 0.f) ? v : NEG_SLOPE * v;
        part += __expf(v - m);
    }
    float ssum = part;
#pragma unroll
    for (int o = 32; o; o >>= 1) ssum += __shfl_xor(ssum, o);

    float ax = 0.f, ay = 0.f;
    int jcap = deg < 64 ? deg : 64;
    int j = 0;
    for (; j + 4 <= jcap; j += 4) {
        int s0 = __shfl(mysrc, j),     s1 = __shfl(mysrc, j + 1);
        int s2 = __shfl(mysrc, j + 2), s3 = __shfl(mysrc, j + 3);
        float e0 = __shfl(myex, j),     e1 = __shfl(myex, j + 1);
        float e2 = __shfl(myex, j + 2), e3 = __shfl(myex, j + 3);
        unsigned u0 = hb[(size_t)s0 * 64 + lane];
        unsigned u1 = hb[(size_t)s1 * 64 + lane];
        unsigned u2 = hb[(size_t)s2 * 64 + lane];
        unsigned u3 = hb[(size_t)s3 * 64 + lane];
        ax = fmaf(e0, bflo(u0), ax); ay = fmaf(e0, bfhi(u0), ay);
        ax = fmaf(e1, bflo(u1), ax); ay = fmaf(e1, bfhi(u1), ay);
        ax = fmaf(e2, bflo(u2), ax); ay = fmaf(e2, bfhi(u2), ay);
        ax = fmaf(e3, bflo(u3), ax); ay = fmaf(e3, bfhi(u3), ay);
    }
    for (; j < jcap; ++j) {
        int s = __shfl(mysrc, j);
        float e = __shfl(myex, j);
        unsigned u = hb[(size_t)s * 64 + lane];
        ax = fmaf(e, bflo(u), ax); ay = fmaf(e, bfhi(u), ay);
    }
    for (int p = p0 + 64; p < p1; ++p) {
        int s = csrc[p];
        float v = ssrc[s] + sd;
        v = (v > 0.f) ? v : NEG_SLOPE * v;
        float e = __expf(v - m);
        unsigned u = hb[(size_t)s * 64 + lane];
        ax = fmaf(e, bflo(u), ax); ay = fmaf(e, bfhi(u), ay);
    }

    float inv = 1.f / (ssum + 1e-16f);
    float2 bv = ((const float2*)bias)[lane];
    float ox = fmaf(ax, inv, bv.x);
    float oy = fmaf(ay, inv, bv.y);
    if (relu) { ox = fmaxf(ox, 0.f); oy = fmaxf(oy, 0.f); }
    outu[(size_t)node * 64 + lane] = pkbf(ox, oy);
}

// ---------------- fused fc + log_softmax: 128 rows/block, 4 rows/thread ----------------
// ox/oy packed bf16, x f32; only the 40x132 weight chunk lives in LDS.
__global__ __launch_bounds__(256) void fc_logsoftmax(
    const unsigned* __restrict__ oxu, const unsigned* __restrict__ oyu,
    const float* __restrict__ xres,
    const float* __restrict__ fcw, const float* __restrict__ fcb,
    float* __restrict__ out, int n)
{
    __shared__ float wt[40 * 132];
    const int t = threadIdx.x;
    const int node0 = blockIdx.x * 128;
    const int c0 = (t & 7) * 5;
    int gr[4];
#pragma unroll
    for (int j = 0; j < 4; ++j) {
        gr[j] = node0 + (t >> 3) * 4 + j;
        if (gr[j] >= n) gr[j] = n - 1;
    }

    float acc[4][5] = {};

    for (int kc = 0; kc < 3; ++kc) {
        __syncthreads();
        for (int i = t; i < 40 * 32; i += 256) {
            int cc = i >> 5, c4 = i & 31;
            *(float4*)&wt[cc * 132 + c4 * 4] = ((const float4*)fcw)[(size_t)cc * 96 + kc * 32 + c4];
        }
        __syncthreads();
#pragma unroll 4
        for (int k4 = 0; k4 < 32; ++k4) {
            float4 xv[4];
            if (kc == 2) {
#pragma unroll
                for (int j = 0; j < 4; ++j)
                    xv[j] = ((const float4*)xres)[(size_t)gr[j] * 32 + k4];
            } else {
                const unsigned* S = kc ? oyu : oxu;
#pragma unroll
                for (int j = 0; j < 4; ++j) {
                    uint2 u = *(const uint2*)&S[(size_t)gr[j] * 64 + k4 * 2];
                    xv[j] = make_float4(bflo(u.x), bfhi(u.x), bflo(u.y), bfhi(u.y));
                }
            }
#pragma unroll
            for (int j5 = 0; j5 < 5; ++j5) {
                float4 wv = *(const float4*)&wt[(c0 + j5) * 132 + k4 * 4];
#pragma unroll
                for (int j = 0; j < 4; ++j) {
                    acc[j][j5] = fmaf(xv[j].x, wv.x, acc[j][j5]);
                    acc[j][j5] = fmaf(xv[j].y, wv.y, acc[j][j5]);
                    acc[j][j5] = fmaf(xv[j].z, wv.z, acc[j][j5]);
                    acc[j][j5] = fmaf(xv[j].w, wv.w, acc[j][j5]);
                }
            }
        }
    }

    float fb[5];
#pragma unroll
    for (int j5 = 0; j5 < 5; ++j5) fb[j5] = fcb[c0 + j5];

#pragma unroll
    for (int j = 0; j < 4; ++j) {
        float m0 = -INFINITY;
#pragma unroll
        for (int j5 = 0; j5 < 5; ++j5) { acc[j][j5] += fb[j5]; m0 = fmaxf(m0, acc[j][j5]); }
#pragma unroll
        for (int o = 1; o < 8; o <<= 1) m0 = fmaxf(m0, __shfl_xor(m0, o));
        float s0 = 0.f;
#pragma unroll
        for (int j5 = 0; j5 < 5; ++j5) s0 += __expf(acc[j][j5] - m0);
#pragma unroll
        for (int o = 1; o < 8; o <<= 1) s0 += __shfl_xor(s0, o);
        float lse = m0 + logf(s0);
#pragma unroll
        for (int j5 = 0; j5 < 5; ++j5)
            out[(size_t)gr[j] * 40 + c0 + j5] = acc[j][j5] - lse;
    }
}

// ---------------- host-side helpers ----------------

static void build_csr(const int* ei, int E, int N,
                      int* cnt, int* off, int* csrc, int* bsum, int* cursor,
                      hipStream_t stream)
{
    int ET = E + N;
    int nb = (N + 1023) / 1024;
    hipMemsetAsync(cnt, 0, (size_t)N * sizeof(int), stream);
    hist_k<<<(ET + 255) / 256, 256, 0, stream>>>(ei, E, N, cnt);
    scan1<<<nb, 256, 0, stream>>>(cnt, N, bsum);
    scan2<<<1, 64, 0, stream>>>(bsum, nb, off + N);
    scan3<<<nb, 256, 0, stream>>>(cnt, N, bsum, off, cursor);
    csr_scatter<<<(ET + 255) / 256, 256, 0, stream>>>(ei, E, N, cursor, csrc);
}

extern "C" void kernel_launch(void* const* d_in, const int* in_sizes, int n_in,
                              void* d_out, int out_size, void* d_ws, size_t ws_size,
                              hipStream_t stream)
{
    const float* x    = (const float*)d_in[0];
    const float* y    = (const float*)d_in[1];
    const int*   eix  = (const int*)d_in[2];
    const int*   eiy  = (const int*)d_in[3];
    const float* a1iw = (const float*)d_in[4];
    const float* a1ib = (const float*)d_in[5];
    const float* a1ow = (const float*)d_in[6];
    const float* a1ob = (const float*)d_in[7];
    const float* a2iw = (const float*)d_in[8];
    const float* a2ib = (const float*)d_in[9];
    const float* a2ow = (const float*)d_in[10];
    const float* a2ob = (const float*)d_in[11];
    const float* g1w  = (const float*)d_in[12];
    const float* g1as = (const float*)d_in[13];
    const float* g1ad = (const float*)d_in[14];
    const float* g1b  = (const float*)d_in[15];
    const float* g2xw = (const float*)d_in[16];
    const float* g2xas= (const float*)d_in[17];
    const float* g2xad= (const float*)d_in[18];
    const float* g2xb = (const float*)d_in[19];
    const float* g2yw = (const float*)d_in[20];
    const float* g2yas= (const float*)d_in[21];
    const float* g2yad= (const float*)d_in[22];
    const float* g2yb = (const float*)d_in[23];
    const float* fcw  = (const float*)d_in[24];
    const float* fcb  = (const float*)d_in[25];
    float* outp = (float*)d_out;

    const int N = in_sizes[0] / 128;
    const int E = in_sizes[2] / 2;
    (void)n_in; (void)out_size; (void)ws_size;

    size_t NU = (size_t)N * 64;          // uints per bf16 node buffer
    unsigned* u0 = (unsigned*)d_ws;      // gemm h scratch
    unsigned* u1 = u0 + NU;              // xa/ya, later oy
    unsigned* u2 = u1 + NU;              // layer-1 out
    unsigned* u3 = u2 + NU;              // ox
    float* ssrc = (float*)(u3 + NU);
    float* sdst = ssrc + N;
    float* cw1  = sdst + N;
    float* cb1  = cw1 + 128 * 128;
    float* cw2  = cb1 + 128;
    float* cb2  = cw2 + 128 * 128;
    int*   off  = (int*)(cb2 + 128);       // N+1
    int*   cnt  = off + ((N + 4) & ~3);    // N (histogram, then cursor)
    int*   bsum = cnt + ((N + 4) & ~3);
    int*   csrc = bsum + 1024;             // E+N

    mha_combine2<<<128, 256, 0, stream>>>(a1iw, a1ib, a1ow, a1ob,
                                          a2iw, a2ib, a2ow, a2ob,
                                          cw1, cb1, cw2, cb2);

    const int gG = (N + 63) / 64;
    const int gA = (N + 3) / 4;

    // ---- x path ----
    build_csr(eix, E, N, cnt, off, csrc, bsum, cnt, stream);
    gemm_mfma<false><<<gG, 256, 0, stream>>>(x, cw1, cb1, nullptr, nullptr,
                                             (unsigned short*)u1, nullptr, nullptr, N);
    gemm_mfma<true><<<gG, 256, 0, stream>>>(u1, g1w, nullptr, g1as, g1ad,
                                            (unsigned short*)u0, ssrc, sdst, N);
    gat_aggregate<<<gA, 256, 0, stream>>>(off, csrc, ssrc, sdst, u0, g1b, u2, N, 1);
    gemm_mfma<true><<<gG, 256, 0, stream>>>(u2, g2xw, nullptr, g2xas, g2xad,
                                            (unsigned short*)u0, ssrc, sdst, N);
    gat_aggregate<<<gA, 256, 0, stream>>>(off, csrc, ssrc, sdst, u0, g2xb, u3, N, 0);

    // ---- y path ----
    build_csr(eiy, E, N, cnt, off, csrc, bsum, cnt, stream);
    gemm_mfma<false><<<gG, 256, 0, stream>>>(y, cw2, cb2, nullptr, nullptr,
                                             (unsigned short*)u1, nullptr, nullptr, N);
    gemm_mfma<true><<<gG, 256, 0, stream>>>(u1, g1w, nullptr, g1as, g1ad,
                                            (unsigned short*)u0, ssrc, sdst, N);
    gat_aggregate<<<gA, 256, 0, stream>>>(off, csrc, ssrc, sdst, u0, g1b, u2, N, 1);
    gemm_mfma<true><<<gG, 256, 0, stream>>>(u2, g2yw, nullptr, g2yas, g2yad,
                                            (unsigned short*)u0, ssrc, sdst, N);
    gat_aggregate<<<gA, 256, 0, stream>>>(off, csrc, ssrc, sdst, u0, g2yb, u1, N, 0);

    // ---- fusion fc + log_softmax ----
    fc_logsoftmax<<<(N + 127) / 128, 256, 0, stream>>>(u3, u1, x, fcw, fcb, outp, N);
}

// Round 7
// 445.602 us; speedup vs baseline: 8.6184x; 1.0912x over previous
//
#include <hip/hip_runtime.h>
#include <hip/hip_bf16.h>

#define NEG_SLOPE 0.2f

typedef __attribute__((ext_vector_type(4))) float f32x4;
typedef __attribute__((ext_vector_type(8))) short s16x8;

static __device__ __forceinline__ unsigned pkbf(float a, float b) {
    unsigned ua = __float_as_uint(a);
    ua = (ua + 0x7FFFu + ((ua >> 16) & 1u)) >> 16;
    unsigned ub = __float_as_uint(b);
    ub = (ub + 0x7FFFu + ((ub >> 16) & 1u)) & 0xFFFF0000u;
    return (ua & 0xFFFFu) | ub;
}
static __device__ __forceinline__ unsigned short bf1(float a) {
    unsigned ua = __float_as_uint(a);
    return (unsigned short)((ua + 0x7FFFu + ((ua >> 16) & 1u)) >> 16);
}
static __device__ __forceinline__ float bflo(unsigned u) { return __uint_as_float(u << 16); }
static __device__ __forceinline__ float bfhi(unsigned u) { return __uint_as_float(u & 0xFFFF0000u); }

// both MHA weight-combines in one kernel
__global__ __launch_bounds__(256) void mha_combine2(
    const float* __restrict__ iw1, const float* __restrict__ ib1,
    const float* __restrict__ ow1, const float* __restrict__ ob1,
    const float* __restrict__ iw2, const float* __restrict__ ib2,
    const float* __restrict__ ow2, const float* __restrict__ ob2,
    float* __restrict__ cw1, float* __restrict__ cb1,
    float* __restrict__ cw2, float* __restrict__ cb2)
{
    int idx = blockIdx.x * blockDim.x + threadIdx.x;
    int set = idx >> 14;
    int local = idx & 16383;
    int o = local >> 7, i = local & 127;
    const float* in_w  = set ? iw2 : iw1;
    const float* in_b  = set ? ib2 : ib1;
    const float* out_w = set ? ow2 : ow1;
    const float* out_b = set ? ob2 : ob1;
    float* combW = set ? cw2 : cw1;
    float* combb = set ? cb2 : cb1;
    float a = 0.f;
    for (int k = 0; k < 128; ++k)
        a = fmaf(out_w[o * 128 + k], in_w[(256 + k) * 128 + i], a);
    combW[local] = a;
    if (i == 0) {
        float b = out_b[o];
        for (int k = 0; k < 128; ++k)
            b = fmaf(out_w[o * 128 + k], in_b[256 + k], b);
        combb[o] = b;
    }
}

// Fused two-graph MFMA GEMM: grid half 0 -> set 0, half 1 -> set 1.
// out[r][o] = sum_k A[r][k]*W[o][k] (+bias); writes bf16 h + optional ssrc/sdst.
template<bool ABF>
__global__ __launch_bounds__(256) void gemm_mfma2(
    const void* __restrict__ A0, const void* __restrict__ A1,
    const float* __restrict__ W0, const float* __restrict__ W1,
    const float* __restrict__ bias0, const float* __restrict__ bias1,
    const float* __restrict__ as0, const float* __restrict__ ad0,
    const float* __restrict__ as1, const float* __restrict__ ad1,
    unsigned short* __restrict__ h0, unsigned short* __restrict__ h1,
    float* __restrict__ ss0, float* __restrict__ sd0,
    float* __restrict__ ss1, float* __restrict__ sd1,
    int n, int half)
{
    __shared__ unsigned xl[64 * 64];    // A tile bf16 pairs, 16 KB
    __shared__ unsigned wl[128 * 64];   // W bf16 pairs, 32 KB

    int b = blockIdx.x;
    const void* Ain; const float *W, *bias, *asrc, *adst;
    unsigned short* hbs; float *ssrc, *sdst;
    if (b < half) { Ain = A0; W = W0; bias = bias0; asrc = as0; adst = ad0; hbs = h0; ssrc = ss0; sdst = sd0; }
    else { b -= half; Ain = A1; W = W1; bias = bias1; asrc = as1; adst = ad1; hbs = h1; ssrc = ss1; sdst = sd1; }

    const int t = threadIdx.x;
    const int row0 = b * 64;

#pragma unroll
    for (int i = 0; i < 4; ++i) {
        int q = t + i * 256;
        int r = q >> 4, sl = q & 15;
        int gr = row0 + r; if (gr >= n) gr = n - 1;
        unsigned p0, p1, p2, p3;
        if (ABF) {
            uint4 v = ((const uint4*)Ain)[(size_t)gr * 16 + sl];
            p0 = v.x; p1 = v.y; p2 = v.z; p3 = v.w;
        } else {
            float4 a = ((const float4*)Ain)[(size_t)gr * 32 + sl * 2];
            float4 bb = ((const float4*)Ain)[(size_t)gr * 32 + sl * 2 + 1];
            p0 = pkbf(a.x, a.y); p1 = pkbf(a.z, a.w);
            p2 = pkbf(bb.x, bb.y); p3 = pkbf(bb.z, bb.w);
        }
        int dsl = sl ^ (r & 7);
        *(uint4*)&xl[r * 64 + dsl * 4] = make_uint4(p0, p1, p2, p3);
    }
#pragma unroll
    for (int i = 0; i < 8; ++i) {
        int q = t + i * 256;
        int r = q >> 4, sl = q & 15;
        float4 a = ((const float4*)W)[(size_t)r * 32 + sl * 2];
        float4 bb = ((const float4*)W)[(size_t)r * 32 + sl * 2 + 1];
        int dsl = sl ^ (r & 7);
        *(uint4*)&wl[r * 64 + dsl * 4] = make_uint4(
            pkbf(a.x, a.y), pkbf(a.z, a.w), pkbf(bb.x, bb.y), pkbf(bb.z, bb.w));
    }
    __syncthreads();

    const int l = t & 63, w = t >> 6;
    const int c = l & 15, q4 = l >> 4;
    const int rloc = w * 16 + c;
    f32x4 acc[8];
#pragma unroll
    for (int nt = 0; nt < 8; ++nt) acc[nt] = (f32x4){0.f, 0.f, 0.f, 0.f};

#pragma unroll
    for (int s = 0; s < 4; ++s) {
        int slot = (s * 4 + q4) ^ (c & 7);
        s16x8 af = *(const s16x8*)&xl[rloc * 64 + slot * 4];
#pragma unroll
        for (int nt = 0; nt < 8; ++nt) {
            int wr = nt * 16 + c;
            s16x8 bfr = *(const s16x8*)&wl[wr * 64 + slot * 4];
            acc[nt] = __builtin_amdgcn_mfma_f32_16x16x32_bf16(af, bfr, acc[nt], 0, 0, 0);
        }
    }

    float bv[8], as8[8], ad8[8];
#pragma unroll
    for (int nt = 0; nt < 8; ++nt) {
        bv[nt]  = bias ? bias[nt * 16 + c] : 0.f;
        as8[nt] = asrc ? asrc[nt * 16 + c] : 0.f;
        ad8[nt] = asrc ? adst[nt * 16 + c] : 0.f;
    }
    float ps[4] = {0.f, 0.f, 0.f, 0.f}, pd[4] = {0.f, 0.f, 0.f, 0.f};
    const int grow0 = row0 + w * 16 + q4 * 4;
#pragma unroll
    for (int nt = 0; nt < 8; ++nt) {
#pragma unroll
        for (int j = 0; j < 4; ++j) {
            float val = acc[nt][j] + bv[nt];
            if (grow0 + j < n) hbs[(size_t)(grow0 + j) * 128 + nt * 16 + c] = bf1(val);
            ps[j] = fmaf(val, as8[nt], ps[j]);
            pd[j] = fmaf(val, ad8[nt], pd[j]);
        }
    }
    if (asrc) {
#pragma unroll
        for (int j = 0; j < 4; ++j) {
            float a = ps[j], bb = pd[j];
#pragma unroll
            for (int o = 1; o < 16; o <<= 1) {
                a += __shfl_xor(a, o);
                bb += __shfl_xor(bb, o);
            }
            if (c == 0 && grow0 + j < n) { ssrc[grow0 + j] = a; sdst[grow0 + j] = bb; }
        }
    }
}

// ---------------- CSR build for BOTH graphs ----------------

__global__ __launch_bounds__(256) void hist2(
    const int* __restrict__ eix, const int* __restrict__ eiy, int E, int n,
    int* __restrict__ cntx, int* __restrict__ cnty)
{
    int e = blockIdx.x * blockDim.x + threadIdx.x;
    int ET = E + n;
    if (e >= 2 * ET) return;
    const int* ei = eix; int* cnt = cntx;
    if (e >= ET) { e -= ET; ei = eiy; cnt = cnty; }
    int d = (e < E) ? ei[E + e] : (e - E);
    atomicAdd(&cnt[d], 1);
}

__global__ __launch_bounds__(256) void scan1(
    const int* __restrict__ cntx, const int* __restrict__ cnty,
    int n, int nb, int* __restrict__ bsum)
{
    __shared__ int ws[256];
    int b = blockIdx.x;
    const int* cnt = cntx; int* bs = bsum;
    if (b >= nb) { b -= nb; cnt = cnty; bs = bsum + 512; }
    int t = threadIdx.x;
    int i = b * 1024 + t * 4;
    int s = 0;
    if (i + 3 < n) { int4 v = *(const int4*)&cnt[i]; s = v.x + v.y + v.z + v.w; }
    else {
        for (int j = 0; j < 4; ++j) if (i + j < n) s += cnt[i + j];
    }
    ws[t] = s; __syncthreads();
    for (int o = 128; o; o >>= 1) { if (t < o) ws[t] += ws[t + o]; __syncthreads(); }
    if (t == 0) bs[b] = ws[0];
}

// 128 threads: wave 0 scans graph-x block sums, wave 1 graph-y
__global__ void scan2(int* __restrict__ bsum, int nb,
                      int* __restrict__ totx, int* __restrict__ toty)
{
    int w = threadIdx.x >> 6;
    int* bs = bsum + (w ? 512 : 0);
    int* total = w ? toty : totx;
    int lane = threadIdx.x & 63;
    if (nb <= 64) {
        int orig = (lane < nb) ? bs[lane] : 0;
        int v = orig;
#pragma unroll
        for (int o = 1; o < 64; o <<= 1) {
            int u = __shfl_up(v, o);
            if (lane >= o) v += u;
        }
        if (lane < nb) bs[lane] = v - orig;
        if (lane == 63) *total = v;
    } else if (lane == 0) {
        int run = 0;
        for (int i = 0; i < nb; ++i) { int v = bs[i]; bs[i] = run; run += v; }
        *total = run;
    }
}

__global__ __launch_bounds__(256) void scan3(
    const int* __restrict__ cntx, const int* __restrict__ cnty,
    int n, int nb, const int* __restrict__ bsum,
    int* __restrict__ offx, int* __restrict__ offy,
    int* __restrict__ curx, int* __restrict__ cury)
{
    __shared__ int ws[256];
    int b = blockIdx.x;
    const int* cnt = cntx; const int* bs = bsum; int* off = offx; int* cursor = curx;
    if (b >= nb) { b -= nb; cnt = cnty; bs = bsum + 512; off = offy; cursor = cury; }
    int t = threadIdx.x;
    int i = b * 1024 + t * 4;
    int4 v = make_int4(0, 0, 0, 0);
    if (i + 3 < n) v = *(const int4*)&cnt[i];
    else {
        if (i     < n) v.x = cnt[i];
        if (i + 1 < n) v.y = cnt[i + 1];
        if (i + 2 < n) v.z = cnt[i + 2];
        if (i + 3 < n) v.w = cnt[i + 3];
    }
    int s = v.x + v.y + v.z + v.w;
    ws[t] = s; __syncthreads();
    for (int o = 1; o < 256; o <<= 1) {
        int a = (t >= o) ? ws[t - o] : 0;
        __syncthreads();
        ws[t] += a;
        __syncthreads();
    }
    int excl = ws[t] - s + bs[b];
    int e0 = excl, e1 = excl + v.x, e2 = e1 + v.y, e3 = e2 + v.z;
    if (i     < n) { off[i]     = e0; cursor[i]     = e0; }
    if (i + 1 < n) { off[i + 1] = e1; cursor[i + 1] = e1; }
    if (i + 2 < n) { off[i + 2] = e2; cursor[i + 2] = e2; }
    if (i + 3 < n) { off[i + 3] = e3; cursor[i + 3] = e3; }
}

__global__ __launch_bounds__(256) void csr_scatter2(
    const int* __restrict__ eix, const int* __restrict__ eiy, int E, int n,
    int* __restrict__ curx, int* __restrict__ cury,
    int* __restrict__ csx, int* __restrict__ csy)
{
    int e = blockIdx.x * blockDim.x + threadIdx.x;
    int ET = E + n;
    if (e >= 2 * ET) return;
    const int* ei = eix; int* cursor = curx; int* cs = csx;
    if (e >= ET) { e -= ET; ei = eiy; cursor = cury; cs = csy; }
    int s, d;
    if (e < E) { s = ei[e]; d = ei[E + e]; }
    else       { s = e - E; d = e - E; }
    int pos = atomicAdd(&cursor[d], 1);
    cs[pos] = s;
}

// ---------------- fused two-graph GAT aggregation: one wave per destination node ----------------
__global__ __launch_bounds__(256) void gat_aggregate2(
    const int* __restrict__ off0, const int* __restrict__ cs0,
    const float* __restrict__ ss0, const float* __restrict__ sd0,
    const unsigned* __restrict__ hb0, const float* __restrict__ bias0,
    unsigned* __restrict__ out0,
    const int* __restrict__ off1, const int* __restrict__ cs1,
    const float* __restrict__ ss1, const float* __restrict__ sd1,
    const unsigned* __restrict__ hb1, const float* __restrict__ bias1,
    unsigned* __restrict__ out1,
    int n, int relu, int half)
{
    int b = blockIdx.x;
    const int *off, *csrc; const float *ssrc, *sdst, *bias; const unsigned* hb; unsigned* outu;
    if (b < half) { off = off0; csrc = cs0; ssrc = ss0; sdst = sd0; hb = hb0; bias = bias0; outu = out0; }
    else { b -= half; off = off1; csrc = cs1; ssrc = ss1; sdst = sd1; hb = hb1; bias = bias1; outu = out1; }

    int node = b * 4 + (threadIdx.x >> 6);
    int lane = threadIdx.x & 63;
    if (node >= n) return;
    int p0 = off[node], p1 = off[node + 1];
    int deg = p1 - p0;
    float sd = sdst[node];

    int mysrc = 0; float myv = -INFINITY;
    if (lane < deg) {
        mysrc = csrc[p0 + lane];
        float v = ssrc[mysrc] + sd;
        myv = (v > 0.f) ? v : NEG_SLOPE * v;
    }
    float m = myv;
    for (int p = p0 + 64 + lane; p < p1; p += 64) {
        int s = csrc[p];
        float v = ssrc[s] + sd;
        v = (v > 0.f) ? v : NEG_SLOPE * v;
        m = fmaxf(m, v);
    }
#pragma unroll
    for (int o = 32; o; o >>= 1) m = fmaxf(m, __shfl_xor(m, o));

    float myex = (lane < deg) ? __expf(myv - m) : 0.f;
    float part = myex;
    for (int p = p0 + 64 + lane; p < p1; p += 64) {
        int s = csrc[p];
        float v = ssrc[s] + sd;
        v = (v > 0.f) ? v : NEG_SLOPE * v;
        part += __expf(v - m);
    }
    float ssum = part;
#pragma unroll
    for (int o = 32; o; o >>= 1) ssum += __shfl_xor(ssum, o);

    float ax = 0.f, ay = 0.f;
    int jcap = deg < 64 ? deg : 64;
    int j = 0;
    for (; j + 4 <= jcap; j += 4) {
        int s0 = __shfl(mysrc, j),     s1 = __shfl(mysrc, j + 1);
        int s2 = __shfl(mysrc, j + 2), s3 = __shfl(mysrc, j + 3);
        float e0 = __shfl(myex, j),     e1 = __shfl(myex, j + 1);
        float e2 = __shfl(myex, j + 2), e3 = __shfl(myex, j + 3);
        unsigned u0 = hb[(size_t)s0 * 64 + lane];
        unsigned u1 = hb[(size_t)s1 * 64 + lane];
        unsigned u2 = hb[(size_t)s2 * 64 + lane];
        unsigned u3 = hb[(size_t)s3 * 64 + lane];
        ax = fmaf(e0, bflo(u0), ax); ay = fmaf(e0, bfhi(u0), ay);
        ax = fmaf(e1, bflo(u1), ax); ay = fmaf(e1, bfhi(u1), ay);
        ax = fmaf(e2, bflo(u2), ax); ay = fmaf(e2, bfhi(u2), ay);
        ax = fmaf(e3, bflo(u3), ax); ay = fmaf(e3, bfhi(u3), ay);
    }
    for (; j < jcap; ++j) {
        int s = __shfl(mysrc, j);
        float e = __shfl(myex, j);
        unsigned u = hb[(size_t)s * 64 + lane];
        ax = fmaf(e, bflo(u), ax); ay = fmaf(e, bfhi(u), ay);
    }
    for (int p = p0 + 64; p < p1; ++p) {
        int s = csrc[p];
        float v = ssrc[s] + sd;
        v = (v > 0.f) ? v : NEG_SLOPE * v;
        float e = __expf(v - m);
        unsigned u = hb[(size_t)s * 64 + lane];
        ax = fmaf(e, bflo(u), ax); ay = fmaf(e, bfhi(u), ay);
    }

    float inv = 1.f / (ssum + 1e-16f);
    float2 bv = ((const float2*)bias)[lane];
    float ox = fmaf(ax, inv, bv.x);
    float oy = fmaf(ay, inv, bv.y);
    if (relu) { ox = fmaxf(ox, 0.f); oy = fmaxf(oy, 0.f); }
    outu[(size_t)node * 64 + lane] = pkbf(ox, oy);
}

// ---------------- fused fc + log_softmax: 128 rows/block, 4 rows/thread ----------------
__global__ __launch_bounds__(256) void fc_logsoftmax(
    const unsigned* __restrict__ oxu, const unsigned* __restrict__ oyu,
    const float* __restrict__ xres,
    const float* __restrict__ fcw, const float* __restrict__ fcb,
    float* __restrict__ out, int n)
{
    __shared__ float wt[40 * 132];
    const int t = threadIdx.x;
    const int node0 = blockIdx.x * 128;
    const int c0 = (t & 7) * 5;
    int gr[4];
#pragma unroll
    for (int j = 0; j < 4; ++j) {
        gr[j] = node0 + (t >> 3) * 4 + j;
        if (gr[j] >= n) gr[j] = n - 1;
    }

    float acc[4][5] = {};

    for (int kc = 0; kc < 3; ++kc) {
        __syncthreads();
        for (int i = t; i < 40 * 32; i += 256) {
            int cc = i >> 5, c4 = i & 31;
            *(float4*)&wt[cc * 132 + c4 * 4] = ((const float4*)fcw)[(size_t)cc * 96 + kc * 32 + c4];
        }
        __syncthreads();
#pragma unroll 4
        for (int k4 = 0; k4 < 32; ++k4) {
            float4 xv[4];
            if (kc == 2) {
#pragma unroll
                for (int j = 0; j < 4; ++j)
                    xv[j] = ((const float4*)xres)[(size_t)gr[j] * 32 + k4];
            } else {
                const unsigned* S = kc ? oyu : oxu;
#pragma unroll
                for (int j = 0; j < 4; ++j) {
                    uint2 u = *(const uint2*)&S[(size_t)gr[j] * 64 + k4 * 2];
                    xv[j] = make_float4(bflo(u.x), bfhi(u.x), bflo(u.y), bfhi(u.y));
                }
            }
#pragma unroll
            for (int j5 = 0; j5 < 5; ++j5) {
                float4 wv = *(const float4*)&wt[(c0 + j5) * 132 + k4 * 4];
#pragma unroll
                for (int j = 0; j < 4; ++j) {
                    acc[j][j5] = fmaf(xv[j].x, wv.x, acc[j][j5]);
                    acc[j][j5] = fmaf(xv[j].y, wv.y, acc[j][j5]);
                    acc[j][j5] = fmaf(xv[j].z, wv.z, acc[j][j5]);
                    acc[j][j5] = fmaf(xv[j].w, wv.w, acc[j][j5]);
                }
            }
        }
    }

    float fb[5];
#pragma unroll
    for (int j5 = 0; j5 < 5; ++j5) fb[j5] = fcb[c0 + j5];

#pragma unroll
    for (int j = 0; j < 4; ++j) {
        float m0 = -INFINITY;
#pragma unroll
        for (int j5 = 0; j5 < 5; ++j5) { acc[j][j5] += fb[j5]; m0 = fmaxf(m0, acc[j][j5]); }
#pragma unroll
        for (int o = 1; o < 8; o <<= 1) m0 = fmaxf(m0, __shfl_xor(m0, o));
        float s0 = 0.f;
#pragma unroll
        for (int j5 = 0; j5 < 5; ++j5) s0 += __expf(acc[j][j5] - m0);
#pragma unroll
        for (int o = 1; o < 8; o <<= 1) s0 += __shfl_xor(s0, o);
        float lse = m0 + logf(s0);
#pragma unroll
        for (int j5 = 0; j5 < 5; ++j5)
            out[(size_t)gr[j] * 40 + c0 + j5] = acc[j][j5] - lse;
    }
}

extern "C" void kernel_launch(void* const* d_in, const int* in_sizes, int n_in,
                              void* d_out, int out_size, void* d_ws, size_t ws_size,
                              hipStream_t stream)
{
    const float* x    = (const float*)d_in[0];
    const float* y    = (const float*)d_in[1];
    const int*   eix  = (const int*)d_in[2];
    const int*   eiy  = (const int*)d_in[3];
    const float* a1iw = (const float*)d_in[4];
    const float* a1ib = (const float*)d_in[5];
    const float* a1ow = (const float*)d_in[6];
    const float* a1ob = (const float*)d_in[7];
    const float* a2iw = (const float*)d_in[8];
    const float* a2ib = (const float*)d_in[9];
    const float* a2ow = (const float*)d_in[10];
    const float* a2ob = (const float*)d_in[11];
    const float* g1w  = (const float*)d_in[12];
    const float* g1as = (const float*)d_in[13];
    const float* g1ad = (const float*)d_in[14];
    const float* g1b  = (const float*)d_in[15];
    const float* g2xw = (const float*)d_in[16];
    const float* g2xas= (const float*)d_in[17];
    const float* g2xad= (const float*)d_in[18];
    const float* g2xb = (const float*)d_in[19];
    const float* g2yw = (const float*)d_in[20];
    const float* g2yas= (const float*)d_in[21];
    const float* g2yad= (const float*)d_in[22];
    const float* g2yb = (const float*)d_in[23];
    const float* fcw  = (const float*)d_in[24];
    const float* fcb  = (const float*)d_in[25];
    float* outp = (float*)d_out;

    const int N = in_sizes[0] / 128;
    const int E = in_sizes[2] / 2;
    (void)n_in; (void)out_size; (void)ws_size;

    size_t NU = (size_t)N * 64;              // uints per bf16 node buffer
    unsigned* u0 = (unsigned*)d_ws;          // xa -> r1x -> ox
    unsigned* u1 = u0 + NU;                  // hx -> h2x
    unsigned* u2 = u1 + NU;                  // ya -> r1y -> oy
    unsigned* u3 = u2 + NU;                  // hy -> h2y
    float* ssx = (float*)(u3 + NU);
    float* sdx = ssx + N;
    float* ssy = sdx + N;
    float* sdy = ssy + N;
    float* cw1 = sdy + N;
    float* cb1 = cw1 + 128 * 128;
    float* cw2 = cb1 + 128;
    float* cb2 = cw2 + 128 * 128;
    const int Npad = (N + 4) & ~3;
    int* offx = (int*)(cb2 + 128);           // N+1
    int* offy = offx + Npad;
    int* cntx = offy + Npad;                 // histogram then cursor (contiguous pair)
    int* cnty = cntx + Npad;
    int* bsum = cnty + Npad;                 // 1024 (two 512 halves)
    int* csx  = bsum + 1024;                 // E+N
    int* csy  = csx + (E + N);

    const int ET = E + N;
    const int nb = (N + 1023) / 1024;
    const int gG = (N + 63) / 64;
    const int gA = (N + 3) / 4;

    mha_combine2<<<128, 256, 0, stream>>>(a1iw, a1ib, a1ow, a1ob,
                                          a2iw, a2ib, a2ow, a2ob,
                                          cw1, cb1, cw2, cb2);

    // ---- build both CSRs ----
    hipMemsetAsync(cntx, 0, (size_t)2 * Npad * sizeof(int), stream);
    hist2<<<(2 * ET + 255) / 256, 256, 0, stream>>>(eix, eiy, E, N, cntx, cnty);
    scan1<<<2 * nb, 256, 0, stream>>>(cntx, cnty, N, nb, bsum);
    scan2<<<1, 128, 0, stream>>>(bsum, nb, offx + N, offy + N);
    scan3<<<2 * nb, 256, 0, stream>>>(cntx, cnty, N, nb, bsum, offx, offy, cntx, cnty);
    csr_scatter2<<<(2 * ET + 255) / 256, 256, 0, stream>>>(eix, eiy, E, N, cntx, cnty, csx, csy);

    // ---- MHA projection (both) ----
    gemm_mfma2<false><<<2 * gG, 256, 0, stream>>>(
        x, y, cw1, cw2, cb1, cb2,
        nullptr, nullptr, nullptr, nullptr,
        (unsigned short*)u0, (unsigned short*)u2,
        nullptr, nullptr, nullptr, nullptr, N, gG);

    // ---- GAT layer 1 (both) ----
    gemm_mfma2<true><<<2 * gG, 256, 0, stream>>>(
        u0, u2, g1w, g1w, nullptr, nullptr,
        g1as, g1ad, g1as, g1ad,
        (unsigned short*)u1, (unsigned short*)u3,
        ssx, sdx, ssy, sdy, N, gG);
    gat_aggregate2<<<2 * gA, 256, 0, stream>>>(
        offx, csx, ssx, sdx, u1, g1b, u0,
        offy, csy, ssy, sdy, u3, g1b, u2,
        N, 1, gA);

    // ---- GAT layer 2 (both) ----
    gemm_mfma2<true><<<2 * gG, 256, 0, stream>>>(
        u0, u2, g2xw, g2yw, nullptr, nullptr,
        g2xas, g2xad, g2yas, g2yad,
        (unsigned short*)u1, (unsigned short*)u3,
        ssx, sdx, ssy, sdy, N, gG);
    gat_aggregate2<<<2 * gA, 256, 0, stream>>>(
        offx, csx, ssx, sdx, u1, g2xb, u0,
        offy, csy, ssy, sdy, u3, g2yb, u2,
        N, 0, gA);

    // ---- fusion fc + log_softmax ----
    fc_logsoftmax<<<(N + 127) / 128, 256, 0, stream>>>(u0, u2, x, fcw, fcb, outp, N);
}

// Round 8
// 315.463 us; speedup vs baseline: 12.1738x; 1.4125x over previous
//
#include <hip/hip_runtime.h>
#include <hip/hip_bf16.h>

#define NEG_SLOPE 0.2f
#define LOG_R 10
#define RPB (1 << LOG_R)      // dsts per coarse bucket
#define EPB 4096              // edges per bucket_pass block
#define CAPB 24576            // fine_sort LDS staging entries

typedef __attribute__((ext_vector_type(4))) float f32x4;
typedef __attribute__((ext_vector_type(8))) short s16x8;

static __device__ __forceinline__ unsigned pkbf(float a, float b) {
    unsigned ua = __float_as_uint(a);
    ua = (ua + 0x7FFFu + ((ua >> 16) & 1u)) >> 16;
    unsigned ub = __float_as_uint(b);
    ub = (ub + 0x7FFFu + ((ub >> 16) & 1u)) & 0xFFFF0000u;
    return (ua & 0xFFFFu) | ub;
}
static __device__ __forceinline__ unsigned short bf1(float a) {
    unsigned ua = __float_as_uint(a);
    return (unsigned short)((ua + 0x7FFFu + ((ua >> 16) & 1u)) >> 16);
}
static __device__ __forceinline__ float bflo(unsigned u) { return __uint_as_float(u << 16); }
static __device__ __forceinline__ float bfhi(unsigned u) { return __uint_as_float(u & 0xFFFF0000u); }

// both MHA weight-combines in one kernel
__global__ __launch_bounds__(256) void mha_combine2(
    const float* __restrict__ iw1, const float* __restrict__ ib1,
    const float* __restrict__ ow1, const float* __restrict__ ob1,
    const float* __restrict__ iw2, const float* __restrict__ ib2,
    const float* __restrict__ ow2, const float* __restrict__ ob2,
    float* __restrict__ cw1, float* __restrict__ cb1,
    float* __restrict__ cw2, float* __restrict__ cb2)
{
    int idx = blockIdx.x * blockDim.x + threadIdx.x;
    int set = idx >> 14;
    int local = idx & 16383;
    int o = local >> 7, i = local & 127;
    const float* in_w  = set ? iw2 : iw1;
    const float* in_b  = set ? ib2 : ib1;
    const float* out_w = set ? ow2 : ow1;
    const float* out_b = set ? ob2 : ob1;
    float* combW = set ? cw2 : cw1;
    float* combb = set ? cb2 : cb1;
    float a = 0.f;
    for (int k = 0; k < 128; ++k)
        a = fmaf(out_w[o * 128 + k], in_w[(256 + k) * 128 + i], a);
    combW[local] = a;
    if (i == 0) {
        float b = out_b[o];
        for (int k = 0; k < 128; ++k)
            b = fmaf(out_w[o * 128 + k], in_b[256 + k], b);
        combb[o] = b;
    }
}

// Fused two-graph MFMA GEMM: grid half 0 -> set 0, half 1 -> set 1.
template<bool ABF>
__global__ __launch_bounds__(256) void gemm_mfma2(
    const void* __restrict__ A0, const void* __restrict__ A1,
    const float* __restrict__ W0, const float* __restrict__ W1,
    const float* __restrict__ bias0, const float* __restrict__ bias1,
    const float* __restrict__ as0, const float* __restrict__ ad0,
    const float* __restrict__ as1, const float* __restrict__ ad1,
    unsigned short* __restrict__ h0, unsigned short* __restrict__ h1,
    float* __restrict__ ss0, float* __restrict__ sd0,
    float* __restrict__ ss1, float* __restrict__ sd1,
    int n, int half)
{
    __shared__ unsigned xl[64 * 64];    // A tile bf16 pairs, 16 KB
    __shared__ unsigned wl[128 * 64];   // W bf16 pairs, 32 KB

    int b = blockIdx.x;
    const void* Ain; const float *W, *bias, *asrc, *adst;
    unsigned short* hbs; float *ssrc, *sdst;
    if (b < half) { Ain = A0; W = W0; bias = bias0; asrc = as0; adst = ad0; hbs = h0; ssrc = ss0; sdst = sd0; }
    else { b -= half; Ain = A1; W = W1; bias = bias1; asrc = as1; adst = ad1; hbs = h1; ssrc = ss1; sdst = sd1; }

    const int t = threadIdx.x;
    const int row0 = b * 64;

#pragma unroll
    for (int i = 0; i < 4; ++i) {
        int q = t + i * 256;
        int r = q >> 4, sl = q & 15;
        int gr = row0 + r; if (gr >= n) gr = n - 1;
        unsigned p0, p1, p2, p3;
        if (ABF) {
            uint4 v = ((const uint4*)Ain)[(size_t)gr * 16 + sl];
            p0 = v.x; p1 = v.y; p2 = v.z; p3 = v.w;
        } else {
            float4 a = ((const float4*)Ain)[(size_t)gr * 32 + sl * 2];
            float4 bb = ((const float4*)Ain)[(size_t)gr * 32 + sl * 2 + 1];
            p0 = pkbf(a.x, a.y); p1 = pkbf(a.z, a.w);
            p2 = pkbf(bb.x, bb.y); p3 = pkbf(bb.z, bb.w);
        }
        int dsl = sl ^ (r & 7);
        *(uint4*)&xl[r * 64 + dsl * 4] = make_uint4(p0, p1, p2, p3);
    }
#pragma unroll
    for (int i = 0; i < 8; ++i) {
        int q = t + i * 256;
        int r = q >> 4, sl = q & 15;
        float4 a = ((const float4*)W)[(size_t)r * 32 + sl * 2];
        float4 bb = ((const float4*)W)[(size_t)r * 32 + sl * 2 + 1];
        int dsl = sl ^ (r & 7);
        *(uint4*)&wl[r * 64 + dsl * 4] = make_uint4(
            pkbf(a.x, a.y), pkbf(a.z, a.w), pkbf(bb.x, bb.y), pkbf(bb.z, bb.w));
    }
    __syncthreads();

    const int l = t & 63, w = t >> 6;
    const int c = l & 15, q4 = l >> 4;
    const int rloc = w * 16 + c;
    f32x4 acc[8];
#pragma unroll
    for (int nt = 0; nt < 8; ++nt) acc[nt] = (f32x4){0.f, 0.f, 0.f, 0.f};

#pragma unroll
    for (int s = 0; s < 4; ++s) {
        int slot = (s * 4 + q4) ^ (c & 7);
        s16x8 af = *(const s16x8*)&xl[rloc * 64 + slot * 4];
#pragma unroll
        for (int nt = 0; nt < 8; ++nt) {
            int wr = nt * 16 + c;
            s16x8 bfr = *(const s16x8*)&wl[wr * 64 + slot * 4];
            acc[nt] = __builtin_amdgcn_mfma_f32_16x16x32_bf16(af, bfr, acc[nt], 0, 0, 0);
        }
    }

    float bv[8], as8[8], ad8[8];
#pragma unroll
    for (int nt = 0; nt < 8; ++nt) {
        bv[nt]  = bias ? bias[nt * 16 + c] : 0.f;
        as8[nt] = asrc ? asrc[nt * 16 + c] : 0.f;
        ad8[nt] = asrc ? adst[nt * 16 + c] : 0.f;
    }
    float ps[4] = {0.f, 0.f, 0.f, 0.f}, pd[4] = {0.f, 0.f, 0.f, 0.f};
    const int grow0 = row0 + w * 16 + q4 * 4;
#pragma unroll
    for (int nt = 0; nt < 8; ++nt) {
#pragma unroll
        for (int j = 0; j < 4; ++j) {
            float val = acc[nt][j] + bv[nt];
            if (grow0 + j < n) hbs[(size_t)(grow0 + j) * 128 + nt * 16 + c] = bf1(val);
            ps[j] = fmaf(val, as8[nt], ps[j]);
            pd[j] = fmaf(val, ad8[nt], pd[j]);
        }
    }
    if (asrc) {
#pragma unroll
        for (int j = 0; j < 4; ++j) {
            float a = ps[j], bb = pd[j];
#pragma unroll
            for (int o = 1; o < 16; o <<= 1) {
                a += __shfl_xor(a, o);
                bb += __shfl_xor(bb, o);
            }
            if (c == 0 && grow0 + j < n) { ssrc[grow0 + j] = a; sdst[grow0 + j] = bb; }
        }
    }
}

// ---------------- CSR build: two-level bucket sort ----------------

// coarse histogram (49 buckets), LDS-aggregated
__global__ __launch_bounds__(256) void hist_bucket2(
    const int* __restrict__ eix, const int* __restrict__ eiy, int E, int n,
    int* __restrict__ bcx, int* __restrict__ bcy, int half)
{
    __shared__ int lh[64];
    int gb = blockIdx.x;
    const int* ei = eix; int* bc = bcx;
    if (gb >= half) { gb -= half; ei = eiy; bc = bcy; }
    int t = threadIdx.x;
    int ET = E + n;
    int nbk = (n + RPB - 1) >> LOG_R;
    for (int i = t; i < nbk; i += 256) lh[i] = 0;
    __syncthreads();
    for (int e = gb * 256 + t; e < ET; e += half * 256) {
        int d = (e < E) ? ei[E + e] : (e - E);
        atomicAdd(&lh[d >> LOG_R], 1);
    }
    __syncthreads();
    if (t < nbk) atomicAdd(&bc[t], lh[t]);
}

// scan bucket counts (wave 0 = x, wave 1 = y); writes bases, cursors, off[N]
__global__ void bscan(
    const int* __restrict__ bcx, const int* __restrict__ bcy, int nbk,
    int* __restrict__ bbx, int* __restrict__ bby,
    int* __restrict__ curx, int* __restrict__ cury,
    int* __restrict__ offx_n, int* __restrict__ offy_n)
{
    int w = threadIdx.x >> 6, lane = threadIdx.x & 63;
    if (w > 1) return;
    const int* bc = w ? bcy : bcx;
    int* bb  = w ? bby : bbx;
    int* cur = w ? cury : curx;
    int* offn = w ? offy_n : offx_n;
    int c = (lane < nbk) ? bc[lane] : 0;
    int v = c;
#pragma unroll
    for (int o = 1; o < 64; o <<= 1) {
        int u = __shfl_up(v, o);
        if (lane >= o) v += u;
    }
    int excl = v - c;
    if (lane < nbk) { bb[lane] = excl; cur[lane] = excl; }
    if (lane == 63) { bb[nbk] = v; *offn = v; }
}

// pass A: bucket edges by dst>>LOG_R; per-block LDS sort + contiguous run flush.
// packed entry = (src << LOG_R) | (dst & (RPB-1))   (src<65536, fits 26 bits)
__global__ __launch_bounds__(256) void bucket_pass(
    const int* __restrict__ eix, const int* __restrict__ eiy, int E, int n,
    int* __restrict__ curx, int* __restrict__ cury,
    unsigned* __restrict__ pkx, unsigned* __restrict__ pky, int half)
{
    __shared__ int lhist[64], lbase[64], gbase[64], lpos[64];
    __shared__ unsigned stg[EPB];
    __shared__ int gidx[EPB];
    int gb = blockIdx.x;
    const int* ei = eix; int* bcur = curx; unsigned* pk = pkx;
    if (gb >= half) { gb -= half; ei = eiy; bcur = cury; pk = pky; }
    const int t = threadIdx.x;
    const int ET = E + n;
    const int nbk = (n + RPB - 1) >> LOG_R;   // must be <= 64
    const int base = gb * EPB;

    for (int i = t; i < nbk; i += 256) lhist[i] = 0;
    __syncthreads();

    unsigned mypk[16];
    int myb[16];
#pragma unroll
    for (int k = 0; k < 16; ++k) {
        int e = base + k * 256 + t;
        if (e < ET) {
            int s, d;
            if (e < E) { s = ei[e]; d = ei[E + e]; }
            else       { s = e - E; d = e - E; }
            myb[k] = d >> LOG_R;
            mypk[k] = ((unsigned)s << LOG_R) | (unsigned)(d & (RPB - 1));
            atomicAdd(&lhist[myb[k]], 1);
        } else myb[k] = -1;
    }
    __syncthreads();

    if (t < 64) {
        int c = (t < nbk) ? lhist[t] : 0;
        int v = c;
#pragma unroll
        for (int o = 1; o < 64; o <<= 1) {
            int u = __shfl_up(v, o);
            if (t >= o) v += u;
        }
        int excl = v - c;
        if (t < nbk) {
            lbase[t] = excl;
            lpos[t] = excl;
            gbase[t] = c ? atomicAdd(&bcur[t], c) : 0;
        }
    }
    __syncthreads();

#pragma unroll
    for (int k = 0; k < 16; ++k) {
        if (myb[k] >= 0) {
            int p = atomicAdd(&lpos[myb[k]], 1);
            stg[p] = mypk[k];
            gidx[p] = gbase[myb[k]] + (p - lbase[myb[k]]);
        }
    }
    __syncthreads();

    int tot = lbase[nbk - 1] + lhist[nbk - 1];
    for (int i = t; i < tot; i += 256) pk[gidx[i]] = stg[i];
}

// pass B: one block per bucket; per-dst hist + scan (produces off[]), then
// in-LDS scatter and coalesced ushort writeback.
__global__ __launch_bounds__(256) void fine_sort(
    const unsigned* __restrict__ pkx, const unsigned* __restrict__ pky,
    const int* __restrict__ bbx, const int* __restrict__ bby,
    int* __restrict__ offx, int* __restrict__ offy,
    unsigned short* __restrict__ csx, unsigned short* __restrict__ csy,
    int n, int half)
{
    __shared__ int cur[RPB];
    __shared__ int ws[256];
    __shared__ unsigned short outs[CAPB];
    int gb = blockIdx.x;
    const unsigned* pk; const int* bb; int* off; unsigned short* cs;
    if (gb < half) { pk = pkx; bb = bbx; off = offx; cs = csx; }
    else { gb -= half; pk = pky; bb = bby; off = offy; cs = csy; }
    const int t = threadIdx.x;
    const int d0 = gb << LOG_R;
    const int nd = min(RPB, n - d0);
    const int base = bb[gb];
    const int sz = bb[gb + 1] - base;

    for (int i = t; i < RPB; i += 256) cur[i] = 0;
    __syncthreads();
    for (int i = t; i < sz; i += 256)
        atomicAdd(&cur[pk[base + i] & (RPB - 1)], 1);
    __syncthreads();

    // exclusive scan of cur[0..1023]; also emit global off
    int c0 = cur[t * 4], c1 = cur[t * 4 + 1], c2 = cur[t * 4 + 2], c3 = cur[t * 4 + 3];
    int s = c0 + c1 + c2 + c3;
    ws[t] = s; __syncthreads();
    for (int o = 1; o < 256; o <<= 1) {
        int a = (t >= o) ? ws[t - o] : 0;
        __syncthreads();
        ws[t] += a;
        __syncthreads();
    }
    int ex = ws[t] - s;
    int e0 = ex, e1 = ex + c0, e2 = e1 + c1, e3 = e2 + c2;
    cur[t * 4] = e0; cur[t * 4 + 1] = e1; cur[t * 4 + 2] = e2; cur[t * 4 + 3] = e3;
    int i0 = t * 4;
    if (i0     < nd) off[d0 + i0]     = base + e0;
    if (i0 + 1 < nd) off[d0 + i0 + 1] = base + e1;
    if (i0 + 2 < nd) off[d0 + i0 + 2] = base + e2;
    if (i0 + 3 < nd) off[d0 + i0 + 3] = base + e3;
    __syncthreads();

    if (sz <= CAPB) {
        for (int i = t; i < sz; i += 256) {
            unsigned p = pk[base + i];
            int pos = atomicAdd(&cur[p & (RPB - 1)], 1);
            outs[pos] = (unsigned short)(p >> LOG_R);
        }
        __syncthreads();
        for (int i = t; i < sz; i += 256) cs[base + i] = outs[i];
    } else {
        for (int i = t; i < sz; i += 256) {
            unsigned p = pk[base + i];
            int pos = atomicAdd(&cur[p & (RPB - 1)], 1);
            cs[base + pos] = (unsigned short)(p >> LOG_R);
        }
    }
}

// ---------------- fused two-graph GAT aggregation: one wave per destination node ----------------
__global__ __launch_bounds__(256) void gat_aggregate2(
    const int* __restrict__ off0, const unsigned short* __restrict__ cs0,
    const float* __restrict__ ss0, const float* __restrict__ sd0,
    const unsigned* __restrict__ hb0, const float* __restrict__ bias0,
    unsigned* __restrict__ out0,
    const int* __restrict__ off1, const unsigned short* __restrict__ cs1,
    const float* __restrict__ ss1, const float* __restrict__ sd1,
    const unsigned* __restrict__ hb1, const float* __restrict__ bias1,
    unsigned* __restrict__ out1,
    int n, int relu, int half)
{
    int b = blockIdx.x;
    const int *off; const unsigned short *csrc; const float *ssrc, *sdst, *bias;
    const unsigned* hb; unsigned* outu;
    if (b < half) { off = off0; csrc = cs0; ssrc = ss0; sdst = sd0; hb = hb0; bias = bias0; outu = out0; }
    else { b -= half; off = off1; csrc = cs1; ssrc = ss1; sdst = sd1; hb = hb1; bias = bias1; outu = out1; }

    int node = b * 4 + (threadIdx.x >> 6);
    int lane = threadIdx.x & 63;
    if (node >= n) return;
    int p0 = off[node], p1 = off[node + 1];
    int deg = p1 - p0;
    float sd = sdst[node];

    int mysrc = 0; float myv = -INFINITY;
    if (lane < deg) {
        mysrc = csrc[p0 + lane];
        float v = ssrc[mysrc] + sd;
        myv = (v > 0.f) ? v : NEG_SLOPE * v;
    }
    float m = myv;
    for (int p = p0 + 64 + lane; p < p1; p += 64) {
        int s = csrc[p];
        float v = ssrc[s] + sd;
        v = (v > 0.f) ? v : NEG_SLOPE * v;
        m = fmaxf(m, v);
    }
#pragma unroll
    for (int o = 32; o; o >>= 1) m = fmaxf(m, __shfl_xor(m, o));

    float myex = (lane < deg) ? __expf(myv - m) : 0.f;
    float part = myex;
    for (int p = p0 + 64 + lane; p < p1; p += 64) {
        int s = csrc[p];
        float v = ssrc[s] + sd;
        v = (v > 0.f) ? v : NEG_SLOPE * v;
        part += __expf(v - m);
    }
    float ssum = part;
#pragma unroll
    for (int o = 32; o; o >>= 1) ssum += __shfl_xor(ssum, o);

    float ax = 0.f, ay = 0.f;
    int jcap = deg < 64 ? deg : 64;
    int j = 0;
    for (; j + 4 <= jcap; j += 4) {
        int s0 = __shfl(mysrc, j),     s1 = __shfl(mysrc, j + 1);
        int s2 = __shfl(mysrc, j + 2), s3 = __shfl(mysrc, j + 3);
        float e0 = __shfl(myex, j),     e1 = __shfl(myex, j + 1);
        float e2 = __shfl(myex, j + 2), e3 = __shfl(myex, j + 3);
        unsigned u0 = hb[(size_t)s0 * 64 + lane];
        unsigned u1 = hb[(size_t)s1 * 64 + lane];
        unsigned u2 = hb[(size_t)s2 * 64 + lane];
        unsigned u3 = hb[(size_t)s3 * 64 + lane];
        ax = fmaf(e0, bflo(u0), ax); ay = fmaf(e0, bfhi(u0), ay);
        ax = fmaf(e1, bflo(u1), ax); ay = fmaf(e1, bfhi(u1), ay);
        ax = fmaf(e2, bflo(u2), ax); ay = fmaf(e2, bfhi(u2), ay);
        ax = fmaf(e3, bflo(u3), ax); ay = fmaf(e3, bfhi(u3), ay);
    }
    for (; j < jcap; ++j) {
        int s = __shfl(mysrc, j);
        float e = __shfl(myex, j);
        unsigned u = hb[(size_t)s * 64 + lane];
        ax = fmaf(e, bflo(u), ax); ay = fmaf(e, bfhi(u), ay);
    }
    for (int p = p0 + 64; p < p1; ++p) {
        int s = csrc[p];
        float v = ssrc[s] + sd;
        v = (v > 0.f) ? v : NEG_SLOPE * v;
        float e = __expf(v - m);
        unsigned u = hb[(size_t)s * 64 + lane];
        ax = fmaf(e, bflo(u), ax); ay = fmaf(e, bfhi(u), ay);
    }

    float inv = 1.f / (ssum + 1e-16f);
    float2 bv = ((const float2*)bias)[lane];
    float ox = fmaf(ax, inv, bv.x);
    float oy = fmaf(ay, inv, bv.y);
    if (relu) { ox = fmaxf(ox, 0.f); oy = fmaxf(oy, 0.f); }
    outu[(size_t)node * 64 + lane] = pkbf(ox, oy);
}

// ---------------- fused fc + log_softmax: 128 rows/block, 4 rows/thread ----------------
__global__ __launch_bounds__(256) void fc_logsoftmax(
    const unsigned* __restrict__ oxu, const unsigned* __restrict__ oyu,
    const float* __restrict__ xres,
    const float* __restrict__ fcw, const float* __restrict__ fcb,
    float* __restrict__ out, int n)
{
    __shared__ float wt[40 * 132];
    const int t = threadIdx.x;
    const int node0 = blockIdx.x * 128;
    const int c0 = (t & 7) * 5;
    int gr[4];
#pragma unroll
    for (int j = 0; j < 4; ++j) {
        gr[j] = node0 + (t >> 3) * 4 + j;
        if (gr[j] >= n) gr[j] = n - 1;
    }

    float acc[4][5] = {};

    for (int kc = 0; kc < 3; ++kc) {
        __syncthreads();
        for (int i = t; i < 40 * 32; i += 256) {
            int cc = i >> 5, c4 = i & 31;
            *(float4*)&wt[cc * 132 + c4 * 4] = ((const float4*)fcw)[(size_t)cc * 96 + kc * 32 + c4];
        }
        __syncthreads();
#pragma unroll 4
        for (int k4 = 0; k4 < 32; ++k4) {
            float4 xv[4];
            if (kc == 2) {
#pragma unroll
                for (int j = 0; j < 4; ++j)
                    xv[j] = ((const float4*)xres)[(size_t)gr[j] * 32 + k4];
            } else {
                const unsigned* S = kc ? oyu : oxu;
#pragma unroll
                for (int j = 0; j < 4; ++j) {
                    uint2 u = *(const uint2*)&S[(size_t)gr[j] * 64 + k4 * 2];
                    xv[j] = make_float4(bflo(u.x), bfhi(u.x), bflo(u.y), bfhi(u.y));
                }
            }
#pragma unroll
            for (int j5 = 0; j5 < 5; ++j5) {
                float4 wv = *(const float4*)&wt[(c0 + j5) * 132 + k4 * 4];
#pragma unroll
                for (int j = 0; j < 4; ++j) {
                    acc[j][j5] = fmaf(xv[j].x, wv.x, acc[j][j5]);
                    acc[j][j5] = fmaf(xv[j].y, wv.y, acc[j][j5]);
                    acc[j][j5] = fmaf(xv[j].z, wv.z, acc[j][j5]);
                    acc[j][j5] = fmaf(xv[j].w, wv.w, acc[j][j5]);
                }
            }
        }
    }

    float fb[5];
#pragma unroll
    for (int j5 = 0; j5 < 5; ++j5) fb[j5] = fcb[c0 + j5];

#pragma unroll
    for (int j = 0; j < 4; ++j) {
        float m0 = -INFINITY;
#pragma unroll
        for (int j5 = 0; j5 < 5; ++j5) { acc[j][j5] += fb[j5]; m0 = fmaxf(m0, acc[j][j5]); }
#pragma unroll
        for (int o = 1; o < 8; o <<= 1) m0 = fmaxf(m0, __shfl_xor(m0, o));
        float s0 = 0.f;
#pragma unroll
        for (int j5 = 0; j5 < 5; ++j5) s0 += __expf(acc[j][j5] - m0);
#pragma unroll
        for (int o = 1; o < 8; o <<= 1) s0 += __shfl_xor(s0, o);
        float lse = m0 + logf(s0);
#pragma unroll
        for (int j5 = 0; j5 < 5; ++j5)
            out[(size_t)gr[j] * 40 + c0 + j5] = acc[j][j5] - lse;
    }
}

extern "C" void kernel_launch(void* const* d_in, const int* in_sizes, int n_in,
                              void* d_out, int out_size, void* d_ws, size_t ws_size,
                              hipStream_t stream)
{
    const float* x    = (const float*)d_in[0];
    const float* y    = (const float*)d_in[1];
    const int*   eix  = (const int*)d_in[2];
    const int*   eiy  = (const int*)d_in[3];
    const float* a1iw = (const float*)d_in[4];
    const float* a1ib = (const float*)d_in[5];
    const float* a1ow = (const float*)d_in[6];
    const float* a1ob = (const float*)d_in[7];
    const float* a2iw = (const float*)d_in[8];
    const float* a2ib = (const float*)d_in[9];
    const float* a2ow = (const float*)d_in[10];
    const float* a2ob = (const float*)d_in[11];
    const float* g1w  = (const float*)d_in[12];
    const float* g1as = (const float*)d_in[13];
    const float* g1ad = (const float*)d_in[14];
    const float* g1b  = (const float*)d_in[15];
    const float* g2xw = (const float*)d_in[16];
    const float* g2xas= (const float*)d_in[17];
    const float* g2xad= (const float*)d_in[18];
    const float* g2xb = (const float*)d_in[19];
    const float* g2yw = (const float*)d_in[20];
    const float* g2yas= (const float*)d_in[21];
    const float* g2yad= (const float*)d_in[22];
    const float* g2yb = (const float*)d_in[23];
    const float* fcw  = (const float*)d_in[24];
    const float* fcb  = (const float*)d_in[25];
    float* outp = (float*)d_out;

    const int N = in_sizes[0] / 128;
    const int E = in_sizes[2] / 2;
    (void)n_in; (void)out_size; (void)ws_size;

    size_t NU = (size_t)N * 64;              // uints per bf16 node buffer
    unsigned* u0 = (unsigned*)d_ws;          // xa -> r1x -> ox
    unsigned* u1 = u0 + NU;                  // hx -> h2x
    unsigned* u2 = u1 + NU;                  // ya -> r1y -> oy
    unsigned* u3 = u2 + NU;                  // hy -> h2y
    float* ssx = (float*)(u3 + NU);
    float* sdx = ssx + N;
    float* ssy = sdx + N;
    float* sdy = ssy + N;
    float* cw1 = sdy + N;
    float* cb1 = cw1 + 128 * 128;
    float* cw2 = cb1 + 128;
    float* cb2 = cw2 + 128 * 128;
    const int Npad = (N + 4) & ~3;
    int* offx = (int*)(cb2 + 128);           // N+1
    int* offy = offx + Npad;
    int* bbx  = offy + Npad;                 // nbk+1 (<=65), pad 128
    int* bby  = bbx + 128;
    int* bcx  = bby + 128;                   // 64
    int* bcy  = bcx + 64;
    int* curx = bcy + 64;                    // 64
    int* cury = curx + 64;
    unsigned* pkx = (unsigned*)(cury + 64);  // E+N packed entries
    unsigned* pky = pkx + (E + N);
    unsigned short* csx = (unsigned short*)(pky + (E + N));   // E+N ushort
    unsigned short* csy = csx + (((E + N) + 1) & ~1);

    const int ET = E + N;
    const int NBK = (N + RPB - 1) >> LOG_R;  // <= 64 required (N <= 65536)
    const int gG = (N + 63) / 64;
    const int gA = (N + 3) / 4;
    const int nAB = (ET + EPB - 1) / EPB;

    mha_combine2<<<128, 256, 0, stream>>>(a1iw, a1ib, a1ow, a1ob,
                                          a2iw, a2ib, a2ow, a2ob,
                                          cw1, cb1, cw2, cb2);

    // ---- build both CSRs (two-level bucket sort) ----
    hipMemsetAsync(bcx, 0, 128 * sizeof(int), stream);   // bcx+bcy
    hist_bucket2<<<256, 256, 0, stream>>>(eix, eiy, E, N, bcx, bcy, 128);
    bscan<<<1, 128, 0, stream>>>(bcx, bcy, NBK, bbx, bby, curx, cury, offx + N, offy + N);
    bucket_pass<<<2 * nAB, 256, 0, stream>>>(eix, eiy, E, N, curx, cury, pkx, pky, nAB);
    fine_sort<<<2 * NBK, 256, 0, stream>>>(pkx, pky, bbx, bby, offx, offy, csx, csy, N, NBK);

    // ---- MHA projection (both) ----
    gemm_mfma2<false><<<2 * gG, 256, 0, stream>>>(
        x, y, cw1, cw2, cb1, cb2,
        nullptr, nullptr, nullptr, nullptr,
        (unsigned short*)u0, (unsigned short*)u2,
        nullptr, nullptr, nullptr, nullptr, N, gG);

    // ---- GAT layer 1 (both) ----
    gemm_mfma2<true><<<2 * gG, 256, 0, stream>>>(
        u0, u2, g1w, g1w, nullptr, nullptr,
        g1as, g1ad, g1as, g1ad,
        (unsigned short*)u1, (unsigned short*)u3,
        ssx, sdx, ssy, sdy, N, gG);
    gat_aggregate2<<<2 * gA, 256, 0, stream>>>(
        offx, csx, ssx, sdx, u1, g1b, u0,
        offy, csy, ssy, sdy, u3, g1b, u2,
        N, 1, gA);

    // ---- GAT layer 2 (both) ----
    gemm_mfma2<true><<<2 * gG, 256, 0, stream>>>(
        u0, u2, g2xw, g2yw, nullptr, nullptr,
        g2xas, g2xad, g2yas, g2yad,
        (unsigned short*)u1, (unsigned short*)u3,
        ssx, sdx, ssy, sdy, N, gG);
    gat_aggregate2<<<2 * gA, 256, 0, stream>>>(
        offx, csx, ssx, sdx, u1, g2xb, u0,
        offy, csy, ssy, sdy, u3, g2yb, u2,
        N, 0, gA);

    // ---- fusion fc + log_softmax ----
    fc_logsoftmax<<<(N + 127) / 128, 256, 0, stream>>>(u0, u2, x, fcw, fcb, outp, N);
}

// Round 9
// 311.884 us; speedup vs baseline: 12.3135x; 1.0115x over previous
//
#include <hip/hip_runtime.h>
#include <hip/hip_bf16.h>

#define NEG_SLOPE 0.2f
#define LOG_R 10
#define RPB (1 << LOG_R)      // dsts per coarse bucket
#define EPB 4096              // edges per bucket_pass block
#define CAPB 24576            // fine_sort LDS staging entries

typedef __attribute__((ext_vector_type(4))) float f32x4;
typedef __attribute__((ext_vector_type(8))) short s16x8;

static __device__ __forceinline__ unsigned pkbf(float a, float b) {
    unsigned ua = __float_as_uint(a);
    ua = (ua + 0x7FFFu + ((ua >> 16) & 1u)) >> 16;
    unsigned ub = __float_as_uint(b);
    ub = (ub + 0x7FFFu + ((ub >> 16) & 1u)) & 0xFFFF0000u;
    return (ua & 0xFFFFu) | ub;
}
static __device__ __forceinline__ unsigned short bf1(float a) {
    unsigned ua = __float_as_uint(a);
    return (unsigned short)((ua + 0x7FFFu + ((ua >> 16) & 1u)) >> 16);
}
static __device__ __forceinline__ float bflo(unsigned u) { return __uint_as_float(u << 16); }
static __device__ __forceinline__ float bfhi(unsigned u) { return __uint_as_float(u & 0xFFFF0000u); }

// both MHA weight-combines in one kernel
__global__ __launch_bounds__(256) void mha_combine2(
    const float* __restrict__ iw1, const float* __restrict__ ib1,
    const float* __restrict__ ow1, const float* __restrict__ ob1,
    const float* __restrict__ iw2, const float* __restrict__ ib2,
    const float* __restrict__ ow2, const float* __restrict__ ob2,
    float* __restrict__ cw1, float* __restrict__ cb1,
    float* __restrict__ cw2, float* __restrict__ cb2)
{
    int idx = blockIdx.x * blockDim.x + threadIdx.x;
    int set = idx >> 14;
    int local = idx & 16383;
    int o = local >> 7, i = local & 127;
    const float* in_w  = set ? iw2 : iw1;
    const float* in_b  = set ? ib2 : ib1;
    const float* out_w = set ? ow2 : ow1;
    const float* out_b = set ? ob2 : ob1;
    float* combW = set ? cw2 : cw1;
    float* combb = set ? cb2 : cb1;
    float a = 0.f;
    for (int k = 0; k < 128; ++k)
        a = fmaf(out_w[o * 128 + k], in_w[(256 + k) * 128 + i], a);
    combW[local] = a;
    if (i == 0) {
        float b = out_b[o];
        for (int k = 0; k < 128; ++k)
            b = fmaf(out_w[o * 128 + k], in_b[256 + k], b);
        combb[o] = b;
    }
}

// Fused two-graph MFMA GEMM: grid half 0 -> set 0, half 1 -> set 1.
template<bool ABF>
__global__ __launch_bounds__(256) void gemm_mfma2(
    const void* __restrict__ A0, const void* __restrict__ A1,
    const float* __restrict__ W0, const float* __restrict__ W1,
    const float* __restrict__ bias0, const float* __restrict__ bias1,
    const float* __restrict__ as0, const float* __restrict__ ad0,
    const float* __restrict__ as1, const float* __restrict__ ad1,
    unsigned short* __restrict__ h0, unsigned short* __restrict__ h1,
    float* __restrict__ ss0, float* __restrict__ sd0,
    float* __restrict__ ss1, float* __restrict__ sd1,
    int n, int half)
{
    __shared__ unsigned xl[64 * 64];    // A tile bf16 pairs, 16 KB
    __shared__ unsigned wl[128 * 64];   // W bf16 pairs, 32 KB

    int b = blockIdx.x;
    const void* Ain; const float *W, *bias, *asrc, *adst;
    unsigned short* hbs; float *ssrc, *sdst;
    if (b < half) { Ain = A0; W = W0; bias = bias0; asrc = as0; adst = ad0; hbs = h0; ssrc = ss0; sdst = sd0; }
    else { b -= half; Ain = A1; W = W1; bias = bias1; asrc = as1; adst = ad1; hbs = h1; ssrc = ss1; sdst = sd1; }

    const int t = threadIdx.x;
    const int row0 = b * 64;

#pragma unroll
    for (int i = 0; i < 4; ++i) {
        int q = t + i * 256;
        int r = q >> 4, sl = q & 15;
        int gr = row0 + r; if (gr >= n) gr = n - 1;
        unsigned p0, p1, p2, p3;
        if (ABF) {
            uint4 v = ((const uint4*)Ain)[(size_t)gr * 16 + sl];
            p0 = v.x; p1 = v.y; p2 = v.z; p3 = v.w;
        } else {
            float4 a = ((const float4*)Ain)[(size_t)gr * 32 + sl * 2];
            float4 bb = ((const float4*)Ain)[(size_t)gr * 32 + sl * 2 + 1];
            p0 = pkbf(a.x, a.y); p1 = pkbf(a.z, a.w);
            p2 = pkbf(bb.x, bb.y); p3 = pkbf(bb.z, bb.w);
        }
        int dsl = sl ^ (r & 7);
        *(uint4*)&xl[r * 64 + dsl * 4] = make_uint4(p0, p1, p2, p3);
    }
#pragma unroll
    for (int i = 0; i < 8; ++i) {
        int q = t + i * 256;
        int r = q >> 4, sl = q & 15;
        float4 a = ((const float4*)W)[(size_t)r * 32 + sl * 2];
        float4 bb = ((const float4*)W)[(size_t)r * 32 + sl * 2 + 1];
        int dsl = sl ^ (r & 7);
        *(uint4*)&wl[r * 64 + dsl * 4] = make_uint4(
            pkbf(a.x, a.y), pkbf(a.z, a.w), pkbf(bb.x, bb.y), pkbf(bb.z, bb.w));
    }
    __syncthreads();

    const int l = t & 63, w = t >> 6;
    const int c = l & 15, q4 = l >> 4;
    const int rloc = w * 16 + c;
    f32x4 acc[8];
#pragma unroll
    for (int nt = 0; nt < 8; ++nt) acc[nt] = (f32x4){0.f, 0.f, 0.f, 0.f};

#pragma unroll
    for (int s = 0; s < 4; ++s) {
        int slot = (s * 4 + q4) ^ (c & 7);
        s16x8 af = *(const s16x8*)&xl[rloc * 64 + slot * 4];
#pragma unroll
        for (int nt = 0; nt < 8; ++nt) {
            int wr = nt * 16 + c;
            s16x8 bfr = *(const s16x8*)&wl[wr * 64 + slot * 4];
            acc[nt] = __builtin_amdgcn_mfma_f32_16x16x32_bf16(af, bfr, acc[nt], 0, 0, 0);
        }
    }

    float bv[8], as8[8], ad8[8];
#pragma unroll
    for (int nt = 0; nt < 8; ++nt) {
        bv[nt]  = bias ? bias[nt * 16 + c] : 0.f;
        as8[nt] = asrc ? asrc[nt * 16 + c] : 0.f;
        ad8[nt] = asrc ? adst[nt * 16 + c] : 0.f;
    }
    float ps[4] = {0.f, 0.f, 0.f, 0.f}, pd[4] = {0.f, 0.f, 0.f, 0.f};
    const int grow0 = row0 + w * 16 + q4 * 4;
#pragma unroll
    for (int nt = 0; nt < 8; ++nt) {
#pragma unroll
        for (int j = 0; j < 4; ++j) {
            float val = acc[nt][j] + bv[nt];
            if (grow0 + j < n) hbs[(size_t)(grow0 + j) * 128 + nt * 16 + c] = bf1(val);
            ps[j] = fmaf(val, as8[nt], ps[j]);
            pd[j] = fmaf(val, ad8[nt], pd[j]);
        }
    }
    if (asrc) {
#pragma unroll
        for (int j = 0; j < 4; ++j) {
            float a = ps[j], bb = pd[j];
#pragma unroll
            for (int o = 1; o < 16; o <<= 1) {
                a += __shfl_xor(a, o);
                bb += __shfl_xor(bb, o);
            }
            if (c == 0 && grow0 + j < n) { ssrc[grow0 + j] = a; sdst[grow0 + j] = bb; }
        }
    }
}

// ---------------- CSR build: two-level bucket sort ----------------

__global__ __launch_bounds__(256) void hist_bucket2(
    const int* __restrict__ eix, const int* __restrict__ eiy, int E, int n,
    int* __restrict__ bcx, int* __restrict__ bcy, int half)
{
    __shared__ int lh[64];
    int gb = blockIdx.x;
    const int* ei = eix; int* bc = bcx;
    if (gb >= half) { gb -= half; ei = eiy; bc = bcy; }
    int t = threadIdx.x;
    int ET = E + n;
    int nbk = (n + RPB - 1) >> LOG_R;
    for (int i = t; i < nbk; i += 256) lh[i] = 0;
    __syncthreads();
    for (int e = gb * 256 + t; e < ET; e += half * 256) {
        int d = (e < E) ? ei[E + e] : (e - E);
        atomicAdd(&lh[d >> LOG_R], 1);
    }
    __syncthreads();
    if (t < nbk) atomicAdd(&bc[t], lh[t]);
}

__global__ void bscan(
    const int* __restrict__ bcx, const int* __restrict__ bcy, int nbk,
    int* __restrict__ bbx, int* __restrict__ bby,
    int* __restrict__ curx, int* __restrict__ cury,
    int* __restrict__ offx_n, int* __restrict__ offy_n)
{
    int w = threadIdx.x >> 6, lane = threadIdx.x & 63;
    if (w > 1) return;
    const int* bc = w ? bcy : bcx;
    int* bb  = w ? bby : bbx;
    int* cur = w ? cury : curx;
    int* offn = w ? offy_n : offx_n;
    int c = (lane < nbk) ? bc[lane] : 0;
    int v = c;
#pragma unroll
    for (int o = 1; o < 64; o <<= 1) {
        int u = __shfl_up(v, o);
        if (lane >= o) v += u;
    }
    int excl = v - c;
    if (lane < nbk) { bb[lane] = excl; cur[lane] = excl; }
    if (lane == 63) { bb[nbk] = v; *offn = v; }
}

// pass A: bucket edges by dst>>LOG_R; per-block LDS sort + contiguous run flush.
__global__ __launch_bounds__(256) void bucket_pass(
    const int* __restrict__ eix, const int* __restrict__ eiy, int E, int n,
    int* __restrict__ curx, int* __restrict__ cury,
    unsigned* __restrict__ pkx, unsigned* __restrict__ pky, int half)
{
    __shared__ int lhist[64], lbase[64], gbase[64], lpos[64];
    __shared__ unsigned stg[EPB];
    __shared__ int gidx[EPB];
    int gb = blockIdx.x;
    const int* ei = eix; int* bcur = curx; unsigned* pk = pkx;
    if (gb >= half) { gb -= half; ei = eiy; bcur = cury; pk = pky; }
    const int t = threadIdx.x;
    const int ET = E + n;
    const int nbk = (n + RPB - 1) >> LOG_R;   // must be <= 64
    const int base = gb * EPB;

    for (int i = t; i < nbk; i += 256) lhist[i] = 0;
    __syncthreads();

    unsigned mypk[16];
    int myb[16];
#pragma unroll
    for (int k = 0; k < 16; ++k) {
        int e = base + k * 256 + t;
        if (e < ET) {
            int s, d;
            if (e < E) { s = ei[e]; d = ei[E + e]; }
            else       { s = e - E; d = e - E; }
            myb[k] = d >> LOG_R;
            mypk[k] = ((unsigned)s << LOG_R) | (unsigned)(d & (RPB - 1));
            atomicAdd(&lhist[myb[k]], 1);
        } else myb[k] = -1;
    }
    __syncthreads();

    if (t < 64) {
        int c = (t < nbk) ? lhist[t] : 0;
        int v = c;
#pragma unroll
        for (int o = 1; o < 64; o <<= 1) {
            int u = __shfl_up(v, o);
            if (t >= o) v += u;
        }
        int excl = v - c;
        if (t < nbk) {
            lbase[t] = excl;
            lpos[t] = excl;
            gbase[t] = c ? atomicAdd(&bcur[t], c) : 0;
        }
    }
    __syncthreads();

#pragma unroll
    for (int k = 0; k < 16; ++k) {
        if (myb[k] >= 0) {
            int p = atomicAdd(&lpos[myb[k]], 1);
            stg[p] = mypk[k];
            gidx[p] = gbase[myb[k]] + (p - lbase[myb[k]]);
        }
    }
    __syncthreads();

    int tot = lbase[nbk - 1] + lhist[nbk - 1];
    for (int i = t; i < tot; i += 256) pk[gidx[i]] = stg[i];
}

// pass B: one block per bucket; per-dst hist + scan (produces off[]), then
// in-LDS scatter and coalesced ushort writeback.
__global__ __launch_bounds__(256) void fine_sort(
    const unsigned* __restrict__ pkx, const unsigned* __restrict__ pky,
    const int* __restrict__ bbx, const int* __restrict__ bby,
    int* __restrict__ offx, int* __restrict__ offy,
    unsigned short* __restrict__ csx, unsigned short* __restrict__ csy,
    int n, int half)
{
    __shared__ int cur[RPB];
    __shared__ int ws[256];
    __shared__ unsigned short outs[CAPB];
    int gb = blockIdx.x;
    const unsigned* pk; const int* bb; int* off; unsigned short* cs;
    if (gb < half) { pk = pkx; bb = bbx; off = offx; cs = csx; }
    else { gb -= half; pk = pky; bb = bby; off = offy; cs = csy; }
    const int t = threadIdx.x;
    const int d0 = gb << LOG_R;
    const int nd = min(RPB, n - d0);
    const int base = bb[gb];
    const int sz = bb[gb + 1] - base;

    for (int i = t; i < RPB; i += 256) cur[i] = 0;
    __syncthreads();
    for (int i = t; i < sz; i += 256)
        atomicAdd(&cur[pk[base + i] & (RPB - 1)], 1);
    __syncthreads();

    int c0 = cur[t * 4], c1 = cur[t * 4 + 1], c2 = cur[t * 4 + 2], c3 = cur[t * 4 + 3];
    int s = c0 + c1 + c2 + c3;
    ws[t] = s; __syncthreads();
    for (int o = 1; o < 256; o <<= 1) {
        int a = (t >= o) ? ws[t - o] : 0;
        __syncthreads();
        ws[t] += a;
        __syncthreads();
    }
    int ex = ws[t] - s;
    int e0 = ex, e1 = ex + c0, e2 = e1 + c1, e3 = e2 + c2;
    cur[t * 4] = e0; cur[t * 4 + 1] = e1; cur[t * 4 + 2] = e2; cur[t * 4 + 3] = e3;
    int i0 = t * 4;
    if (i0     < nd) off[d0 + i0]     = base + e0;
    if (i0 + 1 < nd) off[d0 + i0 + 1] = base + e1;
    if (i0 + 2 < nd) off[d0 + i0 + 2] = base + e2;
    if (i0 + 3 < nd) off[d0 + i0 + 3] = base + e3;
    __syncthreads();

    if (sz <= CAPB) {
        for (int i = t; i < sz; i += 256) {
            unsigned p = pk[base + i];
            int pos = atomicAdd(&cur[p & (RPB - 1)], 1);
            outs[pos] = (unsigned short)(p >> LOG_R);
        }
        __syncthreads();
        for (int i = t; i < sz; i += 256) cs[base + i] = outs[i];
    } else {
        for (int i = t; i < sz; i += 256) {
            unsigned p = pk[base + i];
            int pos = atomicAdd(&cur[p & (RPB - 1)], 1);
            cs[base + pos] = (unsigned short)(p >> LOG_R);
        }
    }
}

// ---------------- fused two-graph GAT aggregation ----------------
// pass A: lane owns neighbor; (src, ex) staged to per-wave LDS (kills dynamic shfl).
// pass B: uniform-address LDS broadcast reads + 8-deep gather unroll.
__global__ __launch_bounds__(256) void gat_aggregate2(
    const int* __restrict__ off0, const unsigned short* __restrict__ cs0,
    const float* __restrict__ ss0, const float* __restrict__ sd0,
    const unsigned* __restrict__ hb0, const float* __restrict__ bias0,
    unsigned* __restrict__ out0,
    const int* __restrict__ off1, const unsigned short* __restrict__ cs1,
    const float* __restrict__ ss1, const float* __restrict__ sd1,
    const unsigned* __restrict__ hb1, const float* __restrict__ bias1,
    unsigned* __restrict__ out1,
    int n, int relu, int half)
{
    __shared__ uint2 stg[4][64];
    int b = blockIdx.x;
    const int *off; const unsigned short *csrc; const float *ssrc, *sdst, *bias;
    const unsigned* hb; unsigned* outu;
    if (b < half) { off = off0; csrc = cs0; ssrc = ss0; sdst = sd0; hb = hb0; bias = bias0; outu = out0; }
    else { b -= half; off = off1; csrc = cs1; ssrc = ss1; sdst = sd1; hb = hb1; bias = bias1; outu = out1; }

    int w = threadIdx.x >> 6;
    int node = b * 4 + w;
    int lane = threadIdx.x & 63;
    if (node >= n) return;
    int p0 = off[node], p1 = off[node + 1];
    int deg = p1 - p0;
    float sd = sdst[node];

    int mysrc = 0; float myv = -INFINITY;
    if (lane < deg) {
        mysrc = csrc[p0 + lane];
        float v = ssrc[mysrc] + sd;
        myv = (v > 0.f) ? v : NEG_SLOPE * v;
    }
    float m = myv;
    for (int p = p0 + 64 + lane; p < p1; p += 64) {   // rare deg>64 overflow
        int s = csrc[p];
        float v = ssrc[s] + sd;
        v = (v > 0.f) ? v : NEG_SLOPE * v;
        m = fmaxf(m, v);
    }
#pragma unroll
    for (int o = 32; o; o >>= 1) m = fmaxf(m, __shfl_xor(m, o));

    float myex = (lane < deg) ? __expf(myv - m) : 0.f;
    float part = myex;
    for (int p = p0 + 64 + lane; p < p1; p += 64) {
        int s = csrc[p];
        float v = ssrc[s] + sd;
        v = (v > 0.f) ? v : NEG_SLOPE * v;
        part += __expf(v - m);
    }
    float ssum = part;
#pragma unroll
    for (int o = 32; o; o >>= 1) ssum += __shfl_xor(ssum, o);

    // stage (src, ex) to wave-private LDS; read back at uniform addresses
    if (lane < deg && lane < 64)
        stg[w][lane] = make_uint2((unsigned)mysrc, __float_as_uint(myex));

    float ax = 0.f, ay = 0.f;
    int jcap = deg < 64 ? deg : 64;
    int j = 0;
    for (; j + 8 <= jcap; j += 8) {
        uint2 q[8];
#pragma unroll
        for (int k = 0; k < 8; ++k) q[k] = stg[w][j + k];     // broadcast reads
        unsigned u[8];
#pragma unroll
        for (int k = 0; k < 8; ++k) u[k] = hb[(size_t)q[k].x * 64 + lane];
#pragma unroll
        for (int k = 0; k < 8; ++k) {
            float e = __uint_as_float(q[k].y);
            ax = fmaf(e, bflo(u[k]), ax);
            ay = fmaf(e, bfhi(u[k]), ay);
        }
    }
    for (; j < jcap; ++j) {
        uint2 q = stg[w][j];
        unsigned u = hb[(size_t)q.x * 64 + lane];
        float e = __uint_as_float(q.y);
        ax = fmaf(e, bflo(u), ax);
        ay = fmaf(e, bfhi(u), ay);
    }
    for (int p = p0 + 64; p < p1; ++p) {              // rare deg>64 overflow
        int s = csrc[p];
        float v = ssrc[s] + sd;
        v = (v > 0.f) ? v : NEG_SLOPE * v;
        float e = __expf(v - m);
        unsigned u = hb[(size_t)s * 64 + lane];
        ax = fmaf(e, bflo(u), ax); ay = fmaf(e, bfhi(u), ay);
    }

    float inv = 1.f / (ssum + 1e-16f);
    float2 bv = ((const float2*)bias)[lane];
    float ox = fmaf(ax, inv, bv.x);
    float oy = fmaf(ay, inv, bv.y);
    if (relu) { ox = fmaxf(ox, 0.f); oy = fmaxf(oy, 0.f); }
    outu[(size_t)node * 64 + lane] = pkbf(ox, oy);
}

// ---------------- fused fc + log_softmax: 128 rows/block, 4 rows/thread ----------------
__global__ __launch_bounds__(256) void fc_logsoftmax(
    const unsigned* __restrict__ oxu, const unsigned* __restrict__ oyu,
    const float* __restrict__ xres,
    const float* __restrict__ fcw, const float* __restrict__ fcb,
    float* __restrict__ out, int n)
{
    __shared__ float wt[40 * 132];
    const int t = threadIdx.x;
    const int node0 = blockIdx.x * 128;
    const int c0 = (t & 7) * 5;
    int gr[4];
#pragma unroll
    for (int j = 0; j < 4; ++j) {
        gr[j] = node0 + (t >> 3) * 4 + j;
        if (gr[j] >= n) gr[j] = n - 1;
    }

    float acc[4][5] = {};

    for (int kc = 0; kc < 3; ++kc) {
        __syncthreads();
        for (int i = t; i < 40 * 32; i += 256) {
            int cc = i >> 5, c4 = i & 31;
            *(float4*)&wt[cc * 132 + c4 * 4] = ((const float4*)fcw)[(size_t)cc * 96 + kc * 32 + c4];
        }
        __syncthreads();
#pragma unroll 4
        for (int k4 = 0; k4 < 32; ++k4) {
            float4 xv[4];
            if (kc == 2) {
#pragma unroll
                for (int j = 0; j < 4; ++j)
                    xv[j] = ((const float4*)xres)[(size_t)gr[j] * 32 + k4];
            } else {
                const unsigned* S = kc ? oyu : oxu;
#pragma unroll
                for (int j = 0; j < 4; ++j) {
                    uint2 u = *(const uint2*)&S[(size_t)gr[j] * 64 + k4 * 2];
                    xv[j] = make_float4(bflo(u.x), bfhi(u.x), bflo(u.y), bfhi(u.y));
                }
            }
#pragma unroll
            for (int j5 = 0; j5 < 5; ++j5) {
                float4 wv = *(const float4*)&wt[(c0 + j5) * 132 + k4 * 4];
#pragma unroll
                for (int j = 0; j < 4; ++j) {
                    acc[j][j5] = fmaf(xv[j].x, wv.x, acc[j][j5]);
                    acc[j][j5] = fmaf(xv[j].y, wv.y, acc[j][j5]);
                    acc[j][j5] = fmaf(xv[j].z, wv.z, acc[j][j5]);
                    acc[j][j5] = fmaf(xv[j].w, wv.w, acc[j][j5]);
                }
            }
        }
    }

    float fb[5];
#pragma unroll
    for (int j5 = 0; j5 < 5; ++j5) fb[j5] = fcb[c0 + j5];

#pragma unroll
    for (int j = 0; j < 4; ++j) {
        float m0 = -INFINITY;
#pragma unroll
        for (int j5 = 0; j5 < 5; ++j5) { acc[j][j5] += fb[j5]; m0 = fmaxf(m0, acc[j][j5]); }
#pragma unroll
        for (int o = 1; o < 8; o <<= 1) m0 = fmaxf(m0, __shfl_xor(m0, o));
        float s0 = 0.f;
#pragma unroll
        for (int j5 = 0; j5 < 5; ++j5) s0 += __expf(acc[j][j5] - m0);
#pragma unroll
        for (int o = 1; o < 8; o <<= 1) s0 += __shfl_xor(s0, o);
        float lse = m0 + logf(s0);
#pragma unroll
        for (int j5 = 0; j5 < 5; ++j5)
            out[(size_t)gr[j] * 40 + c0 + j5] = acc[j][j5] - lse;
    }
}

extern "C" void kernel_launch(void* const* d_in, const int* in_sizes, int n_in,
                              void* d_out, int out_size, void* d_ws, size_t ws_size,
                              hipStream_t stream)
{
    const float* x    = (const float*)d_in[0];
    const float* y    = (const float*)d_in[1];
    const int*   eix  = (const int*)d_in[2];
    const int*   eiy  = (const int*)d_in[3];
    const float* a1iw = (const float*)d_in[4];
    const float* a1ib = (const float*)d_in[5];
    const float* a1ow = (const float*)d_in[6];
    const float* a1ob = (const float*)d_in[7];
    const float* a2iw = (const float*)d_in[8];
    const float* a2ib = (const float*)d_in[9];
    const float* a2ow = (const float*)d_in[10];
    const float* a2ob = (const float*)d_in[11];
    const float* g1w  = (const float*)d_in[12];
    const float* g1as = (const float*)d_in[13];
    const float* g1ad = (const float*)d_in[14];
    const float* g1b  = (const float*)d_in[15];
    const float* g2xw = (const float*)d_in[16];
    const float* g2xas= (const float*)d_in[17];
    const float* g2xad= (const float*)d_in[18];
    const float* g2xb = (const float*)d_in[19];
    const float* g2yw = (const float*)d_in[20];
    const float* g2yas= (const float*)d_in[21];
    const float* g2yad= (const float*)d_in[22];
    const float* g2yb = (const float*)d_in[23];
    const float* fcw  = (const float*)d_in[24];
    const float* fcb  = (const float*)d_in[25];
    float* outp = (float*)d_out;

    const int N = in_sizes[0] / 128;
    const int E = in_sizes[2] / 2;
    (void)n_in; (void)out_size; (void)ws_size;

    size_t NU = (size_t)N * 64;              // uints per bf16 node buffer
    unsigned* u0 = (unsigned*)d_ws;          // xa -> r1x -> ox
    unsigned* u1 = u0 + NU;                  // hx -> h2x
    unsigned* u2 = u1 + NU;                  // ya -> r1y -> oy
    unsigned* u3 = u2 + NU;                  // hy -> h2y
    float* ssx = (float*)(u3 + NU);
    float* sdx = ssx + N;
    float* ssy = sdx + N;
    float* sdy = ssy + N;
    float* cw1 = sdy + N;
    float* cb1 = cw1 + 128 * 128;
    float* cw2 = cb1 + 128;
    float* cb2 = cw2 + 128 * 128;
    const int Npad = (N + 4) & ~3;
    int* offx = (int*)(cb2 + 128);           // N+1
    int* offy = offx + Npad;
    int* bbx  = offy + Npad;                 // nbk+1 (<=65), pad 128
    int* bby  = bbx + 128;
    int* bcx  = bby + 128;                   // 64
    int* bcy  = bcx + 64;
    int* curx = bcy + 64;                    // 64
    int* cury = curx + 64;
    unsigned* pkx = (unsigned*)(cury + 64);  // E+N packed entries
    unsigned* pky = pkx + (E + N);
    unsigned short* csx = (unsigned short*)(pky + (E + N));   // E+N ushort
    unsigned short* csy = csx + (((E + N) + 1) & ~1);

    const int ET = E + N;
    const int NBK = (N + RPB - 1) >> LOG_R;  // <= 64 required (N <= 65536)
    const int gG = (N + 63) / 64;
    const int gA = (N + 3) / 4;
    const int nAB = (ET + EPB - 1) / EPB;

    mha_combine2<<<128, 256, 0, stream>>>(a1iw, a1ib, a1ow, a1ob,
                                          a2iw, a2ib, a2ow, a2ob,
                                          cw1, cb1, cw2, cb2);

    // ---- build both CSRs (two-level bucket sort) ----
    hipMemsetAsync(bcx, 0, 128 * sizeof(int), stream);   // bcx+bcy
    hist_bucket2<<<256, 256, 0, stream>>>(eix, eiy, E, N, bcx, bcy, 128);
    bscan<<<1, 128, 0, stream>>>(bcx, bcy, NBK, bbx, bby, curx, cury, offx + N, offy + N);
    bucket_pass<<<2 * nAB, 256, 0, stream>>>(eix, eiy, E, N, curx, cury, pkx, pky, nAB);
    fine_sort<<<2 * NBK, 256, 0, stream>>>(pkx, pky, bbx, bby, offx, offy, csx, csy, N, NBK);

    // ---- MHA projection (both) ----
    gemm_mfma2<false><<<2 * gG, 256, 0, stream>>>(
        x, y, cw1, cw2, cb1, cb2,
        nullptr, nullptr, nullptr, nullptr,
        (unsigned short*)u0, (unsigned short*)u2,
        nullptr, nullptr, nullptr, nullptr, N, gG);

    // ---- GAT layer 1 (both) ----
    gemm_mfma2<true><<<2 * gG, 256, 0, stream>>>(
        u0, u2, g1w, g1w, nullptr, nullptr,
        g1as, g1ad, g1as, g1ad,
        (unsigned short*)u1, (unsigned short*)u3,
        ssx, sdx, ssy, sdy, N, gG);
    gat_aggregate2<<<2 * gA, 256, 0, stream>>>(
        offx, csx, ssx, sdx, u1, g1b, u0,
        offy, csy, ssy, sdy, u3, g1b, u2,
        N, 1, gA);

    // ---- GAT layer 2 (both) ----
    gemm_mfma2<true><<<2 * gG, 256, 0, stream>>>(
        u0, u2, g2xw, g2yw, nullptr, nullptr,
        g2xas, g2xad, g2yas, g2yad,
        (unsigned short*)u1, (unsigned short*)u3,
        ssx, sdx, ssy, sdy, N, gG);
    gat_aggregate2<<<2 * gA, 256, 0, stream>>>(
        offx, csx, ssx, sdx, u1, g2xb, u0,
        offy, csy, ssy, sdy, u3, g2yb, u2,
        N, 0, gA);

    // ---- fusion fc + log_softmax ----
    fc_logsoftmax<<<(N + 127) / 128, 256, 0, stream>>>(u0, u2, x, fcw, fcb, outp, N);
}